// Round 7
// baseline (261.901 us; speedup 1.0000x reference)
//
#include <hip/hip_runtime.h>
#include <math.h>

#define BATCH 16
#define HW 262144          // 512*512
#define KSEL 26214         // int(0.1 * 262144)
#define MCAND 80           // TOP_K * CAND_MULT
#define TOPK 5
#define CAP 2048

// ---------------------------------------------------------------------------
// In-place radix-2 FFT, N=512:
//   forward DIF: natural input -> bit-reversed output
//   inverse DIT: bit-reversed input -> natural output
// DIT(DIF(x)) = N*x elementwise; phase normalize is elementwise, axes are
// independent, so the bit-reversed intermediate order is unobservable.
// Twiddles from a 256-entry LDS table: tw[i] = (cos, sin)(-2*pi*i/512).
// Stage hh = 1<<s uses idx = r << (8-s); inverse negates the sine.
// ---------------------------------------------------------------------------

// Gaussian blur coefficients, sigma=1, 5-tap.
#define GW0 0.05448868454964294f
#define GW1 0.24420134200323332f
#define GW2 0.40261994689424746f

#define FILL_TW(nthr)                                          \
    for (int i_ = threadIdx.x; i_ < 256; i_ += (nthr)) {       \
        float rev_ = -(float)i_ * (1.0f / 512.0f);             \
        tws[i_] = __builtin_amdgcn_sinf(rev_);                 \
        twc[i_] = __builtin_amdgcn_cosf(rev_);                 \
    }

// K1: window + forward DIF FFT along W. One block per (b, h) row.
__global__ void k_win_rowfft(const float* __restrict__ img, float2* __restrict__ A) {
    __shared__ float re[512], im[512];
    __shared__ float twc[256], tws[256];
    int row = blockIdx.x;           // b*512 + h
    int h = row & 511;
    int t = threadIdx.x;
    FILL_TW(256)
    float wr = 0.5f * (1.0f - __builtin_amdgcn_cosf((float)h * (1.0f / 511.0f)));
    const float* p = img + (size_t)row * 512;
    for (int i = t; i < 512; i += 256) {
        float wc = 0.5f * (1.0f - __builtin_amdgcn_cosf((float)i * (1.0f / 511.0f)));
        re[i] = p[i] * wr * wc;
        im[i] = 0.0f;
    }
    __syncthreads();
    #pragma unroll
    for (int s = 8; s >= 0; --s) {
        int hh = 1 << s;
        int r = t & (hh - 1);
        int j = ((t & ~(hh - 1)) << 1) | r;
        int idx = r << (8 - s);
        float cs = twc[idx], sn = tws[idx];
        float ax = re[j], ay = im[j];
        float bx = re[j + hh], by = im[j + hh];
        re[j] = ax + bx; im[j] = ay + by;
        float cx = ax - bx, cy = ay - by;
        re[j + hh] = cs * cx - sn * cy;
        im[j + hh] = cs * cy + sn * cx;
        __syncthreads();
    }
    float2* out = A + (size_t)row * 512;
    for (int i = t; i < 512; i += 256) out[i] = make_float2(re[i], im[i]);
}

// Fused H-axis pass on 512x16 column tiles (full 128B line per row-chunk):
// load -> fwd DIF along H -> phase-only normalize -> inv DIT along H -> store.
// 512 blocks = 16 images x 32 col-groups, 512 threads.
// LDS column stride 514 (== 2 mod 32): bank = (2c + j) % 32 -> uniform 2-way
// (free) for all stages hh>=2 and the load/store/normalize loops.
#define CSTR 514
__global__ __launch_bounds__(512) void k_colfft(float2* __restrict__ X) {
    __shared__ float re[16 * CSTR];
    __shared__ float im[16 * CSTR];
    __shared__ float twc[256], tws[256];
    int b = blockIdx.x >> 5;
    int c0 = (blockIdx.x & 31) * 16;
    int t = threadIdx.x;
    FILL_TW(512)
    float2* base = X + (size_t)b * HW + c0;
    // load: float4 = 2 interleaved complex cols; 8 lanes cover 16 cols = 128B
    #pragma unroll
    for (int ii = 0; ii < 8; ++ii) {
        int linear = ii * 512 + t;        // 0..4095
        int cp = linear & 7;              // column pair
        int e  = linear >> 3;             // row
        const float4 v = *reinterpret_cast<const float4*>(&base[(size_t)e * 512 + cp * 2]);
        int a0 = (cp * 2) * CSTR + e;
        int a1 = a0 + CSTR;
        re[a0] = v.x; im[a0] = v.y;
        re[a1] = v.z; im[a1] = v.w;
    }
    __syncthreads();
    int c = t & 15, tt = t >> 4;          // 32 threads per column
    float* cr = re + c * CSTR;
    float* ci = im + c * CSTR;
    // forward DIF along H
    #pragma unroll
    for (int s = 8; s >= 0; --s) {
        int hh = 1 << s;
        #pragma unroll
        for (int kk = 0; kk < 8; ++kk) {
            int k = kk * 32 + tt;
            int r = k & (hh - 1);
            int j = ((k & ~(hh - 1)) << 1) | r;
            int idx = r << (8 - s);
            float cs = twc[idx], sn = tws[idx];
            float ax = cr[j], ay = ci[j];
            float bx = cr[j + hh], by = ci[j + hh];
            cr[j] = ax + bx; ci[j] = ay + by;
            float cx = ax - bx, cy = ay - by;
            cr[j + hh] = cs * cx - sn * cy;
            ci[j + hh] = cs * cy + sn * cx;
        }
        __syncthreads();
    }
    // phase-only normalize (elementwise; order-agnostic)
    #pragma unroll
    for (int ii = 0; ii < 16; ++ii) {
        int linear = ii * 512 + t;        // 0..8191
        int cc = linear & 15, e = linear >> 4;
        int a = cc * CSTR + e;
        float x = re[a], y = im[a];
        float m2 = x * x + y * y;
        if (m2 > 0.0f) {
            float inv = rsqrtf(m2);
            re[a] = x * inv; im[a] = y * inv;
        } else {
            re[a] = 1.0f; im[a] = 0.0f;
        }
    }
    __syncthreads();
    // inverse DIT along H
    #pragma unroll
    for (int s = 0; s <= 8; ++s) {
        int hh = 1 << s;
        #pragma unroll
        for (int kk = 0; kk < 8; ++kk) {
            int k = kk * 32 + tt;
            int r = k & (hh - 1);
            int j = ((k & ~(hh - 1)) << 1) | r;
            int idx = r << (8 - s);
            float cs = twc[idx], sn = -tws[idx];
            float ax = cr[j], ay = ci[j];
            float bx0 = cr[j + hh], by0 = ci[j + hh];
            float bx = cs * bx0 - sn * by0;
            float by = cs * by0 + sn * bx0;
            cr[j] = ax + bx; ci[j] = ay + by;
            cr[j + hh] = ax - bx; ci[j + hh] = ay - by;
        }
        __syncthreads();
    }
    #pragma unroll
    for (int ii = 0; ii < 8; ++ii) {
        int linear = ii * 512 + t;
        int cp = linear & 7;
        int e  = linear >> 3;
        int a0 = (cp * 2) * CSTR + e;
        int a1 = a0 + CSTR;
        float4 v = make_float4(re[a0], im[a0], re[a1], im[a1]);
        *reinterpret_cast<float4*>(&base[(size_t)e * 512 + cp * 2]) = v;
    }
}

// Final inverse DIT FFT along W (bit-rev input) + 1/(H*W) scaling + |.|^2
// + horizontal 5-tap blur.
__global__ void k_mag_hblur(const float2* __restrict__ X, float* __restrict__ out) {
    __shared__ float re[512], im[512], smag[512];
    __shared__ float twc[256], tws[256];
    int row = blockIdx.x;
    int t = threadIdx.x;
    FILL_TW(256)
    const float2* p = X + (size_t)row * 512;
    for (int i = t; i < 512; i += 256) {
        float2 v = p[i];
        re[i] = v.x; im[i] = v.y;
    }
    __syncthreads();
    #pragma unroll
    for (int s = 0; s <= 8; ++s) {
        int hh = 1 << s;
        int r = t & (hh - 1);
        int j = ((t & ~(hh - 1)) << 1) | r;
        int idx = r << (8 - s);
        float cs = twc[idx], sn = -tws[idx];
        float ax = re[j], ay = im[j];
        float bx0 = re[j + hh], by0 = im[j + hh];
        float bx = cs * bx0 - sn * by0;
        float by = cs * by0 + sn * bx0;
        re[j] = ax + bx; im[j] = ay + by;
        re[j + hh] = ax - bx; im[j + hh] = ay - by;
        __syncthreads();
    }
    const float s = 3.814697265625e-06f;   // 1/262144, exact
    for (int i = t; i < 512; i += 256) {
        float rr = re[i] * s, ii = im[i] * s;
        smag[i] = rr * rr + ii * ii;
    }
    __syncthreads();
    float* o = out + (size_t)row * 512;
    for (int i = t; i < 512; i += 256) {
        float acc = GW2 * smag[i];
        if (i >= 1)   acc += GW1 * smag[i - 1];
        if (i >= 2)   acc += GW0 * smag[i - 2];
        if (i <= 510) acc += GW1 * smag[i + 1];
        if (i <= 509) acc += GW0 * smag[i + 2];
        o[i] = acc;
    }
}

// Vertical blur + per-BLOCK min/max partials (no atomics).
__global__ void k_vblur(const float* __restrict__ in, float* __restrict__ out,
                        float* __restrict__ pmn, float* __restrict__ pmx) {
    __shared__ float smn[256];
    __shared__ float smx[256];
    int t = threadIdx.x;
    int i = blockIdx.x * 256 + t;
    int y = (i >> 9) & 511;
    float acc = GW2 * in[i];
    if (y >= 1)   acc += GW1 * in[i - 512];
    if (y >= 2)   acc += GW0 * in[i - 1024];
    if (y <= 510) acc += GW1 * in[i + 512];
    if (y <= 509) acc += GW0 * in[i + 1024];
    out[i] = acc;
    smn[t] = acc; smx[t] = acc;
    __syncthreads();
    for (int s = 128; s > 0; s >>= 1) {
        if (t < s) { smn[t] = fminf(smn[t], smn[t + s]); smx[t] = fmaxf(smx[t], smx[t + s]); }
        __syncthreads();
    }
    if (t == 0) { pmn[blockIdx.x] = smn[0]; pmx[blockIdx.x] = smx[0]; }
}

// Fold 1024 partials per image -> mnf/mxf.
__global__ void k_reduce(const float* __restrict__ pmn, const float* __restrict__ pmx,
                         float* __restrict__ mnf, float* __restrict__ mxf) {
    __shared__ float smn[256];
    __shared__ float smx[256];
    int b = blockIdx.x, t = threadIdx.x;
    float lmn = INFINITY, lmx = -INFINITY;
    for (int j = t; j < 1024; j += 256) {
        lmn = fminf(lmn, pmn[b * 1024 + j]);
        lmx = fmaxf(lmx, pmx[b * 1024 + j]);
    }
    smn[t] = lmn; smx[t] = lmx;
    __syncthreads();
    for (int s = 128; s > 0; s >>= 1) {
        if (t < s) { smn[t] = fminf(smn[t], smn[t + s]); smx[t] = fmaxf(smx[t], smx[t + s]); }
        __syncthreads();
    }
    if (t == 0) { mnf[b] = smn[0]; mxf[b] = smx[0]; }
}

// Normalize + border mask -> final saliency (d_out), fused with hist round 1.
__global__ void k_norm_hist(const float* __restrict__ in, const float* __restrict__ mnf,
                            const float* __restrict__ mxf, float* __restrict__ out,
                            unsigned int* __restrict__ g) {
    __shared__ unsigned int h[4096];
    int t = threadIdx.x;
    int b = blockIdx.x >> 5;
    int base = b * HW + (blockIdx.x & 31) * 8192;
    float mn = mnf[b], mx = mxf[b];
    float inv = 1.0f / (mx - mn + 1e-8f);
    for (int i = t; i < 4096; i += 256) h[i] = 0u;
    __syncthreads();
    for (int j = 0; j < 32; ++j) {
        int idx = base + j * 256 + t;
        float v = (in[idx] - mn) * inv;
        int xx = idx & 511, yy = (idx >> 9) & 511;
        bool inside = (xx >= 12) && (xx < 500) && (yy >= 12) && (yy < 500);
        v = inside ? v : 0.0f;
        out[idx] = v;
        atomicAdd(&h[__float_as_uint(v) >> 20], 1u);
    }
    __syncthreads();
    unsigned int* gb = g + b * 4096;
    for (int i = t; i < 4096; i += 256)
        if (h[i]) atomicAdd(&gb[i], h[i]);
}

// ---------------------------------------------------------------------------
// Parallel 3-round radix select (bits 12/12/8) for BOTH k=26214 (threshold)
// and k=80 (candidate cutoff), sharing the same histogram passes.
// ---------------------------------------------------------------------------

__global__ void k_hist2(const float* __restrict__ sal,
                        const unsigned int* __restrict__ prefA,
                        const unsigned int* __restrict__ prefB,
                        unsigned int* __restrict__ gA, unsigned int* __restrict__ gB) {
    __shared__ unsigned int hA[4096];
    __shared__ unsigned int hB[4096];
    int t = threadIdx.x;
    int b = blockIdx.x >> 5;
    int start = (blockIdx.x & 31) * 8192;
    const float* p = sal + (size_t)b * HW;
    unsigned int pA = prefA[b], pB = prefB[b];
    for (int i = t; i < 4096; i += 256) { hA[i] = 0u; hB[i] = 0u; }
    __syncthreads();
    for (int j = 0; j < 32; ++j) {
        unsigned int u = __float_as_uint(p[start + j * 256 + t]);
        unsigned int hi = u >> 20, mid = (u >> 8) & 4095u;
        if (hi == pA) atomicAdd(&hA[mid], 1u);
        if (hi == pB) atomicAdd(&hB[mid], 1u);
    }
    __syncthreads();
    unsigned int* ga = gA + b * 4096;
    unsigned int* gb2 = gB + b * 4096;
    for (int i = t; i < 4096; i += 256) {
        if (hA[i]) atomicAdd(&ga[i], hA[i]);
        if (hB[i]) atomicAdd(&gb2[i], hB[i]);
    }
}

__global__ void k_hist3(const float* __restrict__ sal,
                        const unsigned int* __restrict__ prefA,
                        const unsigned int* __restrict__ prefB,
                        unsigned int* __restrict__ gA, unsigned int* __restrict__ gB) {
    __shared__ unsigned int hA[256];
    __shared__ unsigned int hB[256];
    int t = threadIdx.x;
    int b = blockIdx.x >> 5;
    int start = (blockIdx.x & 31) * 8192;
    const float* p = sal + (size_t)b * HW;
    unsigned int pA = prefA[b], pB = prefB[b];
    hA[t] = 0u; hB[t] = 0u;
    __syncthreads();
    for (int j = 0; j < 32; ++j) {
        unsigned int u = __float_as_uint(p[start + j * 256 + t]);
        unsigned int hi = u >> 8, lo = u & 255u;
        if (hi == pA) atomicAdd(&hA[lo], 1u);
        if (hi == pB) atomicAdd(&hB[lo], 1u);
    }
    __syncthreads();
    unsigned int* ga = gA + b * 256;
    unsigned int* gb2 = gB + b * 256;
    if (hA[t]) atomicAdd(&ga[t], hA[t]);
    if (hB[t]) atomicAdd(&gb2[t], hB[t]);
}

// Find bin d (from top) s.t. suffix count crosses krem.
__device__ void radix_step(const unsigned int* __restrict__ h, int nbins, int krem,
                           int t, unsigned int* tsum, int* sbin, int* skrem) {
    int bpt = nbins >> 8;
    unsigned int s = 0;
    for (int j = 0; j < bpt; ++j) s += h[t * bpt + j];
    tsum[t] = s;
    __syncthreads();
    if (t == 0) {
        unsigned int cum = 0; int seg = 0;
        for (int d = 255; d >= 0; --d) {
            unsigned int c2 = cum + tsum[d];
            if ((int)c2 >= krem) { seg = d; break; }
            cum = c2;
        }
        unsigned int c = cum;
        for (int j = bpt - 1; j >= 0; --j) {
            unsigned int hv = h[seg * bpt + j];
            if ((int)(c + hv) >= krem) { *sbin = seg * bpt + j; *skrem = krem - (int)c; break; }
            c += hv;
        }
    }
    __syncthreads();
}

__global__ void k_scan1(const unsigned int* __restrict__ g,
                        unsigned int* prefA, int* kremA, unsigned int* prefB, int* kremB) {
    __shared__ unsigned int tsum[256];
    __shared__ int sbin, skrem;
    int b = blockIdx.x, t = threadIdx.x;
    radix_step(g + b * 4096, 4096, KSEL, t, tsum, &sbin, &skrem);
    if (t == 0) { prefA[b] = (unsigned int)sbin; kremA[b] = skrem; }
    __syncthreads();
    radix_step(g + b * 4096, 4096, MCAND, t, tsum, &sbin, &skrem);
    if (t == 0) { prefB[b] = (unsigned int)sbin; kremB[b] = skrem; }
}

__global__ void k_scan2(const unsigned int* __restrict__ gA, const unsigned int* __restrict__ gB,
                        unsigned int* prefA, int* kremA, unsigned int* prefB, int* kremB) {
    __shared__ unsigned int tsum[256];
    __shared__ int sbin, skrem;
    int b = blockIdx.x, t = threadIdx.x;
    radix_step(gA + b * 4096, 4096, kremA[b], t, tsum, &sbin, &skrem);
    if (t == 0) { prefA[b] = (prefA[b] << 12) | (unsigned int)sbin; kremA[b] = skrem; }
    __syncthreads();
    radix_step(gB + b * 4096, 4096, kremB[b], t, tsum, &sbin, &skrem);
    if (t == 0) { prefB[b] = (prefB[b] << 12) | (unsigned int)sbin; kremB[b] = skrem; }
}

__global__ void k_scan3(const unsigned int* __restrict__ gA, const unsigned int* __restrict__ gB,
                        const unsigned int* prefA, const int* kremA,
                        const unsigned int* prefB, const int* kremB,
                        unsigned int* __restrict__ ucut) {
    __shared__ unsigned int tsum[256];
    __shared__ int sbin, skrem;
    __shared__ unsigned int thrbits;
    int b = blockIdx.x, t = threadIdx.x;
    radix_step(gA + b * 256, 256, kremA[b], t, tsum, &sbin, &skrem);
    if (t == 0) {
        unsigned int kth = (prefA[b] << 8) | (unsigned int)sbin;
        float thr = fmaxf(__uint_as_float(kth), 0.1f);
        thrbits = __float_as_uint(thr);
    }
    __syncthreads();
    radix_step(gB + b * 256, 256, kremB[b], t, tsum, &sbin, &skrem);
    if (t == 0) {
        unsigned int c80 = (prefB[b] << 8) | (unsigned int)sbin;
        ucut[b] = (c80 > thrbits) ? c80 : thrbits;   // uint order == float order (>=0)
    }
}

__global__ void k_collect(const float* __restrict__ sal, const unsigned int* __restrict__ ucut,
                          float* __restrict__ candv, int* __restrict__ candi,
                          int* __restrict__ ccnt) {
    int t = threadIdx.x;
    int b = blockIdx.x >> 5;
    int start = (blockIdx.x & 31) * 8192;
    const float* p = sal + (size_t)b * HW;
    unsigned int cut = ucut[b];
    for (int j = 0; j < 32; ++j) {
        int i = start + j * 256 + t;
        unsigned int u = __float_as_uint(p[i]);
        if (u >= cut) {
            int pos = atomicAdd(&ccnt[b], 1);
            if (pos < CAP) { candv[b * CAP + pos] = p[i]; candi[b * CAP + pos] = i; }
        }
    }
}

// Rank (value desc, index asc — lax.top_k tie rule), bitmask greedy NMS.
// No runtime-indexed thread-local arrays anywhere (they'd go to scratch).
__global__ void k_final(const float* __restrict__ candv, const int* __restrict__ candi,
                        const int* __restrict__ ccnt, float* __restrict__ out) {
    __shared__ float cval[CAP];
    __shared__ int   cidx[CAP];
    __shared__ int   si[MCAND];
    __shared__ float sx[MCAND];
    __shared__ float sy[MCAND];
    __shared__ unsigned long long nearLo[MCAND];
    __shared__ unsigned long long nearHi[MCAND];
    int b = blockIdx.x, t = threadIdx.x;
    int n = min(ccnt[b], CAP);
    for (int i = t; i < n; i += 256) { cval[i] = candv[b * CAP + i]; cidx[i] = candi[b * CAP + i]; }
    __syncthreads();
    int m = min(n, MCAND);
    for (int i = t; i < n; i += 256) {
        float vi = cval[i]; int ii = cidx[i];
        int rank = 0;
        for (int j = 0; j < n; j++) {
            float vj = cval[j];
            if (vj > vi || (vj == vi && cidx[j] < ii)) rank++;
        }
        if (rank < MCAND) si[rank] = ii;
    }
    __syncthreads();
    for (int i = t; i < m; i += 256) {
        sx[i] = (float)(si[i] & 511);
        sy[i] = (float)(si[i] >> 9);
    }
    __syncthreads();
    for (int i = t; i < m; i += 256) {
        unsigned long long lo = 0ull, hi = 0ull;
        float x = sx[i], y = sy[i];
        for (int j = 0; j < m; j++) {
            float dx = sx[j] - x, dy = sy[j] - y;
            if (dx * dx + dy * dy < 100.0f) {
                if (j < 64) lo |= (1ull << j);
                else        hi |= (1ull << (j - 64));
            }
        }
        nearLo[i] = lo; nearHi[i] = hi;
    }
    __syncthreads();
    if (t == 0) {
        unsigned long long kLo = 0ull, kHi = 0ull;
        int cnt = 0;
        for (int i = 0; i < m; i++) {
            bool near_kept = ((nearLo[i] & kLo) | (nearHi[i] & kHi)) != 0ull;
            if (!near_kept) {
                out[b * 10 + 2 * cnt]     = sx[i];
                out[b * 10 + 2 * cnt + 1] = sy[i];
                out[160 + b * 5 + cnt]    = 1.0f;
                if (i < 64) kLo |= (1ull << i); else kHi |= (1ull << (i - 64));
                cnt++;
                if (cnt == TOPK) break;
            }
        }
        for (int j = cnt; j < TOPK; j++) {
            out[b * 10 + 2 * j]     = -1.0f;
            out[b * 10 + 2 * j + 1] = -1.0f;
            out[160 + b * 5 + j]    = -1.0f;
        }
    }
}

extern "C" void kernel_launch(void* const* d_in, const int* in_sizes, int n_in,
                              void* d_out, int out_size, void* d_ws, size_t ws_size,
                              hipStream_t stream) {
    const float* img = (const float*)d_in[0];
    float* out = (float*)d_out;
    char* ws = (char*)d_ws;

    // ws layout (bytes):
    //   [0, 32M)   : A (complex spectrum, in-place through k_colfft).
    //                Dead after k_mag_hblur. Then reused:
    //                  [0, ~1.1M) hists + ccnt + cand   (memset after vblur)
    //                  [20M, 20M+128K) pmn/pmx partials (written by vblur)
    //   [32M, 48M) : hb (h-blurred saliency)
    //   [48M, 64M) : salb (v-blurred)
    //   [64M, +448): scalar stats
    float2* A    = (float2*)ws;
    float*  hb   = (float*)(ws + 33554432UL);
    float*  salb = (float*)(ws + 50331648UL);

    unsigned int* hist1  = (unsigned int*)(ws + 0UL);        // 16*4096 u32 = 256KB
    unsigned int* hist2a = (unsigned int*)(ws + 262144UL);   // 256KB
    unsigned int* hist2b = (unsigned int*)(ws + 524288UL);   // 256KB
    unsigned int* hist3a = (unsigned int*)(ws + 786432UL);   // 16KB
    unsigned int* hist3b = (unsigned int*)(ws + 802816UL);   // 16KB
    int*          ccnt   = (int*)(ws + 819200UL);            // 64B
    const size_t  ZEROBYTES = 819264UL;
    float*        candv  = (float*)(ws + 851968UL);          // 128KB
    int*          candi  = (int*)(ws + 983040UL);            // 128KB

    float* pmn = (float*)(ws + 20971520UL);                  // 64KB (16384 f32)
    float* pmx = (float*)(ws + 21037056UL);                  // 64KB

    char* stats = ws + 67108864UL;
    unsigned int* prefA = (unsigned int*)(stats + 0);
    int*          kremA = (int*)(stats + 64);
    unsigned int* prefB = (unsigned int*)(stats + 128);
    int*          kremB = (int*)(stats + 192);
    unsigned int* ucut  = (unsigned int*)(stats + 256);
    float*        mnf   = (float*)(stats + 320);
    float*        mxf   = (float*)(stats + 384);

    float* salout = out + 240;   // sal region of d_out

    k_win_rowfft<<<dim3(8192), dim3(256), 0, stream>>>(img, A);     // DIF along W
    k_colfft<<<dim3(512), dim3(512), 0, stream>>>(A);               // DIF-H + phase + DIT-H
    k_mag_hblur<<<dim3(8192), dim3(256), 0, stream>>>(A, hb);       // DIT-W + |.|^2 + hblur
    k_vblur<<<dim3(16384), dim3(256), 0, stream>>>(hb, salb, pmn, pmx);
    hipMemsetAsync(ws, 0, ZEROBYTES, stream);                       // hists + ccnt (A dead)
    k_reduce<<<dim3(BATCH), dim3(256), 0, stream>>>(pmn, pmx, mnf, mxf);
    k_norm_hist<<<dim3(512), dim3(256), 0, stream>>>(salb, mnf, mxf, salout, hist1);
    k_scan1<<<dim3(BATCH), dim3(256), 0, stream>>>(hist1, prefA, kremA, prefB, kremB);
    k_hist2<<<dim3(512), dim3(256), 0, stream>>>(salout, prefA, prefB, hist2a, hist2b);
    k_scan2<<<dim3(BATCH), dim3(256), 0, stream>>>(hist2a, hist2b, prefA, kremA, prefB, kremB);
    k_hist3<<<dim3(512), dim3(256), 0, stream>>>(salout, prefA, prefB, hist3a, hist3b);
    k_scan3<<<dim3(BATCH), dim3(256), 0, stream>>>(hist3a, hist3b, prefA, kremA, prefB, kremB, ucut);
    k_collect<<<dim3(512), dim3(256), 0, stream>>>(salout, ucut, candv, candi, ccnt);
    k_final<<<dim3(BATCH), dim3(256), 0, stream>>>(candv, candi, ccnt, out);
}

// Round 8
// 241.763 us; speedup vs baseline: 1.0833x; 1.0833x over previous
//
#include <hip/hip_runtime.h>
#include <math.h>

#define BATCH 16
#define HW 262144          // 512*512
#define KSEL 26214         // int(0.1 * 262144)
#define MCAND 80           // TOP_K * CAND_MULT
#define TOPK 5
#define CAP 2048

// ---------------------------------------------------------------------------
// In-place FFT, N=512. Row kernels: radix-2 DIF (fwd, natural->bitrev) /
// DIT (inv, bitrev->natural). Column kernel: mixed radix-4 (4 stages) +
// radix-2 (1 stage); inverse mirrors the forward exactly, so
// DIT(DIF(x)) = 512*x elementwise and the digit-reversed intermediate order
// is unobservable (phase normalize is elementwise; axes independent).
// Twiddles from LDS table tw[i] = e^{-2*pi*i*j/512} filled with HW sin/cos
// (args kept in (-0.5, 0] revolutions; tw[i+256] = -tw[i]).
// ---------------------------------------------------------------------------

// Gaussian blur coefficients, sigma=1, 5-tap.
#define GW0 0.05448868454964294f
#define GW1 0.24420134200323332f
#define GW2 0.40261994689424746f

#define FILL_TW256(nthr)                                       \
    for (int i_ = threadIdx.x; i_ < 256; i_ += (nthr)) {       \
        float rev_ = -(float)i_ * (1.0f / 512.0f);             \
        tws[i_] = __builtin_amdgcn_sinf(rev_);                 \
        twc[i_] = __builtin_amdgcn_cosf(rev_);                 \
    }

#define FILL_TW512(nthr)                                       \
    for (int i_ = threadIdx.x; i_ < 256; i_ += (nthr)) {       \
        float rev_ = -(float)i_ * (1.0f / 512.0f);             \
        float s_ = __builtin_amdgcn_sinf(rev_);                \
        float c_ = __builtin_amdgcn_cosf(rev_);                \
        tws[i_] = s_;        twc[i_] = c_;                     \
        tws[i_ + 256] = -s_; twc[i_ + 256] = -c_;              \
    }

// K1: window + forward DIF FFT along W. One block per (b, h) row.
__global__ void k_win_rowfft(const float* __restrict__ img, float2* __restrict__ A) {
    __shared__ float re[512], im[512];
    __shared__ float twc[256], tws[256];
    int row = blockIdx.x;           // b*512 + h
    int h = row & 511;
    int t = threadIdx.x;
    FILL_TW256(256)
    float wr = 0.5f * (1.0f - __builtin_amdgcn_cosf((float)h * (1.0f / 511.0f)));
    const float* p = img + (size_t)row * 512;
    for (int i = t; i < 512; i += 256) {
        float wc = 0.5f * (1.0f - __builtin_amdgcn_cosf((float)i * (1.0f / 511.0f)));
        re[i] = p[i] * wr * wc;
        im[i] = 0.0f;
    }
    __syncthreads();
    #pragma unroll
    for (int s = 8; s >= 0; --s) {
        int hh = 1 << s;
        int r = t & (hh - 1);
        int j = ((t & ~(hh - 1)) << 1) | r;
        int idx = r << (8 - s);
        float cs = twc[idx], sn = tws[idx];
        float ax = re[j], ay = im[j];
        float bx = re[j + hh], by = im[j + hh];
        re[j] = ax + bx; im[j] = ay + by;
        float cx = ax - bx, cy = ay - by;
        re[j + hh] = cs * cx - sn * cy;
        im[j + hh] = cs * cy + sn * cx;
        __syncthreads();
    }
    float2* out = A + (size_t)row * 512;
    for (int i = t; i < 512; i += 256) out[i] = make_float2(re[i], im[i]);
}

// Fused H-axis pass on 512x16 column tiles, radix-4:
// load -> fwd (4x radix-4 + radix-2) -> phase normalize -> inv (radix-2 +
// 4x radix-4, conj twiddles) -> store. 512 blocks, 512 threads.
// LDS column stride 514 (== 2 mod 32): accesses <= 2-way on radix-4 stages.
#define CSTR 514
__global__ __launch_bounds__(512) void k_colfft(float2* __restrict__ X) {
    __shared__ float re[16 * CSTR];
    __shared__ float im[16 * CSTR];
    __shared__ float twc[512], tws[512];
    int b = blockIdx.x >> 5;
    int c0 = (blockIdx.x & 31) * 16;
    int t = threadIdx.x;
    FILL_TW512(512)
    float2* base = X + (size_t)b * HW + c0;
    // load: float4 = 2 interleaved complex cols; 8 lanes cover 16 cols = 128B
    #pragma unroll
    for (int ii = 0; ii < 8; ++ii) {
        int linear = ii * 512 + t;        // 0..4095
        int cp = linear & 7;              // column pair
        int e  = linear >> 3;             // row
        const float4 v = *reinterpret_cast<const float4*>(&base[(size_t)e * 512 + cp * 2]);
        int a0 = (cp * 2) * CSTR + e;
        int a1 = a0 + CSTR;
        re[a0] = v.x; im[a0] = v.y;
        re[a1] = v.z; im[a1] = v.w;
    }
    __syncthreads();
    int c = t & 15, tt = t >> 4;          // 32 threads per column
    float* cr = re + c * CSTR;
    float* ci = im + c * CSTR;

    // ---- forward: 4 radix-4 DIF stages (n = 512,128,32,8) ----
    for (int s4 = 0; s4 < 4; ++s4) {
        int log2n = 9 - 2 * s4;
        int log2m = log2n - 2;
        int m = 1 << log2m;
        #pragma unroll
        for (int kk = 0; kk < 4; ++kk) {
            int q = kk * 32 + tt;
            int r = q & (m - 1);
            int j0 = ((q >> log2m) << log2n) + r;
            float a0x = cr[j0],         a0y = ci[j0];
            float a1x = cr[j0 + m],     a1y = ci[j0 + m];
            float a2x = cr[j0 + 2*m],   a2y = ci[j0 + 2*m];
            float a3x = cr[j0 + 3*m],   a3y = ci[j0 + 3*m];
            float s02x = a0x + a2x, s02y = a0y + a2y;
            float d02x = a0x - a2x, d02y = a0y - a2y;
            float s13x = a1x + a3x, s13y = a1y + a3y;
            float d13x = a1x - a3x, d13y = a1y - a3y;
            float y0x = s02x + s13x, y0y = s02y + s13y;
            float y2x = s02x - s13x, y2y = s02y - s13y;
            float y1x = d02x + d13y, y1y = d02y - d13x;   // d02 - i*d13
            float y3x = d02x - d13y, y3y = d02y + d13x;   // d02 + i*d13
            int e = r << (2 * s4);
            float c1 = twc[e],     s1 = tws[e];
            float c2 = twc[2*e],   s2 = tws[2*e];
            float c3 = twc[3*e],   s3 = tws[3*e];
            cr[j0]       = y0x;                 ci[j0]       = y0y;
            cr[j0 + m]   = y1x*c1 - y1y*s1;     ci[j0 + m]   = y1x*s1 + y1y*c1;
            cr[j0 + 2*m] = y2x*c2 - y2y*s2;     ci[j0 + 2*m] = y2x*s2 + y2y*c2;
            cr[j0 + 3*m] = y3x*c3 - y3y*s3;     ci[j0 + 3*m] = y3x*s3 + y3y*c3;
        }
        __syncthreads();
    }
    // ---- forward: final radix-2 stage (n=2) ----
    #pragma unroll
    for (int kk = 0; kk < 8; ++kk) {
        int j = (kk * 32 + tt) << 1;
        float ax = cr[j], ay = ci[j], bx = cr[j+1], by = ci[j+1];
        cr[j]   = ax + bx; ci[j]   = ay + by;
        cr[j+1] = ax - bx; ci[j+1] = ay - by;
    }
    __syncthreads();

    // ---- phase-only normalize (elementwise; order-agnostic) ----
    #pragma unroll
    for (int ii = 0; ii < 16; ++ii) {
        int linear = ii * 512 + t;        // 0..8191
        int cc = linear & 15, e = linear >> 4;
        int a = cc * CSTR + e;
        float x = re[a], y = im[a];
        float m2 = x * x + y * y;
        if (m2 > 0.0f) {
            float inv = rsqrtf(m2);
            re[a] = x * inv; im[a] = y * inv;
        } else {
            re[a] = 1.0f; im[a] = 0.0f;
        }
    }
    __syncthreads();

    // ---- inverse: radix-2 stage first (mirror of forward order) ----
    #pragma unroll
    for (int kk = 0; kk < 8; ++kk) {
        int j = (kk * 32 + tt) << 1;
        float ax = cr[j], ay = ci[j], bx = cr[j+1], by = ci[j+1];
        cr[j]   = ax + bx; ci[j]   = ay + by;
        cr[j+1] = ax - bx; ci[j+1] = ay - by;
    }
    __syncthreads();
    // ---- inverse: 4 radix-4 DIT stages (n = 8,32,128,512), conj twiddles ----
    for (int s4 = 3; s4 >= 0; --s4) {
        int log2n = 9 - 2 * s4;
        int log2m = log2n - 2;
        int m = 1 << log2m;
        #pragma unroll
        for (int kk = 0; kk < 4; ++kk) {
            int q = kk * 32 + tt;
            int r = q & (m - 1);
            int j0 = ((q >> log2m) << log2n) + r;
            float a0x = cr[j0],         a0y = ci[j0];
            float a1x = cr[j0 + m],     a1y = ci[j0 + m];
            float a2x = cr[j0 + 2*m],   a2y = ci[j0 + 2*m];
            float a3x = cr[j0 + 3*m],   a3y = ci[j0 + 3*m];
            int e = r << (2 * s4);
            float c1 = twc[e],     s1 = tws[e];
            float c2 = twc[2*e],   s2 = tws[2*e];
            float c3 = twc[3*e],   s3 = tws[3*e];
            // t_k = a_k * conj(tw[e*k])
            float t1x = a1x*c1 + a1y*s1,  t1y = a1y*c1 - a1x*s1;
            float t2x = a2x*c2 + a2y*s2,  t2y = a2y*c2 - a2x*s2;
            float t3x = a3x*c3 + a3y*s3,  t3y = a3y*c3 - a3x*s3;
            float s02x = a0x + t2x, s02y = a0y + t2y;
            float d02x = a0x - t2x, d02y = a0y - t2y;
            float s13x = t1x + t3x, s13y = t1y + t3y;
            float d13x = t1x - t3x, d13y = t1y - t3y;
            cr[j0]       = s02x + s13x;   ci[j0]       = s02y + s13y;
            cr[j0 + 2*m] = s02x - s13x;   ci[j0 + 2*m] = s02y - s13y;
            cr[j0 + m]   = d02x - d13y;   ci[j0 + m]   = d02y + d13x;   // d02 + i*d13
            cr[j0 + 3*m] = d02x + d13y;   ci[j0 + 3*m] = d02y - d13x;   // d02 - i*d13
        }
        __syncthreads();
    }

    #pragma unroll
    for (int ii = 0; ii < 8; ++ii) {
        int linear = ii * 512 + t;
        int cp = linear & 7;
        int e  = linear >> 3;
        int a0 = (cp * 2) * CSTR + e;
        int a1 = a0 + CSTR;
        float4 v = make_float4(re[a0], im[a0], re[a1], im[a1]);
        *reinterpret_cast<float4*>(&base[(size_t)e * 512 + cp * 2]) = v;
    }
}

// Final inverse DIT FFT along W (bit-rev input) + 1/(H*W) scaling + |.|^2
// + horizontal 5-tap blur.
__global__ void k_mag_hblur(const float2* __restrict__ X, float* __restrict__ out) {
    __shared__ float re[512], im[512], smag[512];
    __shared__ float twc[256], tws[256];
    int row = blockIdx.x;
    int t = threadIdx.x;
    FILL_TW256(256)
    const float2* p = X + (size_t)row * 512;
    for (int i = t; i < 512; i += 256) {
        float2 v = p[i];
        re[i] = v.x; im[i] = v.y;
    }
    __syncthreads();
    #pragma unroll
    for (int s = 0; s <= 8; ++s) {
        int hh = 1 << s;
        int r = t & (hh - 1);
        int j = ((t & ~(hh - 1)) << 1) | r;
        int idx = r << (8 - s);
        float cs = twc[idx], sn = -tws[idx];
        float ax = re[j], ay = im[j];
        float bx0 = re[j + hh], by0 = im[j + hh];
        float bx = cs * bx0 - sn * by0;
        float by = cs * by0 + sn * bx0;
        re[j] = ax + bx; im[j] = ay + by;
        re[j + hh] = ax - bx; im[j + hh] = ay - by;
        __syncthreads();
    }
    const float s = 3.814697265625e-06f;   // 1/262144, exact
    for (int i = t; i < 512; i += 256) {
        float rr = re[i] * s, ii = im[i] * s;
        smag[i] = rr * rr + ii * ii;
    }
    __syncthreads();
    float* o = out + (size_t)row * 512;
    for (int i = t; i < 512; i += 256) {
        float acc = GW2 * smag[i];
        if (i >= 1)   acc += GW1 * smag[i - 1];
        if (i >= 2)   acc += GW0 * smag[i - 2];
        if (i <= 510) acc += GW1 * smag[i + 1];
        if (i <= 509) acc += GW0 * smag[i + 2];
        o[i] = acc;
    }
}

// Vertical blur + per-BLOCK min/max partials (no atomics).
__global__ void k_vblur(const float* __restrict__ in, float* __restrict__ out,
                        float* __restrict__ pmn, float* __restrict__ pmx) {
    __shared__ float smn[256];
    __shared__ float smx[256];
    int t = threadIdx.x;
    int i = blockIdx.x * 256 + t;
    int y = (i >> 9) & 511;
    float acc = GW2 * in[i];
    if (y >= 1)   acc += GW1 * in[i - 512];
    if (y >= 2)   acc += GW0 * in[i - 1024];
    if (y <= 510) acc += GW1 * in[i + 512];
    if (y <= 509) acc += GW0 * in[i + 1024];
    out[i] = acc;
    smn[t] = acc; smx[t] = acc;
    __syncthreads();
    for (int s = 128; s > 0; s >>= 1) {
        if (t < s) { smn[t] = fminf(smn[t], smn[t + s]); smx[t] = fmaxf(smx[t], smx[t + s]); }
        __syncthreads();
    }
    if (t == 0) { pmn[blockIdx.x] = smn[0]; pmx[blockIdx.x] = smx[0]; }
}

// Normalize + border mask -> final saliency (d_out), fused with hist round 1.
// Each block redundantly folds its image's 1024 min/max partials first
// (reads are L2-hot; cheaper than a separate 16-block kernel launch).
__global__ void k_norm_hist(const float* __restrict__ in, const float* __restrict__ pmn,
                            const float* __restrict__ pmx, float* __restrict__ out,
                            unsigned int* __restrict__ g) {
    __shared__ unsigned int h[4096];
    __shared__ float smn[256], smx[256];
    int t = threadIdx.x;
    int b = blockIdx.x >> 5;
    int base = b * HW + (blockIdx.x & 31) * 8192;
    float lmn = INFINITY, lmx = -INFINITY;
    for (int j2 = t; j2 < 1024; j2 += 256) {
        lmn = fminf(lmn, pmn[b * 1024 + j2]);
        lmx = fmaxf(lmx, pmx[b * 1024 + j2]);
    }
    smn[t] = lmn; smx[t] = lmx;
    for (int i = t; i < 4096; i += 256) h[i] = 0u;
    __syncthreads();
    for (int s = 128; s > 0; s >>= 1) {
        if (t < s) { smn[t] = fminf(smn[t], smn[t + s]); smx[t] = fmaxf(smx[t], smx[t + s]); }
        __syncthreads();
    }
    float mn = smn[0], mx = smx[0];
    float inv = 1.0f / (mx - mn + 1e-8f);
    for (int j = 0; j < 32; ++j) {
        int idx = base + j * 256 + t;
        float v = (in[idx] - mn) * inv;
        int xx = idx & 511, yy = (idx >> 9) & 511;
        bool inside = (xx >= 12) && (xx < 500) && (yy >= 12) && (yy < 500);
        v = inside ? v : 0.0f;
        out[idx] = v;
        atomicAdd(&h[__float_as_uint(v) >> 20], 1u);
    }
    __syncthreads();
    unsigned int* gb = g + b * 4096;
    for (int i = t; i < 4096; i += 256)
        if (h[i]) atomicAdd(&gb[i], h[i]);
}

// ---------------------------------------------------------------------------
// Parallel 3-round radix select (bits 12/12/8) for BOTH k=26214 (threshold)
// and k=80 (candidate cutoff), sharing the same histogram passes.
// ---------------------------------------------------------------------------

__global__ void k_hist2(const float* __restrict__ sal,
                        const unsigned int* __restrict__ prefA,
                        const unsigned int* __restrict__ prefB,
                        unsigned int* __restrict__ gA, unsigned int* __restrict__ gB) {
    __shared__ unsigned int hA[4096];
    __shared__ unsigned int hB[4096];
    int t = threadIdx.x;
    int b = blockIdx.x >> 5;
    int start = (blockIdx.x & 31) * 8192;
    const float* p = sal + (size_t)b * HW;
    unsigned int pA = prefA[b], pB = prefB[b];
    for (int i = t; i < 4096; i += 256) { hA[i] = 0u; hB[i] = 0u; }
    __syncthreads();
    for (int j = 0; j < 32; ++j) {
        unsigned int u = __float_as_uint(p[start + j * 256 + t]);
        unsigned int hi = u >> 20, mid = (u >> 8) & 4095u;
        if (hi == pA) atomicAdd(&hA[mid], 1u);
        if (hi == pB) atomicAdd(&hB[mid], 1u);
    }
    __syncthreads();
    unsigned int* ga = gA + b * 4096;
    unsigned int* gb2 = gB + b * 4096;
    for (int i = t; i < 4096; i += 256) {
        if (hA[i]) atomicAdd(&ga[i], hA[i]);
        if (hB[i]) atomicAdd(&gb2[i], hB[i]);
    }
}

__global__ void k_hist3(const float* __restrict__ sal,
                        const unsigned int* __restrict__ prefA,
                        const unsigned int* __restrict__ prefB,
                        unsigned int* __restrict__ gA, unsigned int* __restrict__ gB) {
    __shared__ unsigned int hA[256];
    __shared__ unsigned int hB[256];
    int t = threadIdx.x;
    int b = blockIdx.x >> 5;
    int start = (blockIdx.x & 31) * 8192;
    const float* p = sal + (size_t)b * HW;
    unsigned int pA = prefA[b], pB = prefB[b];
    hA[t] = 0u; hB[t] = 0u;
    __syncthreads();
    for (int j = 0; j < 32; ++j) {
        unsigned int u = __float_as_uint(p[start + j * 256 + t]);
        unsigned int hi = u >> 8, lo = u & 255u;
        if (hi == pA) atomicAdd(&hA[lo], 1u);
        if (hi == pB) atomicAdd(&hB[lo], 1u);
    }
    __syncthreads();
    unsigned int* ga = gA + b * 256;
    unsigned int* gb2 = gB + b * 256;
    if (hA[t]) atomicAdd(&ga[t], hA[t]);
    if (hB[t]) atomicAdd(&gb2[t], hB[t]);
}

// Find bin d (from top) s.t. suffix count crosses krem.
__device__ void radix_step(const unsigned int* __restrict__ h, int nbins, int krem,
                           int t, unsigned int* tsum, int* sbin, int* skrem) {
    int bpt = nbins >> 8;
    unsigned int s = 0;
    for (int j = 0; j < bpt; ++j) s += h[t * bpt + j];
    tsum[t] = s;
    __syncthreads();
    if (t == 0) {
        unsigned int cum = 0; int seg = 0;
        for (int d = 255; d >= 0; --d) {
            unsigned int c2 = cum + tsum[d];
            if ((int)c2 >= krem) { seg = d; break; }
            cum = c2;
        }
        unsigned int c = cum;
        for (int j = bpt - 1; j >= 0; --j) {
            unsigned int hv = h[seg * bpt + j];
            if ((int)(c + hv) >= krem) { *sbin = seg * bpt + j; *skrem = krem - (int)c; break; }
            c += hv;
        }
    }
    __syncthreads();
}

__global__ void k_scan1(const unsigned int* __restrict__ g,
                        unsigned int* prefA, int* kremA, unsigned int* prefB, int* kremB) {
    __shared__ unsigned int tsum[256];
    __shared__ int sbin, skrem;
    int b = blockIdx.x, t = threadIdx.x;
    radix_step(g + b * 4096, 4096, KSEL, t, tsum, &sbin, &skrem);
    if (t == 0) { prefA[b] = (unsigned int)sbin; kremA[b] = skrem; }
    __syncthreads();
    radix_step(g + b * 4096, 4096, MCAND, t, tsum, &sbin, &skrem);
    if (t == 0) { prefB[b] = (unsigned int)sbin; kremB[b] = skrem; }
}

__global__ void k_scan2(const unsigned int* __restrict__ gA, const unsigned int* __restrict__ gB,
                        unsigned int* prefA, int* kremA, unsigned int* prefB, int* kremB) {
    __shared__ unsigned int tsum[256];
    __shared__ int sbin, skrem;
    int b = blockIdx.x, t = threadIdx.x;
    radix_step(gA + b * 4096, 4096, kremA[b], t, tsum, &sbin, &skrem);
    if (t == 0) { prefA[b] = (prefA[b] << 12) | (unsigned int)sbin; kremA[b] = skrem; }
    __syncthreads();
    radix_step(gB + b * 4096, 4096, kremB[b], t, tsum, &sbin, &skrem);
    if (t == 0) { prefB[b] = (prefB[b] << 12) | (unsigned int)sbin; kremB[b] = skrem; }
}

__global__ void k_scan3(const unsigned int* __restrict__ gA, const unsigned int* __restrict__ gB,
                        const unsigned int* prefA, const int* kremA,
                        const unsigned int* prefB, const int* kremB,
                        unsigned int* __restrict__ ucut) {
    __shared__ unsigned int tsum[256];
    __shared__ int sbin, skrem;
    __shared__ unsigned int thrbits;
    int b = blockIdx.x, t = threadIdx.x;
    radix_step(gA + b * 256, 256, kremA[b], t, tsum, &sbin, &skrem);
    if (t == 0) {
        unsigned int kth = (prefA[b] << 8) | (unsigned int)sbin;
        float thr = fmaxf(__uint_as_float(kth), 0.1f);
        thrbits = __float_as_uint(thr);
    }
    __syncthreads();
    radix_step(gB + b * 256, 256, kremB[b], t, tsum, &sbin, &skrem);
    if (t == 0) {
        unsigned int c80 = (prefB[b] << 8) | (unsigned int)sbin;
        ucut[b] = (c80 > thrbits) ? c80 : thrbits;   // uint order == float order (>=0)
    }
}

__global__ void k_collect(const float* __restrict__ sal, const unsigned int* __restrict__ ucut,
                          float* __restrict__ candv, int* __restrict__ candi,
                          int* __restrict__ ccnt) {
    int t = threadIdx.x;
    int b = blockIdx.x >> 5;
    int start = (blockIdx.x & 31) * 8192;
    const float* p = sal + (size_t)b * HW;
    unsigned int cut = ucut[b];
    for (int j = 0; j < 32; ++j) {
        int i = start + j * 256 + t;
        unsigned int u = __float_as_uint(p[i]);
        if (u >= cut) {
            int pos = atomicAdd(&ccnt[b], 1);
            if (pos < CAP) { candv[b * CAP + pos] = p[i]; candi[b * CAP + pos] = i; }
        }
    }
}

// Rank (value desc, index asc — lax.top_k tie rule), bitmask greedy NMS.
// No runtime-indexed thread-local arrays anywhere (they'd go to scratch).
__global__ void k_final(const float* __restrict__ candv, const int* __restrict__ candi,
                        const int* __restrict__ ccnt, float* __restrict__ out) {
    __shared__ float cval[CAP];
    __shared__ int   cidx[CAP];
    __shared__ int   si[MCAND];
    __shared__ float sx[MCAND];
    __shared__ float sy[MCAND];
    __shared__ unsigned long long nearLo[MCAND];
    __shared__ unsigned long long nearHi[MCAND];
    int b = blockIdx.x, t = threadIdx.x;
    int n = min(ccnt[b], CAP);
    for (int i = t; i < n; i += 256) { cval[i] = candv[b * CAP + i]; cidx[i] = candi[b * CAP + i]; }
    __syncthreads();
    int m = min(n, MCAND);
    for (int i = t; i < n; i += 256) {
        float vi = cval[i]; int ii = cidx[i];
        int rank = 0;
        for (int j = 0; j < n; j++) {
            float vj = cval[j];
            if (vj > vi || (vj == vi && cidx[j] < ii)) rank++;
        }
        if (rank < MCAND) si[rank] = ii;
    }
    __syncthreads();
    for (int i = t; i < m; i += 256) {
        sx[i] = (float)(si[i] & 511);
        sy[i] = (float)(si[i] >> 9);
    }
    __syncthreads();
    for (int i = t; i < m; i += 256) {
        unsigned long long lo = 0ull, hi = 0ull;
        float x = sx[i], y = sy[i];
        for (int j = 0; j < m; j++) {
            float dx = sx[j] - x, dy = sy[j] - y;
            if (dx * dx + dy * dy < 100.0f) {
                if (j < 64) lo |= (1ull << j);
                else        hi |= (1ull << (j - 64));
            }
        }
        nearLo[i] = lo; nearHi[i] = hi;
    }
    __syncthreads();
    if (t == 0) {
        unsigned long long kLo = 0ull, kHi = 0ull;
        int cnt = 0;
        for (int i = 0; i < m; i++) {
            bool near_kept = ((nearLo[i] & kLo) | (nearHi[i] & kHi)) != 0ull;
            if (!near_kept) {
                out[b * 10 + 2 * cnt]     = sx[i];
                out[b * 10 + 2 * cnt + 1] = sy[i];
                out[160 + b * 5 + cnt]    = 1.0f;
                if (i < 64) kLo |= (1ull << i); else kHi |= (1ull << (i - 64));
                cnt++;
                if (cnt == TOPK) break;
            }
        }
        for (int j = cnt; j < TOPK; j++) {
            out[b * 10 + 2 * j]     = -1.0f;
            out[b * 10 + 2 * j + 1] = -1.0f;
            out[160 + b * 5 + j]    = -1.0f;
        }
    }
}

extern "C" void kernel_launch(void* const* d_in, const int* in_sizes, int n_in,
                              void* d_out, int out_size, void* d_ws, size_t ws_size,
                              hipStream_t stream) {
    const float* img = (const float*)d_in[0];
    float* out = (float*)d_out;
    char* ws = (char*)d_ws;

    // ws layout (bytes):
    //   [0, 32M)   : A (complex spectrum, in-place through k_colfft).
    //                Dead after k_mag_hblur. Then reused:
    //                  [0, ~1.1M) hists + ccnt + cand   (memset after vblur)
    //                  [20M, 20M+128K) pmn/pmx partials (written by vblur)
    //   [32M, 48M) : hb (h-blurred saliency)
    //   [48M, 64M) : salb (v-blurred)
    //   [64M, +448): scalar stats
    float2* A    = (float2*)ws;
    float*  hb   = (float*)(ws + 33554432UL);
    float*  salb = (float*)(ws + 50331648UL);

    unsigned int* hist1  = (unsigned int*)(ws + 0UL);        // 16*4096 u32 = 256KB
    unsigned int* hist2a = (unsigned int*)(ws + 262144UL);   // 256KB
    unsigned int* hist2b = (unsigned int*)(ws + 524288UL);   // 256KB
    unsigned int* hist3a = (unsigned int*)(ws + 786432UL);   // 16KB
    unsigned int* hist3b = (unsigned int*)(ws + 802816UL);   // 16KB
    int*          ccnt   = (int*)(ws + 819200UL);            // 64B
    const size_t  ZEROBYTES = 819264UL;
    float*        candv  = (float*)(ws + 851968UL);          // 128KB
    int*          candi  = (int*)(ws + 983040UL);            // 128KB

    float* pmn = (float*)(ws + 20971520UL);                  // 64KB (16384 f32)
    float* pmx = (float*)(ws + 21037056UL);                  // 64KB

    char* stats = ws + 67108864UL;
    unsigned int* prefA = (unsigned int*)(stats + 0);
    int*          kremA = (int*)(stats + 64);
    unsigned int* prefB = (unsigned int*)(stats + 128);
    int*          kremB = (int*)(stats + 192);
    unsigned int* ucut  = (unsigned int*)(stats + 256);

    float* salout = out + 240;   // sal region of d_out

    k_win_rowfft<<<dim3(8192), dim3(256), 0, stream>>>(img, A);     // DIF along W
    k_colfft<<<dim3(512), dim3(512), 0, stream>>>(A);               // radix-4 H pass
    k_mag_hblur<<<dim3(8192), dim3(256), 0, stream>>>(A, hb);       // DIT-W + |.|^2 + hblur
    k_vblur<<<dim3(16384), dim3(256), 0, stream>>>(hb, salb, pmn, pmx);
    hipMemsetAsync(ws, 0, ZEROBYTES, stream);                       // hists + ccnt (A dead)
    k_norm_hist<<<dim3(512), dim3(256), 0, stream>>>(salb, pmn, pmx, salout, hist1);
    k_scan1<<<dim3(BATCH), dim3(256), 0, stream>>>(hist1, prefA, kremA, prefB, kremB);
    k_hist2<<<dim3(512), dim3(256), 0, stream>>>(salout, prefA, prefB, hist2a, hist2b);
    k_scan2<<<dim3(BATCH), dim3(256), 0, stream>>>(hist2a, hist2b, prefA, kremA, prefB, kremB);
    k_hist3<<<dim3(512), dim3(256), 0, stream>>>(salout, prefA, prefB, hist3a, hist3b);
    k_scan3<<<dim3(BATCH), dim3(256), 0, stream>>>(hist3a, hist3b, prefA, kremA, prefB, kremB, ucut);
    k_collect<<<dim3(512), dim3(256), 0, stream>>>(salout, ucut, candv, candi, ccnt);
    k_final<<<dim3(BATCH), dim3(256), 0, stream>>>(candv, candi, ccnt, out);
}

// Round 9
// 232.478 us; speedup vs baseline: 1.1266x; 1.0399x over previous
//
#include <hip/hip_runtime.h>
#include <math.h>

#define BATCH 16
#define HW 262144          // 512*512
#define KSEL 26214         // int(0.1 * 262144)
#define MCAND 80           // TOP_K * CAND_MULT
#define TOPK 5
#define CAP 2048

// ---------------------------------------------------------------------------
// In-place FFT, N=512, mixed radix-4 (4 stages) + radix-2 (1 stage) on all
// axes. Forward DIF: natural -> digit-reversed; inverse DIT (conj twiddles,
// mirrored stage order): digit-reversed -> natural. DIT(DIF(x)) = 512*x
// elementwise, so the digit-reversed intermediate order is unobservable
// (phase normalize is elementwise; axes independent).
// Twiddles from LDS table tw[i] = e^{-2*pi*i/512} (tw[i+256] = -tw[i]).
// ---------------------------------------------------------------------------

// Gaussian blur coefficients, sigma=1, 5-tap.
#define GW0 0.05448868454964294f
#define GW1 0.24420134200323332f
#define GW2 0.40261994689424746f

#define FILL_TW512(nthr)                                       \
    for (int i_ = threadIdx.x; i_ < 256; i_ += (nthr)) {       \
        float rev_ = -(float)i_ * (1.0f / 512.0f);             \
        float s_ = __builtin_amdgcn_sinf(rev_);                \
        float c_ = __builtin_amdgcn_cosf(rev_);                \
        tws[i_] = s_;        twc[i_] = c_;                     \
        tws[i_ + 256] = -s_; twc[i_ + 256] = -c_;              \
    }

// LDS pad-every-16: breaks power-of-2 stride conflicts (<=4-way worst).
#define RP(a) ((a) + ((a) >> 4))
#define RSZ 544             // 512 + 32 pad floats per row

// Radix-4 DIF forward butterfly (1 per thread), q = butterfly idx 0..127.
#define R4_FWD(rr, ri, q, s4)                                                 \
    {                                                                          \
        const int log2n = 9 - 2 * (s4);                                        \
        const int log2m = log2n - 2;                                           \
        const int m = 1 << log2m;                                              \
        int r = (q) & (m - 1);                                                 \
        int j0 = (((q) >> log2m) << log2n) + r;                                \
        float a0x = rr[RP(j0)],       a0y = ri[RP(j0)];                        \
        float a1x = rr[RP(j0 + m)],   a1y = ri[RP(j0 + m)];                    \
        float a2x = rr[RP(j0 + 2*m)], a2y = ri[RP(j0 + 2*m)];                  \
        float a3x = rr[RP(j0 + 3*m)], a3y = ri[RP(j0 + 3*m)];                  \
        float s02x = a0x + a2x, s02y = a0y + a2y;                              \
        float d02x = a0x - a2x, d02y = a0y - a2y;                              \
        float s13x = a1x + a3x, s13y = a1y + a3y;                              \
        float d13x = a1x - a3x, d13y = a1y - a3y;                              \
        float y0x = s02x + s13x, y0y = s02y + s13y;                            \
        float y2x = s02x - s13x, y2y = s02y - s13y;                            \
        float y1x = d02x + d13y, y1y = d02y - d13x;                            \
        float y3x = d02x - d13y, y3y = d02y + d13x;                            \
        int e = r << (2 * (s4));                                               \
        float c1 = twc[e],   s1 = tws[e];                                      \
        float c2 = twc[2*e], s2 = tws[2*e];                                    \
        float c3 = twc[3*e], s3 = tws[3*e];                                    \
        rr[RP(j0)]       = y0x;             ri[RP(j0)]       = y0y;            \
        rr[RP(j0 + m)]   = y1x*c1 - y1y*s1; ri[RP(j0 + m)]   = y1x*s1 + y1y*c1;\
        rr[RP(j0 + 2*m)] = y2x*c2 - y2y*s2; ri[RP(j0 + 2*m)] = y2x*s2 + y2y*c2;\
        rr[RP(j0 + 3*m)] = y3x*c3 - y3y*s3; ri[RP(j0 + 3*m)] = y3x*s3 + y3y*c3;\
    }

// Radix-4 DIT inverse butterfly (conj twiddles), mirror of R4_FWD.
#define R4_INV(rr, ri, q, s4)                                                 \
    {                                                                          \
        const int log2n = 9 - 2 * (s4);                                        \
        const int log2m = log2n - 2;                                           \
        const int m = 1 << log2m;                                              \
        int r = (q) & (m - 1);                                                 \
        int j0 = (((q) >> log2m) << log2n) + r;                                \
        float a0x = rr[RP(j0)],       a0y = ri[RP(j0)];                        \
        float a1x = rr[RP(j0 + m)],   a1y = ri[RP(j0 + m)];                    \
        float a2x = rr[RP(j0 + 2*m)], a2y = ri[RP(j0 + 2*m)];                  \
        float a3x = rr[RP(j0 + 3*m)], a3y = ri[RP(j0 + 3*m)];                  \
        int e = r << (2 * (s4));                                               \
        float c1 = twc[e],   s1 = tws[e];                                      \
        float c2 = twc[2*e], s2 = tws[2*e];                                    \
        float c3 = twc[3*e], s3 = tws[3*e];                                    \
        float t1x = a1x*c1 + a1y*s1,  t1y = a1y*c1 - a1x*s1;                   \
        float t2x = a2x*c2 + a2y*s2,  t2y = a2y*c2 - a2x*s2;                   \
        float t3x = a3x*c3 + a3y*s3,  t3y = a3y*c3 - a3x*s3;                   \
        float s02x = a0x + t2x, s02y = a0y + t2y;                              \
        float d02x = a0x - t2x, d02y = a0y - t2y;                              \
        float s13x = t1x + t3x, s13y = t1y + t3y;                              \
        float d13x = t1x - t3x, d13y = t1y - t3y;                              \
        rr[RP(j0)]       = s02x + s13x;  ri[RP(j0)]       = s02y + s13y;       \
        rr[RP(j0 + 2*m)] = s02x - s13x;  ri[RP(j0 + 2*m)] = s02y - s13y;       \
        rr[RP(j0 + m)]   = d02x - d13y;  ri[RP(j0 + m)]   = d02y + d13x;       \
        rr[RP(j0 + 3*m)] = d02x + d13y;  ri[RP(j0 + 3*m)] = d02y - d13x;       \
    }

// K1: window + forward radix-4 FFT along W. 2 rows per 256-thread block.
__global__ void k_win_rowfft(const float* __restrict__ img, float2* __restrict__ A) {
    __shared__ float re[2 * RSZ], im[2 * RSZ];
    __shared__ float twc[512], tws[512];
    int t = threadIdx.x;
    FILL_TW512(256)
    int lr = t >> 7;                 // local row 0/1
    int u  = t & 127;                // per-row lane
    int row = blockIdx.x * 2 + lr;   // b*512 + h
    int h = row & 511;
    float wr = 0.5f * (1.0f - __builtin_amdgcn_cosf((float)h * (1.0f / 511.0f)));
    const float* p = img + (size_t)row * 512;
    float* rr = re + lr * RSZ;
    float* ri = im + lr * RSZ;
    {
        int i0 = u * 4;
        float4 v = *reinterpret_cast<const float4*>(p + i0);
        float w0 = 0.5f * (1.0f - __builtin_amdgcn_cosf((float)(i0 + 0) * (1.0f / 511.0f)));
        float w1 = 0.5f * (1.0f - __builtin_amdgcn_cosf((float)(i0 + 1) * (1.0f / 511.0f)));
        float w2 = 0.5f * (1.0f - __builtin_amdgcn_cosf((float)(i0 + 2) * (1.0f / 511.0f)));
        float w3 = 0.5f * (1.0f - __builtin_amdgcn_cosf((float)(i0 + 3) * (1.0f / 511.0f)));
        rr[RP(i0 + 0)] = v.x * wr * w0;  ri[RP(i0 + 0)] = 0.0f;
        rr[RP(i0 + 1)] = v.y * wr * w1;  ri[RP(i0 + 1)] = 0.0f;
        rr[RP(i0 + 2)] = v.z * wr * w2;  ri[RP(i0 + 2)] = 0.0f;
        rr[RP(i0 + 3)] = v.w * wr * w3;  ri[RP(i0 + 3)] = 0.0f;
    }
    __syncthreads();
    R4_FWD(rr, ri, u, 0)  __syncthreads();
    R4_FWD(rr, ri, u, 1)  __syncthreads();
    R4_FWD(rr, ri, u, 2)  __syncthreads();
    R4_FWD(rr, ri, u, 3)  __syncthreads();
    #pragma unroll
    for (int kk = 0; kk < 2; ++kk) {     // final radix-2 (2 butterflies/thread)
        int j = (kk * 128 + u) << 1;
        float ax = rr[RP(j)], ay = ri[RP(j)], bx = rr[RP(j + 1)], by = ri[RP(j + 1)];
        rr[RP(j)]     = ax + bx;  ri[RP(j)]     = ay + by;
        rr[RP(j + 1)] = ax - bx;  ri[RP(j + 1)] = ay - by;
    }
    __syncthreads();
    float2* out = A + (size_t)row * 512;
    #pragma unroll
    for (int k2 = 0; k2 < 2; ++k2) {
        int i = u * 4 + k2 * 2;
        float4 v = make_float4(rr[RP(i)], ri[RP(i)], rr[RP(i + 1)], ri[RP(i + 1)]);
        *reinterpret_cast<float4*>(&out[i]) = v;
    }
}

// Fused H-axis pass on 512x16 column tiles, radix-4 (unchanged from r8).
#define CSTR 514
__global__ __launch_bounds__(512) void k_colfft(float2* __restrict__ X) {
    __shared__ float re[16 * CSTR];
    __shared__ float im[16 * CSTR];
    __shared__ float twc[512], tws[512];
    int b = blockIdx.x >> 5;
    int c0 = (blockIdx.x & 31) * 16;
    int t = threadIdx.x;
    FILL_TW512(512)
    float2* base = X + (size_t)b * HW + c0;
    #pragma unroll
    for (int ii = 0; ii < 8; ++ii) {
        int linear = ii * 512 + t;
        int cp = linear & 7;
        int e  = linear >> 3;
        const float4 v = *reinterpret_cast<const float4*>(&base[(size_t)e * 512 + cp * 2]);
        int a0 = (cp * 2) * CSTR + e;
        int a1 = a0 + CSTR;
        re[a0] = v.x; im[a0] = v.y;
        re[a1] = v.z; im[a1] = v.w;
    }
    __syncthreads();
    int c = t & 15, tt = t >> 4;
    float* cr = re + c * CSTR;
    float* ci = im + c * CSTR;

    for (int s4 = 0; s4 < 4; ++s4) {
        int log2n = 9 - 2 * s4;
        int log2m = log2n - 2;
        int m = 1 << log2m;
        #pragma unroll
        for (int kk = 0; kk < 4; ++kk) {
            int q = kk * 32 + tt;
            int r = q & (m - 1);
            int j0 = ((q >> log2m) << log2n) + r;
            float a0x = cr[j0],       a0y = ci[j0];
            float a1x = cr[j0 + m],   a1y = ci[j0 + m];
            float a2x = cr[j0 + 2*m], a2y = ci[j0 + 2*m];
            float a3x = cr[j0 + 3*m], a3y = ci[j0 + 3*m];
            float s02x = a0x + a2x, s02y = a0y + a2y;
            float d02x = a0x - a2x, d02y = a0y - a2y;
            float s13x = a1x + a3x, s13y = a1y + a3y;
            float d13x = a1x - a3x, d13y = a1y - a3y;
            float y0x = s02x + s13x, y0y = s02y + s13y;
            float y2x = s02x - s13x, y2y = s02y - s13y;
            float y1x = d02x + d13y, y1y = d02y - d13x;
            float y3x = d02x - d13y, y3y = d02y + d13x;
            int e = r << (2 * s4);
            float c1 = twc[e],   s1 = tws[e];
            float c2 = twc[2*e], s2 = tws[2*e];
            float c3 = twc[3*e], s3 = tws[3*e];
            cr[j0]       = y0x;                 ci[j0]       = y0y;
            cr[j0 + m]   = y1x*c1 - y1y*s1;     ci[j0 + m]   = y1x*s1 + y1y*c1;
            cr[j0 + 2*m] = y2x*c2 - y2y*s2;     ci[j0 + 2*m] = y2x*s2 + y2y*c2;
            cr[j0 + 3*m] = y3x*c3 - y3y*s3;     ci[j0 + 3*m] = y3x*s3 + y3y*c3;
        }
        __syncthreads();
    }
    #pragma unroll
    for (int kk = 0; kk < 8; ++kk) {
        int j = (kk * 32 + tt) << 1;
        float ax = cr[j], ay = ci[j], bx = cr[j+1], by = ci[j+1];
        cr[j]   = ax + bx; ci[j]   = ay + by;
        cr[j+1] = ax - bx; ci[j+1] = ay - by;
    }
    __syncthreads();
    #pragma unroll
    for (int ii = 0; ii < 16; ++ii) {
        int linear = ii * 512 + t;
        int cc = linear & 15, e = linear >> 4;
        int a = cc * CSTR + e;
        float x = re[a], y = im[a];
        float m2 = x * x + y * y;
        if (m2 > 0.0f) {
            float inv = rsqrtf(m2);
            re[a] = x * inv; im[a] = y * inv;
        } else {
            re[a] = 1.0f; im[a] = 0.0f;
        }
    }
    __syncthreads();
    #pragma unroll
    for (int kk = 0; kk < 8; ++kk) {
        int j = (kk * 32 + tt) << 1;
        float ax = cr[j], ay = ci[j], bx = cr[j+1], by = ci[j+1];
        cr[j]   = ax + bx; ci[j]   = ay + by;
        cr[j+1] = ax - bx; ci[j+1] = ay - by;
    }
    __syncthreads();
    for (int s4 = 3; s4 >= 0; --s4) {
        int log2n = 9 - 2 * s4;
        int log2m = log2n - 2;
        int m = 1 << log2m;
        #pragma unroll
        for (int kk = 0; kk < 4; ++kk) {
            int q = kk * 32 + tt;
            int r = q & (m - 1);
            int j0 = ((q >> log2m) << log2n) + r;
            float a0x = cr[j0],       a0y = ci[j0];
            float a1x = cr[j0 + m],   a1y = ci[j0 + m];
            float a2x = cr[j0 + 2*m], a2y = ci[j0 + 2*m];
            float a3x = cr[j0 + 3*m], a3y = ci[j0 + 3*m];
            int e = r << (2 * s4);
            float c1 = twc[e],   s1 = tws[e];
            float c2 = twc[2*e], s2 = tws[2*e];
            float c3 = twc[3*e], s3 = tws[3*e];
            float t1x = a1x*c1 + a1y*s1,  t1y = a1y*c1 - a1x*s1;
            float t2x = a2x*c2 + a2y*s2,  t2y = a2y*c2 - a2x*s2;
            float t3x = a3x*c3 + a3y*s3,  t3y = a3y*c3 - a3x*s3;
            float s02x = a0x + t2x, s02y = a0y + t2y;
            float d02x = a0x - t2x, d02y = a0y - t2y;
            float s13x = t1x + t3x, s13y = t1y + t3y;
            float d13x = t1x - t3x, d13y = t1y - t3y;
            cr[j0]       = s02x + s13x;   ci[j0]       = s02y + s13y;
            cr[j0 + 2*m] = s02x - s13x;   ci[j0 + 2*m] = s02y - s13y;
            cr[j0 + m]   = d02x - d13y;   ci[j0 + m]   = d02y + d13x;
            cr[j0 + 3*m] = d02x + d13y;   ci[j0 + 3*m] = d02y - d13x;
        }
        __syncthreads();
    }
    #pragma unroll
    for (int ii = 0; ii < 8; ++ii) {
        int linear = ii * 512 + t;
        int cp = linear & 7;
        int e  = linear >> 3;
        int a0 = (cp * 2) * CSTR + e;
        int a1 = a0 + CSTR;
        float4 v = make_float4(re[a0], im[a0], re[a1], im[a1]);
        *reinterpret_cast<float4*>(&base[(size_t)e * 512 + cp * 2]) = v;
    }
}

// Inverse radix-4 FFT along W + 1/(H*W) scaling + |.|^2 + horizontal blur.
// 2 rows per 256-thread block.
__global__ void k_mag_hblur(const float2* __restrict__ X, float* __restrict__ out) {
    __shared__ float re[2 * RSZ], im[2 * RSZ];
    __shared__ float twc[512], tws[512];
    int t = threadIdx.x;
    FILL_TW512(256)
    int lr = t >> 7;
    int u  = t & 127;
    int row = blockIdx.x * 2 + lr;
    const float2* p = X + (size_t)row * 512;
    float* rr = re + lr * RSZ;
    float* ri = im + lr * RSZ;
    #pragma unroll
    for (int k2 = 0; k2 < 2; ++k2) {
        int i = u * 4 + k2 * 2;
        float4 v = *reinterpret_cast<const float4*>(&p[i]);
        rr[RP(i)]     = v.x; ri[RP(i)]     = v.y;
        rr[RP(i + 1)] = v.z; ri[RP(i + 1)] = v.w;
    }
    __syncthreads();
    #pragma unroll
    for (int kk = 0; kk < 2; ++kk) {     // radix-2 first (mirror)
        int j = (kk * 128 + u) << 1;
        float ax = rr[RP(j)], ay = ri[RP(j)], bx = rr[RP(j + 1)], by = ri[RP(j + 1)];
        rr[RP(j)]     = ax + bx;  ri[RP(j)]     = ay + by;
        rr[RP(j + 1)] = ax - bx;  ri[RP(j + 1)] = ay - by;
    }
    __syncthreads();
    R4_INV(rr, ri, u, 3)  __syncthreads();
    R4_INV(rr, ri, u, 2)  __syncthreads();
    R4_INV(rr, ri, u, 1)  __syncthreads();
    R4_INV(rr, ri, u, 0)  __syncthreads();
    const float s = 3.814697265625e-06f;   // 1/262144, exact
    #pragma unroll
    for (int k4 = 0; k4 < 4; ++k4) {       // |.|^2 into ri
        int i = u * 4 + k4;
        float x = rr[RP(i)] * s, y = ri[RP(i)] * s;
        ri[RP(i)] = x * x + y * y;
    }
    __syncthreads();
    float* o = out + (size_t)row * 512;
    float4 res;
    #pragma unroll
    for (int k4 = 0; k4 < 4; ++k4) {
        int i = u * 4 + k4;
        float acc = GW2 * ri[RP(i)];
        if (i >= 1)   acc += GW1 * ri[RP(i - 1)];
        if (i >= 2)   acc += GW0 * ri[RP(i - 2)];
        if (i <= 510) acc += GW1 * ri[RP(i + 1)];
        if (i <= 509) acc += GW0 * ri[RP(i + 2)];
        ((float*)&res)[k4] = acc;
    }
    *reinterpret_cast<float4*>(o + u * 4) = res;
}

// Vertical blur + per-BLOCK min/max partials (no atomics).
__global__ void k_vblur(const float* __restrict__ in, float* __restrict__ out,
                        float* __restrict__ pmn, float* __restrict__ pmx) {
    __shared__ float smn[256];
    __shared__ float smx[256];
    int t = threadIdx.x;
    int i = blockIdx.x * 256 + t;
    int y = (i >> 9) & 511;
    float acc = GW2 * in[i];
    if (y >= 1)   acc += GW1 * in[i - 512];
    if (y >= 2)   acc += GW0 * in[i - 1024];
    if (y <= 510) acc += GW1 * in[i + 512];
    if (y <= 509) acc += GW0 * in[i + 1024];
    out[i] = acc;
    smn[t] = acc; smx[t] = acc;
    __syncthreads();
    for (int s = 128; s > 0; s >>= 1) {
        if (t < s) { smn[t] = fminf(smn[t], smn[t + s]); smx[t] = fmaxf(smx[t], smx[t + s]); }
        __syncthreads();
    }
    if (t == 0) { pmn[blockIdx.x] = smn[0]; pmx[blockIdx.x] = smx[0]; }
}

// Normalize + border mask -> final saliency (d_out), fused with hist round 1.
// Each block redundantly folds its image's 1024 min/max partials first.
__global__ void k_norm_hist(const float* __restrict__ in, const float* __restrict__ pmn,
                            const float* __restrict__ pmx, float* __restrict__ out,
                            unsigned int* __restrict__ g) {
    __shared__ unsigned int h[4096];
    __shared__ float smn[256], smx[256];
    int t = threadIdx.x;
    int b = blockIdx.x >> 5;
    int base = b * HW + (blockIdx.x & 31) * 8192;
    float lmn = INFINITY, lmx = -INFINITY;
    for (int j2 = t; j2 < 1024; j2 += 256) {
        lmn = fminf(lmn, pmn[b * 1024 + j2]);
        lmx = fmaxf(lmx, pmx[b * 1024 + j2]);
    }
    smn[t] = lmn; smx[t] = lmx;
    for (int i = t; i < 4096; i += 256) h[i] = 0u;
    __syncthreads();
    for (int s = 128; s > 0; s >>= 1) {
        if (t < s) { smn[t] = fminf(smn[t], smn[t + s]); smx[t] = fmaxf(smx[t], smx[t + s]); }
        __syncthreads();
    }
    float mn = smn[0], mx = smx[0];
    float inv = 1.0f / (mx - mn + 1e-8f);
    for (int j = 0; j < 32; ++j) {
        int idx = base + j * 256 + t;
        float v = (in[idx] - mn) * inv;
        int xx = idx & 511, yy = (idx >> 9) & 511;
        bool inside = (xx >= 12) && (xx < 500) && (yy >= 12) && (yy < 500);
        v = inside ? v : 0.0f;
        out[idx] = v;
        atomicAdd(&h[__float_as_uint(v) >> 20], 1u);
    }
    __syncthreads();
    unsigned int* gb = g + b * 4096;
    for (int i = t; i < 4096; i += 256)
        if (h[i]) atomicAdd(&gb[i], h[i]);
}

// ---------------------------------------------------------------------------
// Parallel 3-round radix select (bits 12/12/8) for BOTH k=26214 (threshold)
// and k=80 (candidate cutoff), sharing the same histogram passes.
// ---------------------------------------------------------------------------

__global__ void k_hist2(const float* __restrict__ sal,
                        const unsigned int* __restrict__ prefA,
                        const unsigned int* __restrict__ prefB,
                        unsigned int* __restrict__ gA, unsigned int* __restrict__ gB) {
    __shared__ unsigned int hA[4096];
    __shared__ unsigned int hB[4096];
    int t = threadIdx.x;
    int b = blockIdx.x >> 5;
    int start = (blockIdx.x & 31) * 8192;
    const float* p = sal + (size_t)b * HW;
    unsigned int pA = prefA[b], pB = prefB[b];
    for (int i = t; i < 4096; i += 256) { hA[i] = 0u; hB[i] = 0u; }
    __syncthreads();
    for (int j = 0; j < 32; ++j) {
        unsigned int u = __float_as_uint(p[start + j * 256 + t]);
        unsigned int hi = u >> 20, mid = (u >> 8) & 4095u;
        if (hi == pA) atomicAdd(&hA[mid], 1u);
        if (hi == pB) atomicAdd(&hB[mid], 1u);
    }
    __syncthreads();
    unsigned int* ga = gA + b * 4096;
    unsigned int* gb2 = gB + b * 4096;
    for (int i = t; i < 4096; i += 256) {
        if (hA[i]) atomicAdd(&ga[i], hA[i]);
        if (hB[i]) atomicAdd(&gb2[i], hB[i]);
    }
}

__global__ void k_hist3(const float* __restrict__ sal,
                        const unsigned int* __restrict__ prefA,
                        const unsigned int* __restrict__ prefB,
                        unsigned int* __restrict__ gA, unsigned int* __restrict__ gB) {
    __shared__ unsigned int hA[256];
    __shared__ unsigned int hB[256];
    int t = threadIdx.x;
    int b = blockIdx.x >> 5;
    int start = (blockIdx.x & 31) * 8192;
    const float* p = sal + (size_t)b * HW;
    unsigned int pA = prefA[b], pB = prefB[b];
    hA[t] = 0u; hB[t] = 0u;
    __syncthreads();
    for (int j = 0; j < 32; ++j) {
        unsigned int u = __float_as_uint(p[start + j * 256 + t]);
        unsigned int hi = u >> 8, lo = u & 255u;
        if (hi == pA) atomicAdd(&hA[lo], 1u);
        if (hi == pB) atomicAdd(&hB[lo], 1u);
    }
    __syncthreads();
    unsigned int* ga = gA + b * 256;
    unsigned int* gb2 = gB + b * 256;
    if (hA[t]) atomicAdd(&ga[t], hA[t]);
    if (hB[t]) atomicAdd(&gb2[t], hB[t]);
}

// Find bin d (from top) s.t. suffix count crosses krem.
__device__ void radix_step(const unsigned int* __restrict__ h, int nbins, int krem,
                           int t, unsigned int* tsum, int* sbin, int* skrem) {
    int bpt = nbins >> 8;
    unsigned int s = 0;
    for (int j = 0; j < bpt; ++j) s += h[t * bpt + j];
    tsum[t] = s;
    __syncthreads();
    if (t == 0) {
        unsigned int cum = 0; int seg = 0;
        for (int d = 255; d >= 0; --d) {
            unsigned int c2 = cum + tsum[d];
            if ((int)c2 >= krem) { seg = d; break; }
            cum = c2;
        }
        unsigned int c = cum;
        for (int j = bpt - 1; j >= 0; --j) {
            unsigned int hv = h[seg * bpt + j];
            if ((int)(c + hv) >= krem) { *sbin = seg * bpt + j; *skrem = krem - (int)c; break; }
            c += hv;
        }
    }
    __syncthreads();
}

__global__ void k_scan1(const unsigned int* __restrict__ g,
                        unsigned int* prefA, int* kremA, unsigned int* prefB, int* kremB) {
    __shared__ unsigned int tsum[256];
    __shared__ int sbin, skrem;
    int b = blockIdx.x, t = threadIdx.x;
    radix_step(g + b * 4096, 4096, KSEL, t, tsum, &sbin, &skrem);
    if (t == 0) { prefA[b] = (unsigned int)sbin; kremA[b] = skrem; }
    __syncthreads();
    radix_step(g + b * 4096, 4096, MCAND, t, tsum, &sbin, &skrem);
    if (t == 0) { prefB[b] = (unsigned int)sbin; kremB[b] = skrem; }
}

__global__ void k_scan2(const unsigned int* __restrict__ gA, const unsigned int* __restrict__ gB,
                        unsigned int* prefA, int* kremA, unsigned int* prefB, int* kremB) {
    __shared__ unsigned int tsum[256];
    __shared__ int sbin, skrem;
    int b = blockIdx.x, t = threadIdx.x;
    radix_step(gA + b * 4096, 4096, kremA[b], t, tsum, &sbin, &skrem);
    if (t == 0) { prefA[b] = (prefA[b] << 12) | (unsigned int)sbin; kremA[b] = skrem; }
    __syncthreads();
    radix_step(gB + b * 4096, 4096, kremB[b], t, tsum, &sbin, &skrem);
    if (t == 0) { prefB[b] = (prefB[b] << 12) | (unsigned int)sbin; kremB[b] = skrem; }
}

__global__ void k_scan3(const unsigned int* __restrict__ gA, const unsigned int* __restrict__ gB,
                        const unsigned int* prefA, const int* kremA,
                        const unsigned int* prefB, const int* kremB,
                        unsigned int* __restrict__ ucut) {
    __shared__ unsigned int tsum[256];
    __shared__ int sbin, skrem;
    __shared__ unsigned int thrbits;
    int b = blockIdx.x, t = threadIdx.x;
    radix_step(gA + b * 256, 256, kremA[b], t, tsum, &sbin, &skrem);
    if (t == 0) {
        unsigned int kth = (prefA[b] << 8) | (unsigned int)sbin;
        float thr = fmaxf(__uint_as_float(kth), 0.1f);
        thrbits = __float_as_uint(thr);
    }
    __syncthreads();
    radix_step(gB + b * 256, 256, kremB[b], t, tsum, &sbin, &skrem);
    if (t == 0) {
        unsigned int c80 = (prefB[b] << 8) | (unsigned int)sbin;
        ucut[b] = (c80 > thrbits) ? c80 : thrbits;   // uint order == float order (>=0)
    }
}

__global__ void k_collect(const float* __restrict__ sal, const unsigned int* __restrict__ ucut,
                          float* __restrict__ candv, int* __restrict__ candi,
                          int* __restrict__ ccnt) {
    int t = threadIdx.x;
    int b = blockIdx.x >> 5;
    int start = (blockIdx.x & 31) * 8192;
    const float* p = sal + (size_t)b * HW;
    unsigned int cut = ucut[b];
    for (int j = 0; j < 32; ++j) {
        int i = start + j * 256 + t;
        unsigned int u = __float_as_uint(p[i]);
        if (u >= cut) {
            int pos = atomicAdd(&ccnt[b], 1);
            if (pos < CAP) { candv[b * CAP + pos] = p[i]; candi[b * CAP + pos] = i; }
        }
    }
}

// Rank (value desc, index asc — lax.top_k tie rule), bitmask greedy NMS.
__global__ void k_final(const float* __restrict__ candv, const int* __restrict__ candi,
                        const int* __restrict__ ccnt, float* __restrict__ out) {
    __shared__ float cval[CAP];
    __shared__ int   cidx[CAP];
    __shared__ int   si[MCAND];
    __shared__ float sx[MCAND];
    __shared__ float sy[MCAND];
    __shared__ unsigned long long nearLo[MCAND];
    __shared__ unsigned long long nearHi[MCAND];
    int b = blockIdx.x, t = threadIdx.x;
    int n = min(ccnt[b], CAP);
    for (int i = t; i < n; i += 256) { cval[i] = candv[b * CAP + i]; cidx[i] = candi[b * CAP + i]; }
    __syncthreads();
    int m = min(n, MCAND);
    for (int i = t; i < n; i += 256) {
        float vi = cval[i]; int ii = cidx[i];
        int rank = 0;
        for (int j = 0; j < n; j++) {
            float vj = cval[j];
            if (vj > vi || (vj == vi && cidx[j] < ii)) rank++;
        }
        if (rank < MCAND) si[rank] = ii;
    }
    __syncthreads();
    for (int i = t; i < m; i += 256) {
        sx[i] = (float)(si[i] & 511);
        sy[i] = (float)(si[i] >> 9);
    }
    __syncthreads();
    for (int i = t; i < m; i += 256) {
        unsigned long long lo = 0ull, hi = 0ull;
        float x = sx[i], y = sy[i];
        for (int j = 0; j < m; j++) {
            float dx = sx[j] - x, dy = sy[j] - y;
            if (dx * dx + dy * dy < 100.0f) {
                if (j < 64) lo |= (1ull << j);
                else        hi |= (1ull << (j - 64));
            }
        }
        nearLo[i] = lo; nearHi[i] = hi;
    }
    __syncthreads();
    if (t == 0) {
        unsigned long long kLo = 0ull, kHi = 0ull;
        int cnt = 0;
        for (int i = 0; i < m; i++) {
            bool near_kept = ((nearLo[i] & kLo) | (nearHi[i] & kHi)) != 0ull;
            if (!near_kept) {
                out[b * 10 + 2 * cnt]     = sx[i];
                out[b * 10 + 2 * cnt + 1] = sy[i];
                out[160 + b * 5 + cnt]    = 1.0f;
                if (i < 64) kLo |= (1ull << i); else kHi |= (1ull << (i - 64));
                cnt++;
                if (cnt == TOPK) break;
            }
        }
        for (int j = cnt; j < TOPK; j++) {
            out[b * 10 + 2 * j]     = -1.0f;
            out[b * 10 + 2 * j + 1] = -1.0f;
            out[160 + b * 5 + j]    = -1.0f;
        }
    }
}

extern "C" void kernel_launch(void* const* d_in, const int* in_sizes, int n_in,
                              void* d_out, int out_size, void* d_ws, size_t ws_size,
                              hipStream_t stream) {
    const float* img = (const float*)d_in[0];
    float* out = (float*)d_out;
    char* ws = (char*)d_ws;

    float2* A    = (float2*)ws;
    float*  hb   = (float*)(ws + 33554432UL);
    float*  salb = (float*)(ws + 50331648UL);

    unsigned int* hist1  = (unsigned int*)(ws + 0UL);
    unsigned int* hist2a = (unsigned int*)(ws + 262144UL);
    unsigned int* hist2b = (unsigned int*)(ws + 524288UL);
    unsigned int* hist3a = (unsigned int*)(ws + 786432UL);
    unsigned int* hist3b = (unsigned int*)(ws + 802816UL);
    int*          ccnt   = (int*)(ws + 819200UL);
    const size_t  ZEROBYTES = 819264UL;
    float*        candv  = (float*)(ws + 851968UL);
    int*          candi  = (int*)(ws + 983040UL);

    float* pmn = (float*)(ws + 20971520UL);
    float* pmx = (float*)(ws + 21037056UL);

    char* stats = ws + 67108864UL;
    unsigned int* prefA = (unsigned int*)(stats + 0);
    int*          kremA = (int*)(stats + 64);
    unsigned int* prefB = (unsigned int*)(stats + 128);
    int*          kremB = (int*)(stats + 192);
    unsigned int* ucut  = (unsigned int*)(stats + 256);

    float* salout = out + 240;   // sal region of d_out

    k_win_rowfft<<<dim3(4096), dim3(256), 0, stream>>>(img, A);     // radix-4 W fwd
    k_colfft<<<dim3(512), dim3(512), 0, stream>>>(A);               // radix-4 H pass
    k_mag_hblur<<<dim3(4096), dim3(256), 0, stream>>>(A, hb);       // radix-4 W inv + mag + hblur
    k_vblur<<<dim3(16384), dim3(256), 0, stream>>>(hb, salb, pmn, pmx);
    hipMemsetAsync(ws, 0, ZEROBYTES, stream);
    k_norm_hist<<<dim3(512), dim3(256), 0, stream>>>(salb, pmn, pmx, salout, hist1);
    k_scan1<<<dim3(BATCH), dim3(256), 0, stream>>>(hist1, prefA, kremA, prefB, kremB);
    k_hist2<<<dim3(512), dim3(256), 0, stream>>>(salout, prefA, prefB, hist2a, hist2b);
    k_scan2<<<dim3(BATCH), dim3(256), 0, stream>>>(hist2a, hist2b, prefA, kremA, prefB, kremB);
    k_hist3<<<dim3(512), dim3(256), 0, stream>>>(salout, prefA, prefB, hist3a, hist3b);
    k_scan3<<<dim3(BATCH), dim3(256), 0, stream>>>(hist3a, hist3b, prefA, kremA, prefB, kremB, ucut);
    k_collect<<<dim3(512), dim3(256), 0, stream>>>(salout, ucut, candv, candi, ccnt);
    k_final<<<dim3(BATCH), dim3(256), 0, stream>>>(candv, candi, ccnt, out);
}

// Round 10
// 200.934 us; speedup vs baseline: 1.3034x; 1.1570x over previous
//
#include <hip/hip_runtime.h>
#include <math.h>

#define BATCH 16
#define HW 262144          // 512*512
#define KSEL 26214         // int(0.1 * 262144)
#define MCAND 80           // TOP_K * CAND_MULT
#define TOPK 5
#define CAP 2048

// ---------------------------------------------------------------------------
// In-place FFT, N=512, mixed radix-4 (4 stages) + radix-2 (1 stage) on all
// axes. Forward DIF: natural -> digit-reversed; inverse DIT (conj twiddles,
// mirrored stage order): digit-reversed -> natural. DIT(DIF(x)) = 512*x
// elementwise, so the digit-reversed intermediate order is unobservable
// (phase normalize is elementwise; axes independent).
// Twiddles from LDS table tw[i] = e^{-2*pi*i/512} (tw[i+256] = -tw[i]).
// ---------------------------------------------------------------------------

// Gaussian blur coefficients, sigma=1, 5-tap.
#define GW0 0.05448868454964294f
#define GW1 0.24420134200323332f
#define GW2 0.40261994689424746f

#define FILL_TW512(nthr)                                       \
    for (int i_ = threadIdx.x; i_ < 256; i_ += (nthr)) {       \
        float rev_ = -(float)i_ * (1.0f / 512.0f);             \
        float s_ = __builtin_amdgcn_sinf(rev_);                \
        float c_ = __builtin_amdgcn_cosf(rev_);                \
        tws[i_] = s_;        twc[i_] = c_;                     \
        tws[i_ + 256] = -s_; twc[i_ + 256] = -c_;              \
    }

// LDS pad-every-16: breaks power-of-2 stride conflicts (<=4-way worst).
#define RP(a) ((a) + ((a) >> 4))
#define RSZ 544             // 512 + 32 pad floats per row

// Radix-4 DIF forward butterfly (1 per thread), q = butterfly idx 0..127.
#define R4_FWD(rr, ri, q, s4)                                                 \
    {                                                                          \
        const int log2n = 9 - 2 * (s4);                                        \
        const int log2m = log2n - 2;                                           \
        const int m = 1 << log2m;                                              \
        int r = (q) & (m - 1);                                                 \
        int j0 = (((q) >> log2m) << log2n) + r;                                \
        float a0x = rr[RP(j0)],       a0y = ri[RP(j0)];                        \
        float a1x = rr[RP(j0 + m)],   a1y = ri[RP(j0 + m)];                    \
        float a2x = rr[RP(j0 + 2*m)], a2y = ri[RP(j0 + 2*m)];                  \
        float a3x = rr[RP(j0 + 3*m)], a3y = ri[RP(j0 + 3*m)];                  \
        float s02x = a0x + a2x, s02y = a0y + a2y;                              \
        float d02x = a0x - a2x, d02y = a0y - a2y;                              \
        float s13x = a1x + a3x, s13y = a1y + a3y;                              \
        float d13x = a1x - a3x, d13y = a1y - a3y;                              \
        float y0x = s02x + s13x, y0y = s02y + s13y;                            \
        float y2x = s02x - s13x, y2y = s02y - s13y;                            \
        float y1x = d02x + d13y, y1y = d02y - d13x;                            \
        float y3x = d02x - d13y, y3y = d02y + d13x;                            \
        int e = r << (2 * (s4));                                               \
        float c1 = twc[e],   s1 = tws[e];                                      \
        float c2 = twc[2*e], s2 = tws[2*e];                                    \
        float c3 = twc[3*e], s3 = tws[3*e];                                    \
        rr[RP(j0)]       = y0x;             ri[RP(j0)]       = y0y;            \
        rr[RP(j0 + m)]   = y1x*c1 - y1y*s1; ri[RP(j0 + m)]   = y1x*s1 + y1y*c1;\
        rr[RP(j0 + 2*m)] = y2x*c2 - y2y*s2; ri[RP(j0 + 2*m)] = y2x*s2 + y2y*c2;\
        rr[RP(j0 + 3*m)] = y3x*c3 - y3y*s3; ri[RP(j0 + 3*m)] = y3x*s3 + y3y*c3;\
    }

// Radix-4 DIT inverse butterfly (conj twiddles), mirror of R4_FWD.
#define R4_INV(rr, ri, q, s4)                                                 \
    {                                                                          \
        const int log2n = 9 - 2 * (s4);                                        \
        const int log2m = log2n - 2;                                           \
        const int m = 1 << log2m;                                              \
        int r = (q) & (m - 1);                                                 \
        int j0 = (((q) >> log2m) << log2n) + r;                                \
        float a0x = rr[RP(j0)],       a0y = ri[RP(j0)];                        \
        float a1x = rr[RP(j0 + m)],   a1y = ri[RP(j0 + m)];                    \
        float a2x = rr[RP(j0 + 2*m)], a2y = ri[RP(j0 + 2*m)];                  \
        float a3x = rr[RP(j0 + 3*m)], a3y = ri[RP(j0 + 3*m)];                  \
        int e = r << (2 * (s4));                                               \
        float c1 = twc[e],   s1 = tws[e];                                      \
        float c2 = twc[2*e], s2 = tws[2*e];                                    \
        float c3 = twc[3*e], s3 = tws[3*e];                                    \
        float t1x = a1x*c1 + a1y*s1,  t1y = a1y*c1 - a1x*s1;                   \
        float t2x = a2x*c2 + a2y*s2,  t2y = a2y*c2 - a2x*s2;                   \
        float t3x = a3x*c3 + a3y*s3,  t3y = a3y*c3 - a3x*s3;                   \
        float s02x = a0x + t2x, s02y = a0y + t2y;                              \
        float d02x = a0x - t2x, d02y = a0y - t2y;                              \
        float s13x = t1x + t3x, s13y = t1y + t3y;                              \
        float d13x = t1x - t3x, d13y = t1y - t3y;                              \
        rr[RP(j0)]       = s02x + s13x;  ri[RP(j0)]       = s02y + s13y;       \
        rr[RP(j0 + 2*m)] = s02x - s13x;  ri[RP(j0 + 2*m)] = s02y - s13y;       \
        rr[RP(j0 + m)]   = d02x - d13y;  ri[RP(j0 + m)]   = d02y + d13x;       \
        rr[RP(j0 + 3*m)] = d02x + d13y;  ri[RP(j0 + 3*m)] = d02y - d13x;       \
    }

// K1: window + forward radix-4 FFT along W. 2 rows per 256-thread block.
__global__ void k_win_rowfft(const float* __restrict__ img, float2* __restrict__ A) {
    __shared__ float re[2 * RSZ], im[2 * RSZ];
    __shared__ float twc[512], tws[512];
    int t = threadIdx.x;
    FILL_TW512(256)
    int lr = t >> 7;                 // local row 0/1
    int u  = t & 127;                // per-row lane
    int row = blockIdx.x * 2 + lr;   // b*512 + h
    int h = row & 511;
    float wr = 0.5f * (1.0f - __builtin_amdgcn_cosf((float)h * (1.0f / 511.0f)));
    const float* p = img + (size_t)row * 512;
    float* rr = re + lr * RSZ;
    float* ri = im + lr * RSZ;
    {
        int i0 = u * 4;
        float4 v = *reinterpret_cast<const float4*>(p + i0);
        float w0 = 0.5f * (1.0f - __builtin_amdgcn_cosf((float)(i0 + 0) * (1.0f / 511.0f)));
        float w1 = 0.5f * (1.0f - __builtin_amdgcn_cosf((float)(i0 + 1) * (1.0f / 511.0f)));
        float w2 = 0.5f * (1.0f - __builtin_amdgcn_cosf((float)(i0 + 2) * (1.0f / 511.0f)));
        float w3 = 0.5f * (1.0f - __builtin_amdgcn_cosf((float)(i0 + 3) * (1.0f / 511.0f)));
        rr[RP(i0 + 0)] = v.x * wr * w0;  ri[RP(i0 + 0)] = 0.0f;
        rr[RP(i0 + 1)] = v.y * wr * w1;  ri[RP(i0 + 1)] = 0.0f;
        rr[RP(i0 + 2)] = v.z * wr * w2;  ri[RP(i0 + 2)] = 0.0f;
        rr[RP(i0 + 3)] = v.w * wr * w3;  ri[RP(i0 + 3)] = 0.0f;
    }
    __syncthreads();
    R4_FWD(rr, ri, u, 0)  __syncthreads();
    R4_FWD(rr, ri, u, 1)  __syncthreads();
    R4_FWD(rr, ri, u, 2)  __syncthreads();
    R4_FWD(rr, ri, u, 3)  __syncthreads();
    #pragma unroll
    for (int kk = 0; kk < 2; ++kk) {     // final radix-2 (2 butterflies/thread)
        int j = (kk * 128 + u) << 1;
        float ax = rr[RP(j)], ay = ri[RP(j)], bx = rr[RP(j + 1)], by = ri[RP(j + 1)];
        rr[RP(j)]     = ax + bx;  ri[RP(j)]     = ay + by;
        rr[RP(j + 1)] = ax - bx;  ri[RP(j + 1)] = ay - by;
    }
    __syncthreads();
    float2* out = A + (size_t)row * 512;
    #pragma unroll
    for (int k2 = 0; k2 < 2; ++k2) {
        int i = u * 4 + k2 * 2;
        float4 v = make_float4(rr[RP(i)], ri[RP(i)], rr[RP(i + 1)], ri[RP(i + 1)]);
        *reinterpret_cast<float4*>(&out[i]) = v;
    }
}

// Fused H-axis pass on 512x16 column tiles, radix-4.
#define CSTR 514
__global__ __launch_bounds__(512) void k_colfft(float2* __restrict__ X) {
    __shared__ float re[16 * CSTR];
    __shared__ float im[16 * CSTR];
    __shared__ float twc[512], tws[512];
    int b = blockIdx.x >> 5;
    int c0 = (blockIdx.x & 31) * 16;
    int t = threadIdx.x;
    FILL_TW512(512)
    float2* base = X + (size_t)b * HW + c0;
    #pragma unroll
    for (int ii = 0; ii < 8; ++ii) {
        int linear = ii * 512 + t;
        int cp = linear & 7;
        int e  = linear >> 3;
        const float4 v = *reinterpret_cast<const float4*>(&base[(size_t)e * 512 + cp * 2]);
        int a0 = (cp * 2) * CSTR + e;
        int a1 = a0 + CSTR;
        re[a0] = v.x; im[a0] = v.y;
        re[a1] = v.z; im[a1] = v.w;
    }
    __syncthreads();
    int c = t & 15, tt = t >> 4;
    float* cr = re + c * CSTR;
    float* ci = im + c * CSTR;

    for (int s4 = 0; s4 < 4; ++s4) {
        int log2n = 9 - 2 * s4;
        int log2m = log2n - 2;
        int m = 1 << log2m;
        #pragma unroll
        for (int kk = 0; kk < 4; ++kk) {
            int q = kk * 32 + tt;
            int r = q & (m - 1);
            int j0 = ((q >> log2m) << log2n) + r;
            float a0x = cr[j0],       a0y = ci[j0];
            float a1x = cr[j0 + m],   a1y = ci[j0 + m];
            float a2x = cr[j0 + 2*m], a2y = ci[j0 + 2*m];
            float a3x = cr[j0 + 3*m], a3y = ci[j0 + 3*m];
            float s02x = a0x + a2x, s02y = a0y + a2y;
            float d02x = a0x - a2x, d02y = a0y - a2y;
            float s13x = a1x + a3x, s13y = a1y + a3y;
            float d13x = a1x - a3x, d13y = a1y - a3y;
            float y0x = s02x + s13x, y0y = s02y + s13y;
            float y2x = s02x - s13x, y2y = s02y - s13y;
            float y1x = d02x + d13y, y1y = d02y - d13x;
            float y3x = d02x - d13y, y3y = d02y + d13x;
            int e = r << (2 * s4);
            float c1 = twc[e],   s1 = tws[e];
            float c2 = twc[2*e], s2 = tws[2*e];
            float c3 = twc[3*e], s3 = tws[3*e];
            cr[j0]       = y0x;                 ci[j0]       = y0y;
            cr[j0 + m]   = y1x*c1 - y1y*s1;     ci[j0 + m]   = y1x*s1 + y1y*c1;
            cr[j0 + 2*m] = y2x*c2 - y2y*s2;     ci[j0 + 2*m] = y2x*s2 + y2y*c2;
            cr[j0 + 3*m] = y3x*c3 - y3y*s3;     ci[j0 + 3*m] = y3x*s3 + y3y*c3;
        }
        __syncthreads();
    }
    #pragma unroll
    for (int kk = 0; kk < 8; ++kk) {
        int j = (kk * 32 + tt) << 1;
        float ax = cr[j], ay = ci[j], bx = cr[j+1], by = ci[j+1];
        cr[j]   = ax + bx; ci[j]   = ay + by;
        cr[j+1] = ax - bx; ci[j+1] = ay - by;
    }
    __syncthreads();
    #pragma unroll
    for (int ii = 0; ii < 16; ++ii) {
        int linear = ii * 512 + t;
        int cc = linear & 15, e = linear >> 4;
        int a = cc * CSTR + e;
        float x = re[a], y = im[a];
        float m2 = x * x + y * y;
        if (m2 > 0.0f) {
            float inv = rsqrtf(m2);
            re[a] = x * inv; im[a] = y * inv;
        } else {
            re[a] = 1.0f; im[a] = 0.0f;
        }
    }
    __syncthreads();
    #pragma unroll
    for (int kk = 0; kk < 8; ++kk) {
        int j = (kk * 32 + tt) << 1;
        float ax = cr[j], ay = ci[j], bx = cr[j+1], by = ci[j+1];
        cr[j]   = ax + bx; ci[j]   = ay + by;
        cr[j+1] = ax - bx; ci[j+1] = ay - by;
    }
    __syncthreads();
    for (int s4 = 3; s4 >= 0; --s4) {
        int log2n = 9 - 2 * s4;
        int log2m = log2n - 2;
        int m = 1 << log2m;
        #pragma unroll
        for (int kk = 0; kk < 4; ++kk) {
            int q = kk * 32 + tt;
            int r = q & (m - 1);
            int j0 = ((q >> log2m) << log2n) + r;
            float a0x = cr[j0],       a0y = ci[j0];
            float a1x = cr[j0 + m],   a1y = ci[j0 + m];
            float a2x = cr[j0 + 2*m], a2y = ci[j0 + 2*m];
            float a3x = cr[j0 + 3*m], a3y = ci[j0 + 3*m];
            int e = r << (2 * s4);
            float c1 = twc[e],   s1 = tws[e];
            float c2 = twc[2*e], s2 = tws[2*e];
            float c3 = twc[3*e], s3 = tws[3*e];
            float t1x = a1x*c1 + a1y*s1,  t1y = a1y*c1 - a1x*s1;
            float t2x = a2x*c2 + a2y*s2,  t2y = a2y*c2 - a2x*s2;
            float t3x = a3x*c3 + a3y*s3,  t3y = a3y*c3 - a3x*s3;
            float s02x = a0x + t2x, s02y = a0y + t2y;
            float d02x = a0x - t2x, d02y = a0y - t2y;
            float s13x = t1x + t3x, s13y = t1y + t3y;
            float d13x = t1x - t3x, d13y = t1y - t3y;
            cr[j0]       = s02x + s13x;   ci[j0]       = s02y + s13y;
            cr[j0 + 2*m] = s02x - s13x;   ci[j0 + 2*m] = s02y - s13y;
            cr[j0 + m]   = d02x - d13y;   ci[j0 + m]   = d02y + d13x;
            cr[j0 + 3*m] = d02x + d13y;   ci[j0 + 3*m] = d02y - d13x;
        }
        __syncthreads();
    }
    #pragma unroll
    for (int ii = 0; ii < 8; ++ii) {
        int linear = ii * 512 + t;
        int cp = linear & 7;
        int e  = linear >> 3;
        int a0 = (cp * 2) * CSTR + e;
        int a1 = a0 + CSTR;
        float4 v = make_float4(re[a0], im[a0], re[a1], im[a1]);
        *reinterpret_cast<float4*>(&base[(size_t)e * 512 + cp * 2]) = v;
    }
}

// Inverse radix-4 FFT along W + 1/(H*W) scaling + |.|^2 + horizontal blur.
__global__ void k_mag_hblur(const float2* __restrict__ X, float* __restrict__ out) {
    __shared__ float re[2 * RSZ], im[2 * RSZ];
    __shared__ float twc[512], tws[512];
    int t = threadIdx.x;
    FILL_TW512(256)
    int lr = t >> 7;
    int u  = t & 127;
    int row = blockIdx.x * 2 + lr;
    const float2* p = X + (size_t)row * 512;
    float* rr = re + lr * RSZ;
    float* ri = im + lr * RSZ;
    #pragma unroll
    for (int k2 = 0; k2 < 2; ++k2) {
        int i = u * 4 + k2 * 2;
        float4 v = *reinterpret_cast<const float4*>(&p[i]);
        rr[RP(i)]     = v.x; ri[RP(i)]     = v.y;
        rr[RP(i + 1)] = v.z; ri[RP(i + 1)] = v.w;
    }
    __syncthreads();
    #pragma unroll
    for (int kk = 0; kk < 2; ++kk) {     // radix-2 first (mirror)
        int j = (kk * 128 + u) << 1;
        float ax = rr[RP(j)], ay = ri[RP(j)], bx = rr[RP(j + 1)], by = ri[RP(j + 1)];
        rr[RP(j)]     = ax + bx;  ri[RP(j)]     = ay + by;
        rr[RP(j + 1)] = ax - bx;  ri[RP(j + 1)] = ay - by;
    }
    __syncthreads();
    R4_INV(rr, ri, u, 3)  __syncthreads();
    R4_INV(rr, ri, u, 2)  __syncthreads();
    R4_INV(rr, ri, u, 1)  __syncthreads();
    R4_INV(rr, ri, u, 0)  __syncthreads();
    const float s = 3.814697265625e-06f;   // 1/262144, exact
    #pragma unroll
    for (int k4 = 0; k4 < 4; ++k4) {       // |.|^2 into ri
        int i = u * 4 + k4;
        float x = rr[RP(i)] * s, y = ri[RP(i)] * s;
        ri[RP(i)] = x * x + y * y;
    }
    __syncthreads();
    float* o = out + (size_t)row * 512;
    float4 res;
    #pragma unroll
    for (int k4 = 0; k4 < 4; ++k4) {
        int i = u * 4 + k4;
        float acc = GW2 * ri[RP(i)];
        if (i >= 1)   acc += GW1 * ri[RP(i - 1)];
        if (i >= 2)   acc += GW0 * ri[RP(i - 2)];
        if (i <= 510) acc += GW1 * ri[RP(i + 1)];
        if (i <= 509) acc += GW0 * ri[RP(i + 2)];
        ((float*)&res)[k4] = acc;
    }
    *reinterpret_cast<float4*>(o + u * 4) = res;
}

// Vertical blur (float4, 4 elems/thread) + per-BLOCK min/max partials.
__global__ void k_vblur(const float* __restrict__ in, float* __restrict__ out,
                        float* __restrict__ pmn, float* __restrict__ pmx) {
    __shared__ float smn[256];
    __shared__ float smx[256];
    int t = threadIdx.x;
    int i = (blockIdx.x * 256 + t) * 4;
    int y = (i >> 9) & 511;               // same row for all 4 elems (4 | 512)
    const float4 c = *reinterpret_cast<const float4*>(in + i);
    float4 acc = make_float4(GW2 * c.x, GW2 * c.y, GW2 * c.z, GW2 * c.w);
    if (y >= 1) {
        const float4 v = *reinterpret_cast<const float4*>(in + i - 512);
        acc.x += GW1 * v.x; acc.y += GW1 * v.y; acc.z += GW1 * v.z; acc.w += GW1 * v.w;
    }
    if (y >= 2) {
        const float4 v = *reinterpret_cast<const float4*>(in + i - 1024);
        acc.x += GW0 * v.x; acc.y += GW0 * v.y; acc.z += GW0 * v.z; acc.w += GW0 * v.w;
    }
    if (y <= 510) {
        const float4 v = *reinterpret_cast<const float4*>(in + i + 512);
        acc.x += GW1 * v.x; acc.y += GW1 * v.y; acc.z += GW1 * v.z; acc.w += GW1 * v.w;
    }
    if (y <= 509) {
        const float4 v = *reinterpret_cast<const float4*>(in + i + 1024);
        acc.x += GW0 * v.x; acc.y += GW0 * v.y; acc.z += GW0 * v.z; acc.w += GW0 * v.w;
    }
    *reinterpret_cast<float4*>(out + i) = acc;
    float lmn = fminf(fminf(acc.x, acc.y), fminf(acc.z, acc.w));
    float lmx = fmaxf(fmaxf(acc.x, acc.y), fmaxf(acc.z, acc.w));
    smn[t] = lmn; smx[t] = lmx;
    __syncthreads();
    for (int s = 128; s > 0; s >>= 1) {
        if (t < s) { smn[t] = fminf(smn[t], smn[t + s]); smx[t] = fmaxf(smx[t], smx[t + s]); }
        __syncthreads();
    }
    if (t == 0) { pmn[blockIdx.x] = smn[0]; pmx[blockIdx.x] = smx[0]; }
}

// Normalize + border mask -> final saliency (d_out), fused with hist round 1.
// Each block redundantly folds its image's 256 min/max partials first.
__global__ void k_norm_hist(const float* __restrict__ in, const float* __restrict__ pmn,
                            const float* __restrict__ pmx, float* __restrict__ out,
                            unsigned int* __restrict__ g) {
    __shared__ unsigned int h[4096];
    __shared__ float smn[256], smx[256];
    int t = threadIdx.x;
    int b = blockIdx.x >> 5;
    int base = b * HW + (blockIdx.x & 31) * 8192;
    smn[t] = pmn[b * 256 + t];
    smx[t] = pmx[b * 256 + t];
    for (int i = t; i < 4096; i += 256) h[i] = 0u;
    __syncthreads();
    for (int s = 128; s > 0; s >>= 1) {
        if (t < s) { smn[t] = fminf(smn[t], smn[t + s]); smx[t] = fmaxf(smx[t], smx[t + s]); }
        __syncthreads();
    }
    float mn = smn[0], mx = smx[0];
    float inv = 1.0f / (mx - mn + 1e-8f);
    for (int j = 0; j < 32; ++j) {
        int idx = base + j * 256 + t;
        float v = (in[idx] - mn) * inv;
        int xx = idx & 511, yy = (idx >> 9) & 511;
        bool inside = (xx >= 12) && (xx < 500) && (yy >= 12) && (yy < 500);
        v = inside ? v : 0.0f;
        out[idx] = v;
        atomicAdd(&h[__float_as_uint(v) >> 20], 1u);
    }
    __syncthreads();
    unsigned int* gb = g + b * 4096;
    for (int i = t; i < 4096; i += 256)
        if (h[i]) atomicAdd(&gb[i], h[i]);
}

// Find bin d (from top) s.t. suffix count crosses krem.
__device__ void radix_step(const unsigned int* __restrict__ h, int nbins, int krem,
                           int t, unsigned int* tsum, int* sbin, int* skrem) {
    int bpt = nbins >> 8;
    unsigned int s = 0;
    for (int j = 0; j < bpt; ++j) s += h[t * bpt + j];
    tsum[t] = s;
    __syncthreads();
    if (t == 0) {
        unsigned int cum = 0; int seg = 0;
        for (int d = 255; d >= 0; --d) {
            unsigned int c2 = cum + tsum[d];
            if ((int)c2 >= krem) { seg = d; break; }
            cum = c2;
        }
        unsigned int c = cum;
        for (int j = bpt - 1; j >= 0; --j) {
            unsigned int hv = h[seg * bpt + j];
            if ((int)(c + hv) >= krem) { *sbin = seg * bpt + j; *skrem = krem - (int)c; break; }
            c += hv;
        }
    }
    __syncthreads();
}

// Round-2 histograms, with round-1 scan fused (redundant per block; integer
// ops -> identical result in every block). Designated blocks publish stats.
__global__ void k_hist2(const float* __restrict__ sal, const unsigned int* __restrict__ g1,
                        unsigned int* __restrict__ gA, unsigned int* __restrict__ gB,
                        unsigned int* prefA1, int* kremA1, unsigned int* prefB1, int* kremB1) {
    __shared__ unsigned int hA[4096];
    __shared__ unsigned int hB[4096];
    __shared__ unsigned int tsum[256];
    __shared__ int sbin, skrem;
    int t = threadIdx.x;
    int b = blockIdx.x >> 5;
    int start = (blockIdx.x & 31) * 8192;
    for (int i = t; i < 4096; i += 256) { hA[i] = 0u; hB[i] = 0u; }
    radix_step(g1 + b * 4096, 4096, KSEL, t, tsum, &sbin, &skrem);
    unsigned int pA = (unsigned int)sbin; int krA = skrem;
    radix_step(g1 + b * 4096, 4096, MCAND, t, tsum, &sbin, &skrem);
    unsigned int pB = (unsigned int)sbin; int krB = skrem;
    if (t == 0 && (blockIdx.x & 31) == 0) {
        prefA1[b] = pA; kremA1[b] = krA; prefB1[b] = pB; kremB1[b] = krB;
    }
    const float* p = sal + (size_t)b * HW;
    for (int j = 0; j < 32; ++j) {
        unsigned int u = __float_as_uint(p[start + j * 256 + t]);
        unsigned int hi = u >> 20, mid = (u >> 8) & 4095u;
        if (hi == pA) atomicAdd(&hA[mid], 1u);
        if (hi == pB) atomicAdd(&hB[mid], 1u);
    }
    __syncthreads();
    unsigned int* ga = gA + b * 4096;
    unsigned int* gb2 = gB + b * 4096;
    for (int i = t; i < 4096; i += 256) {
        if (hA[i]) atomicAdd(&ga[i], hA[i]);
        if (hB[i]) atomicAdd(&gb2[i], hB[i]);
    }
}

// Round-3 A-histogram + candidate collection, with round-2 scan fused.
// cutoffB = bucket floor of the unfiltered 80th value: every top-80 candidate
// is >= it; sub-thr extras are filtered exactly in k_final.
__global__ void k_hist3collect(const float* __restrict__ sal,
                               const unsigned int* __restrict__ gA2, const unsigned int* __restrict__ gB2,
                               const unsigned int* prefA1, const int* kremA1,
                               const unsigned int* prefB1, const int* kremB1,
                               unsigned int* __restrict__ gA3,
                               unsigned int* prefA24, int* kremA2,
                               float* __restrict__ candv, int* __restrict__ candi,
                               int* __restrict__ ccnt) {
    __shared__ unsigned int hA[256];
    __shared__ unsigned int tsum[256];
    __shared__ int sbin, skrem;
    int t = threadIdx.x;
    int b = blockIdx.x >> 5;
    int start = (blockIdx.x & 31) * 8192;
    hA[t] = 0u;
    radix_step(gA2 + b * 4096, 4096, kremA1[b], t, tsum, &sbin, &skrem);
    unsigned int pA = (prefA1[b] << 12) | (unsigned int)sbin;
    int krA2 = skrem;
    radix_step(gB2 + b * 4096, 4096, kremB1[b], t, tsum, &sbin, &skrem);
    unsigned int cutB = ((prefB1[b] << 12) | (unsigned int)sbin) << 8;
    if (t == 0 && (blockIdx.x & 31) == 0) { prefA24[b] = pA; kremA2[b] = krA2; }
    const float* p = sal + (size_t)b * HW;
    for (int j = 0; j < 32; ++j) {
        int i = start + j * 256 + t;
        unsigned int u = __float_as_uint(p[i]);
        if ((u >> 8) == pA) atomicAdd(&hA[u & 255u], 1u);
        if (u >= cutB) {
            int pos = atomicAdd(&ccnt[b], 1);
            if (pos < CAP) { candv[b * CAP + pos] = p[i]; candi[b * CAP + pos] = i; }
        }
    }
    __syncthreads();
    if (hA[t]) atomicAdd(&gA3[b * 256 + t], hA[t]);
}

// Final: derive exact thr from hist3a, rank (value desc, index asc), bitmask
// greedy NMS with validity v >= thr (matches reference -inf filtering).
__global__ void k_final(const unsigned int* __restrict__ gA3,
                        const unsigned int* prefA24, const int* kremA2,
                        const float* __restrict__ candv, const int* __restrict__ candi,
                        const int* __restrict__ ccnt, float* __restrict__ out) {
    __shared__ float cval[CAP];
    __shared__ int   cidx[CAP];
    __shared__ int   si[MCAND];
    __shared__ float svv[MCAND];
    __shared__ float sx[MCAND];
    __shared__ float sy[MCAND];
    __shared__ unsigned long long nearLo[MCAND];
    __shared__ unsigned long long nearHi[MCAND];
    __shared__ unsigned int tsum[256];
    __shared__ int sbin, skrem;
    int b = blockIdx.x, t = threadIdx.x;
    radix_step(gA3 + b * 256, 256, kremA2[b], t, tsum, &sbin, &skrem);
    float thr = fmaxf(__uint_as_float((prefA24[b] << 8) | (unsigned int)sbin), 0.1f);
    int n = min(ccnt[b], CAP);
    for (int i = t; i < n; i += 256) { cval[i] = candv[b * CAP + i]; cidx[i] = candi[b * CAP + i]; }
    __syncthreads();
    int m = min(n, MCAND);
    for (int i = t; i < n; i += 256) {
        float vi = cval[i]; int ii = cidx[i];
        int rank = 0;
        for (int j = 0; j < n; j++) {
            float vj = cval[j];
            if (vj > vi || (vj == vi && cidx[j] < ii)) rank++;
        }
        if (rank < MCAND) { si[rank] = ii; svv[rank] = vi; }
    }
    __syncthreads();
    for (int i = t; i < m; i += 256) {
        sx[i] = (float)(si[i] & 511);
        sy[i] = (float)(si[i] >> 9);
    }
    __syncthreads();
    for (int i = t; i < m; i += 256) {
        unsigned long long lo = 0ull, hi = 0ull;
        float x = sx[i], y = sy[i];
        for (int j = 0; j < m; j++) {
            float dx = sx[j] - x, dy = sy[j] - y;
            if (dx * dx + dy * dy < 100.0f) {
                if (j < 64) lo |= (1ull << j);
                else        hi |= (1ull << (j - 64));
            }
        }
        nearLo[i] = lo; nearHi[i] = hi;
    }
    __syncthreads();
    if (t == 0) {
        unsigned long long kLo = 0ull, kHi = 0ull;
        int cnt = 0;
        for (int i = 0; i < m; i++) {
            bool near_kept = ((nearLo[i] & kLo) | (nearHi[i] & kHi)) != 0ull;
            if (svv[i] >= thr && !near_kept) {
                out[b * 10 + 2 * cnt]     = sx[i];
                out[b * 10 + 2 * cnt + 1] = sy[i];
                out[160 + b * 5 + cnt]    = 1.0f;
                if (i < 64) kLo |= (1ull << i); else kHi |= (1ull << (i - 64));
                cnt++;
                if (cnt == TOPK) break;
            }
        }
        for (int j = cnt; j < TOPK; j++) {
            out[b * 10 + 2 * j]     = -1.0f;
            out[b * 10 + 2 * j + 1] = -1.0f;
            out[160 + b * 5 + j]    = -1.0f;
        }
    }
}

extern "C" void kernel_launch(void* const* d_in, const int* in_sizes, int n_in,
                              void* d_out, int out_size, void* d_ws, size_t ws_size,
                              hipStream_t stream) {
    const float* img = (const float*)d_in[0];
    float* out = (float*)d_out;
    char* ws = (char*)d_ws;

    float2* A    = (float2*)ws;
    float*  hb   = (float*)(ws + 33554432UL);
    float*  salb = (float*)(ws + 50331648UL);

    unsigned int* hist1  = (unsigned int*)(ws + 0UL);
    unsigned int* hist2a = (unsigned int*)(ws + 262144UL);
    unsigned int* hist2b = (unsigned int*)(ws + 524288UL);
    unsigned int* hist3a = (unsigned int*)(ws + 786432UL);
    int*          ccnt   = (int*)(ws + 819200UL);
    const size_t  ZEROBYTES = 819264UL;
    float*        candv  = (float*)(ws + 851968UL);
    int*          candi  = (int*)(ws + 983040UL);

    float* pmn = (float*)(ws + 20971520UL);                 // 4096 f32
    float* pmx = (float*)(ws + 21037056UL);                 // 4096 f32

    char* stats = ws + 67108864UL;
    unsigned int* prefA1  = (unsigned int*)(stats + 0);
    int*          kremA1  = (int*)(stats + 64);
    unsigned int* prefB1  = (unsigned int*)(stats + 128);
    int*          kremB1  = (int*)(stats + 192);
    unsigned int* prefA24 = (unsigned int*)(stats + 256);
    int*          kremA2  = (int*)(stats + 320);

    float* salout = out + 240;   // sal region of d_out

    k_win_rowfft<<<dim3(4096), dim3(256), 0, stream>>>(img, A);     // radix-4 W fwd
    k_colfft<<<dim3(512), dim3(512), 0, stream>>>(A);               // radix-4 H pass
    k_mag_hblur<<<dim3(4096), dim3(256), 0, stream>>>(A, hb);       // radix-4 W inv + mag + hblur
    k_vblur<<<dim3(4096), dim3(256), 0, stream>>>(hb, salb, pmn, pmx);
    hipMemsetAsync(ws, 0, ZEROBYTES, stream);
    k_norm_hist<<<dim3(512), dim3(256), 0, stream>>>(salb, pmn, pmx, salout, hist1);
    k_hist2<<<dim3(512), dim3(256), 0, stream>>>(salout, hist1, hist2a, hist2b,
                                                 prefA1, kremA1, prefB1, kremB1);
    k_hist3collect<<<dim3(512), dim3(256), 0, stream>>>(salout, hist2a, hist2b,
                                                        prefA1, kremA1, prefB1, kremB1,
                                                        hist3a, prefA24, kremA2,
                                                        candv, candi, ccnt);
    k_final<<<dim3(BATCH), dim3(256), 0, stream>>>(hist3a, prefA24, kremA2,
                                                   candv, candi, ccnt, out);
}

// Round 11
// 198.747 us; speedup vs baseline: 1.3178x; 1.0110x over previous
//
#include <hip/hip_runtime.h>
#include <math.h>

#define BATCH 16
#define HW 262144          // 512*512
#define KSEL 26214         // int(0.1 * 262144)
#define MCAND 80           // TOP_K * CAND_MULT
#define TOPK 5
#define CAP 2048
#define ZEROWORDS 204816   // (hists + ccnt) bytes / 4, zeroed inside k_vblur

// ---------------------------------------------------------------------------
// In-place FFT, N=512, mixed radix-4 (4 stages) + radix-2 (1 stage) on all
// axes. Forward DIF: natural -> digit-reversed; inverse DIT (conj twiddles,
// mirrored stage order): digit-reversed -> natural. DIT(DIF(x)) = 512*x
// elementwise, so the digit-reversed intermediate order is unobservable
// (phase normalize is elementwise; axes independent).
// Twiddles from LDS table tw[i] = e^{-2*pi*i/512} (tw[i+256] = -tw[i]).
// ---------------------------------------------------------------------------

// Gaussian blur coefficients, sigma=1, 5-tap.
#define GW0 0.05448868454964294f
#define GW1 0.24420134200323332f
#define GW2 0.40261994689424746f

#define FILL_TW512(nthr)                                       \
    for (int i_ = threadIdx.x; i_ < 256; i_ += (nthr)) {       \
        float rev_ = -(float)i_ * (1.0f / 512.0f);             \
        float s_ = __builtin_amdgcn_sinf(rev_);                \
        float c_ = __builtin_amdgcn_cosf(rev_);                \
        tws[i_] = s_;        twc[i_] = c_;                     \
        tws[i_ + 256] = -s_; twc[i_ + 256] = -c_;              \
    }

// LDS pad-every-16: breaks power-of-2 stride conflicts (<=4-way worst).
#define RP(a) ((a) + ((a) >> 4))
#define RSZ 544             // 512 + 32 pad floats per row

// Radix-4 DIF forward butterfly (1 per thread), q = butterfly idx 0..127.
#define R4_FWD(rr, ri, q, s4)                                                 \
    {                                                                          \
        const int log2n = 9 - 2 * (s4);                                        \
        const int log2m = log2n - 2;                                           \
        const int m = 1 << log2m;                                              \
        int r = (q) & (m - 1);                                                 \
        int j0 = (((q) >> log2m) << log2n) + r;                                \
        float a0x = rr[RP(j0)],       a0y = ri[RP(j0)];                        \
        float a1x = rr[RP(j0 + m)],   a1y = ri[RP(j0 + m)];                    \
        float a2x = rr[RP(j0 + 2*m)], a2y = ri[RP(j0 + 2*m)];                  \
        float a3x = rr[RP(j0 + 3*m)], a3y = ri[RP(j0 + 3*m)];                  \
        float s02x = a0x + a2x, s02y = a0y + a2y;                              \
        float d02x = a0x - a2x, d02y = a0y - a2y;                              \
        float s13x = a1x + a3x, s13y = a1y + a3y;                              \
        float d13x = a1x - a3x, d13y = a1y - a3y;                              \
        float y0x = s02x + s13x, y0y = s02y + s13y;                            \
        float y2x = s02x - s13x, y2y = s02y - s13y;                            \
        float y1x = d02x + d13y, y1y = d02y - d13x;                            \
        float y3x = d02x - d13y, y3y = d02y + d13x;                            \
        int e = r << (2 * (s4));                                               \
        float c1 = twc[e],   s1 = tws[e];                                      \
        float c2 = twc[2*e], s2 = tws[2*e];                                    \
        float c3 = twc[3*e], s3 = tws[3*e];                                    \
        rr[RP(j0)]       = y0x;             ri[RP(j0)]       = y0y;            \
        rr[RP(j0 + m)]   = y1x*c1 - y1y*s1; ri[RP(j0 + m)]   = y1x*s1 + y1y*c1;\
        rr[RP(j0 + 2*m)] = y2x*c2 - y2y*s2; ri[RP(j0 + 2*m)] = y2x*s2 + y2y*c2;\
        rr[RP(j0 + 3*m)] = y3x*c3 - y3y*s3; ri[RP(j0 + 3*m)] = y3x*s3 + y3y*c3;\
    }

// Radix-4 DIT inverse butterfly (conj twiddles), mirror of R4_FWD.
#define R4_INV(rr, ri, q, s4)                                                 \
    {                                                                          \
        const int log2n = 9 - 2 * (s4);                                        \
        const int log2m = log2n - 2;                                           \
        const int m = 1 << log2m;                                              \
        int r = (q) & (m - 1);                                                 \
        int j0 = (((q) >> log2m) << log2n) + r;                                \
        float a0x = rr[RP(j0)],       a0y = ri[RP(j0)];                        \
        float a1x = rr[RP(j0 + m)],   a1y = ri[RP(j0 + m)];                    \
        float a2x = rr[RP(j0 + 2*m)], a2y = ri[RP(j0 + 2*m)];                  \
        float a3x = rr[RP(j0 + 3*m)], a3y = ri[RP(j0 + 3*m)];                  \
        int e = r << (2 * (s4));                                               \
        float c1 = twc[e],   s1 = tws[e];                                      \
        float c2 = twc[2*e], s2 = tws[2*e];                                    \
        float c3 = twc[3*e], s3 = tws[3*e];                                    \
        float t1x = a1x*c1 + a1y*s1,  t1y = a1y*c1 - a1x*s1;                   \
        float t2x = a2x*c2 + a2y*s2,  t2y = a2y*c2 - a2x*s2;                   \
        float t3x = a3x*c3 + a3y*s3,  t3y = a3y*c3 - a3x*s3;                   \
        float s02x = a0x + t2x, s02y = a0y + t2y;                              \
        float d02x = a0x - t2x, d02y = a0y - t2y;                              \
        float s13x = t1x + t3x, s13y = t1y + t3y;                              \
        float d13x = t1x - t3x, d13y = t1y - t3y;                              \
        rr[RP(j0)]       = s02x + s13x;  ri[RP(j0)]       = s02y + s13y;       \
        rr[RP(j0 + 2*m)] = s02x - s13x;  ri[RP(j0 + 2*m)] = s02y - s13y;       \
        rr[RP(j0 + m)]   = d02x - d13y;  ri[RP(j0 + m)]   = d02y + d13x;       \
        rr[RP(j0 + 3*m)] = d02x + d13y;  ri[RP(j0 + 3*m)] = d02y - d13x;       \
    }

// K1: window + forward radix-4 FFT along W. 2 rows per 256-thread block.
__global__ void k_win_rowfft(const float* __restrict__ img, float2* __restrict__ A) {
    __shared__ float re[2 * RSZ], im[2 * RSZ];
    __shared__ float twc[512], tws[512];
    int t = threadIdx.x;
    FILL_TW512(256)
    int lr = t >> 7;                 // local row 0/1
    int u  = t & 127;                // per-row lane
    int row = blockIdx.x * 2 + lr;   // b*512 + h
    int h = row & 511;
    float wr = 0.5f * (1.0f - __builtin_amdgcn_cosf((float)h * (1.0f / 511.0f)));
    const float* p = img + (size_t)row * 512;
    float* rr = re + lr * RSZ;
    float* ri = im + lr * RSZ;
    {
        int i0 = u * 4;
        float4 v = *reinterpret_cast<const float4*>(p + i0);
        float w0 = 0.5f * (1.0f - __builtin_amdgcn_cosf((float)(i0 + 0) * (1.0f / 511.0f)));
        float w1 = 0.5f * (1.0f - __builtin_amdgcn_cosf((float)(i0 + 1) * (1.0f / 511.0f)));
        float w2 = 0.5f * (1.0f - __builtin_amdgcn_cosf((float)(i0 + 2) * (1.0f / 511.0f)));
        float w3 = 0.5f * (1.0f - __builtin_amdgcn_cosf((float)(i0 + 3) * (1.0f / 511.0f)));
        rr[RP(i0 + 0)] = v.x * wr * w0;  ri[RP(i0 + 0)] = 0.0f;
        rr[RP(i0 + 1)] = v.y * wr * w1;  ri[RP(i0 + 1)] = 0.0f;
        rr[RP(i0 + 2)] = v.z * wr * w2;  ri[RP(i0 + 2)] = 0.0f;
        rr[RP(i0 + 3)] = v.w * wr * w3;  ri[RP(i0 + 3)] = 0.0f;
    }
    __syncthreads();
    R4_FWD(rr, ri, u, 0)  __syncthreads();
    R4_FWD(rr, ri, u, 1)  __syncthreads();
    R4_FWD(rr, ri, u, 2)  __syncthreads();
    R4_FWD(rr, ri, u, 3)  __syncthreads();
    #pragma unroll
    for (int kk = 0; kk < 2; ++kk) {     // final radix-2 (2 butterflies/thread)
        int j = (kk * 128 + u) << 1;
        float ax = rr[RP(j)], ay = ri[RP(j)], bx = rr[RP(j + 1)], by = ri[RP(j + 1)];
        rr[RP(j)]     = ax + bx;  ri[RP(j)]     = ay + by;
        rr[RP(j + 1)] = ax - bx;  ri[RP(j + 1)] = ay - by;
    }
    __syncthreads();
    float2* out = A + (size_t)row * 512;
    #pragma unroll
    for (int k2 = 0; k2 < 2; ++k2) {
        int i = u * 4 + k2 * 2;
        float4 v = make_float4(rr[RP(i)], ri[RP(i)], rr[RP(i + 1)], ri[RP(i + 1)]);
        *reinterpret_cast<float4*>(&out[i]) = v;
    }
}

// Fused H-axis pass on 512x16 column tiles, radix-4.
#define CSTR 514
__global__ __launch_bounds__(512) void k_colfft(float2* __restrict__ X) {
    __shared__ float re[16 * CSTR];
    __shared__ float im[16 * CSTR];
    __shared__ float twc[512], tws[512];
    int b = blockIdx.x >> 5;
    int c0 = (blockIdx.x & 31) * 16;
    int t = threadIdx.x;
    FILL_TW512(512)
    float2* base = X + (size_t)b * HW + c0;
    #pragma unroll
    for (int ii = 0; ii < 8; ++ii) {
        int linear = ii * 512 + t;
        int cp = linear & 7;
        int e  = linear >> 3;
        const float4 v = *reinterpret_cast<const float4*>(&base[(size_t)e * 512 + cp * 2]);
        int a0 = (cp * 2) * CSTR + e;
        int a1 = a0 + CSTR;
        re[a0] = v.x; im[a0] = v.y;
        re[a1] = v.z; im[a1] = v.w;
    }
    __syncthreads();
    int c = t & 15, tt = t >> 4;
    float* cr = re + c * CSTR;
    float* ci = im + c * CSTR;

    for (int s4 = 0; s4 < 4; ++s4) {
        int log2n = 9 - 2 * s4;
        int log2m = log2n - 2;
        int m = 1 << log2m;
        #pragma unroll
        for (int kk = 0; kk < 4; ++kk) {
            int q = kk * 32 + tt;
            int r = q & (m - 1);
            int j0 = ((q >> log2m) << log2n) + r;
            float a0x = cr[j0],       a0y = ci[j0];
            float a1x = cr[j0 + m],   a1y = ci[j0 + m];
            float a2x = cr[j0 + 2*m], a2y = ci[j0 + 2*m];
            float a3x = cr[j0 + 3*m], a3y = ci[j0 + 3*m];
            float s02x = a0x + a2x, s02y = a0y + a2y;
            float d02x = a0x - a2x, d02y = a0y - a2y;
            float s13x = a1x + a3x, s13y = a1y + a3y;
            float d13x = a1x - a3x, d13y = a1y - a3y;
            float y0x = s02x + s13x, y0y = s02y + s13y;
            float y2x = s02x - s13x, y2y = s02y - s13y;
            float y1x = d02x + d13y, y1y = d02y - d13x;
            float y3x = d02x - d13y, y3y = d02y + d13x;
            int e = r << (2 * s4);
            float c1 = twc[e],   s1 = tws[e];
            float c2 = twc[2*e], s2 = tws[2*e];
            float c3 = twc[3*e], s3 = tws[3*e];
            cr[j0]       = y0x;                 ci[j0]       = y0y;
            cr[j0 + m]   = y1x*c1 - y1y*s1;     ci[j0 + m]   = y1x*s1 + y1y*c1;
            cr[j0 + 2*m] = y2x*c2 - y2y*s2;     ci[j0 + 2*m] = y2x*s2 + y2y*c2;
            cr[j0 + 3*m] = y3x*c3 - y3y*s3;     ci[j0 + 3*m] = y3x*s3 + y3y*c3;
        }
        __syncthreads();
    }
    #pragma unroll
    for (int kk = 0; kk < 8; ++kk) {
        int j = (kk * 32 + tt) << 1;
        float ax = cr[j], ay = ci[j], bx = cr[j+1], by = ci[j+1];
        cr[j]   = ax + bx; ci[j]   = ay + by;
        cr[j+1] = ax - bx; ci[j+1] = ay - by;
    }
    __syncthreads();
    #pragma unroll
    for (int ii = 0; ii < 16; ++ii) {
        int linear = ii * 512 + t;
        int cc = linear & 15, e = linear >> 4;
        int a = cc * CSTR + e;
        float x = re[a], y = im[a];
        float m2 = x * x + y * y;
        if (m2 > 0.0f) {
            float inv = rsqrtf(m2);
            re[a] = x * inv; im[a] = y * inv;
        } else {
            re[a] = 1.0f; im[a] = 0.0f;
        }
    }
    __syncthreads();
    #pragma unroll
    for (int kk = 0; kk < 8; ++kk) {
        int j = (kk * 32 + tt) << 1;
        float ax = cr[j], ay = ci[j], bx = cr[j+1], by = ci[j+1];
        cr[j]   = ax + bx; ci[j]   = ay + by;
        cr[j+1] = ax - bx; ci[j+1] = ay - by;
    }
    __syncthreads();
    for (int s4 = 3; s4 >= 0; --s4) {
        int log2n = 9 - 2 * s4;
        int log2m = log2n - 2;
        int m = 1 << log2m;
        #pragma unroll
        for (int kk = 0; kk < 4; ++kk) {
            int q = kk * 32 + tt;
            int r = q & (m - 1);
            int j0 = ((q >> log2m) << log2n) + r;
            float a0x = cr[j0],       a0y = ci[j0];
            float a1x = cr[j0 + m],   a1y = ci[j0 + m];
            float a2x = cr[j0 + 2*m], a2y = ci[j0 + 2*m];
            float a3x = cr[j0 + 3*m], a3y = ci[j0 + 3*m];
            int e = r << (2 * s4);
            float c1 = twc[e],   s1 = tws[e];
            float c2 = twc[2*e], s2 = tws[2*e];
            float c3 = twc[3*e], s3 = tws[3*e];
            float t1x = a1x*c1 + a1y*s1,  t1y = a1y*c1 - a1x*s1;
            float t2x = a2x*c2 + a2y*s2,  t2y = a2y*c2 - a2x*s2;
            float t3x = a3x*c3 + a3y*s3,  t3y = a3y*c3 - a3x*s3;
            float s02x = a0x + t2x, s02y = a0y + t2y;
            float d02x = a0x - t2x, d02y = a0y - t2y;
            float s13x = t1x + t3x, s13y = t1y + t3y;
            float d13x = t1x - t3x, d13y = t1y - t3y;
            cr[j0]       = s02x + s13x;   ci[j0]       = s02y + s13y;
            cr[j0 + 2*m] = s02x - s13x;   ci[j0 + 2*m] = s02y - s13y;
            cr[j0 + m]   = d02x - d13y;   ci[j0 + m]   = d02y + d13x;
            cr[j0 + 3*m] = d02x + d13y;   ci[j0 + 3*m] = d02y - d13x;
        }
        __syncthreads();
    }
    #pragma unroll
    for (int ii = 0; ii < 8; ++ii) {
        int linear = ii * 512 + t;
        int cp = linear & 7;
        int e  = linear >> 3;
        int a0 = (cp * 2) * CSTR + e;
        int a1 = a0 + CSTR;
        float4 v = make_float4(re[a0], im[a0], re[a1], im[a1]);
        *reinterpret_cast<float4*>(&base[(size_t)e * 512 + cp * 2]) = v;
    }
}

// Inverse radix-4 FFT along W + 1/(H*W) scaling + |.|^2 + horizontal blur.
__global__ void k_mag_hblur(const float2* __restrict__ X, float* __restrict__ out) {
    __shared__ float re[2 * RSZ], im[2 * RSZ];
    __shared__ float twc[512], tws[512];
    int t = threadIdx.x;
    FILL_TW512(256)
    int lr = t >> 7;
    int u  = t & 127;
    int row = blockIdx.x * 2 + lr;
    const float2* p = X + (size_t)row * 512;
    float* rr = re + lr * RSZ;
    float* ri = im + lr * RSZ;
    #pragma unroll
    for (int k2 = 0; k2 < 2; ++k2) {
        int i = u * 4 + k2 * 2;
        float4 v = *reinterpret_cast<const float4*>(&p[i]);
        rr[RP(i)]     = v.x; ri[RP(i)]     = v.y;
        rr[RP(i + 1)] = v.z; ri[RP(i + 1)] = v.w;
    }
    __syncthreads();
    #pragma unroll
    for (int kk = 0; kk < 2; ++kk) {     // radix-2 first (mirror)
        int j = (kk * 128 + u) << 1;
        float ax = rr[RP(j)], ay = ri[RP(j)], bx = rr[RP(j + 1)], by = ri[RP(j + 1)];
        rr[RP(j)]     = ax + bx;  ri[RP(j)]     = ay + by;
        rr[RP(j + 1)] = ax - bx;  ri[RP(j + 1)] = ay - by;
    }
    __syncthreads();
    R4_INV(rr, ri, u, 3)  __syncthreads();
    R4_INV(rr, ri, u, 2)  __syncthreads();
    R4_INV(rr, ri, u, 1)  __syncthreads();
    R4_INV(rr, ri, u, 0)  __syncthreads();
    const float s = 3.814697265625e-06f;   // 1/262144, exact
    #pragma unroll
    for (int k4 = 0; k4 < 4; ++k4) {       // |.|^2 into ri
        int i = u * 4 + k4;
        float x = rr[RP(i)] * s, y = ri[RP(i)] * s;
        ri[RP(i)] = x * x + y * y;
    }
    __syncthreads();
    float* o = out + (size_t)row * 512;
    float4 res;
    #pragma unroll
    for (int k4 = 0; k4 < 4; ++k4) {
        int i = u * 4 + k4;
        float acc = GW2 * ri[RP(i)];
        if (i >= 1)   acc += GW1 * ri[RP(i - 1)];
        if (i >= 2)   acc += GW0 * ri[RP(i - 2)];
        if (i <= 510) acc += GW1 * ri[RP(i + 1)];
        if (i <= 509) acc += GW0 * ri[RP(i + 2)];
        ((float*)&res)[k4] = acc;
    }
    *reinterpret_cast<float4*>(o + u * 4) = res;
}

// Vertical blur (float4, 4 elems/thread) + per-BLOCK min/max partials.
// Also zeroes the hist/ccnt scratch region (replaces a 41us runtime memset).
__global__ void k_vblur(const float* __restrict__ in, float* __restrict__ out,
                        float* __restrict__ pmn, float* __restrict__ pmx,
                        unsigned int* __restrict__ zr) {
    __shared__ float smn[256];
    __shared__ float smx[256];
    int t = threadIdx.x;
    int gi = blockIdx.x * 256 + t;
    if (gi < ZEROWORDS) zr[gi] = 0u;      // hists + ccnt live at ws[0..819264)
    int i = gi * 4;
    int y = (i >> 9) & 511;               // same row for all 4 elems (4 | 512)
    const float4 c = *reinterpret_cast<const float4*>(in + i);
    float4 acc = make_float4(GW2 * c.x, GW2 * c.y, GW2 * c.z, GW2 * c.w);
    if (y >= 1) {
        const float4 v = *reinterpret_cast<const float4*>(in + i - 512);
        acc.x += GW1 * v.x; acc.y += GW1 * v.y; acc.z += GW1 * v.z; acc.w += GW1 * v.w;
    }
    if (y >= 2) {
        const float4 v = *reinterpret_cast<const float4*>(in + i - 1024);
        acc.x += GW0 * v.x; acc.y += GW0 * v.y; acc.z += GW0 * v.z; acc.w += GW0 * v.w;
    }
    if (y <= 510) {
        const float4 v = *reinterpret_cast<const float4*>(in + i + 512);
        acc.x += GW1 * v.x; acc.y += GW1 * v.y; acc.z += GW1 * v.z; acc.w += GW1 * v.w;
    }
    if (y <= 509) {
        const float4 v = *reinterpret_cast<const float4*>(in + i + 1024);
        acc.x += GW0 * v.x; acc.y += GW0 * v.y; acc.z += GW0 * v.z; acc.w += GW0 * v.w;
    }
    *reinterpret_cast<float4*>(out + i) = acc;
    float lmn = fminf(fminf(acc.x, acc.y), fminf(acc.z, acc.w));
    float lmx = fmaxf(fmaxf(acc.x, acc.y), fmaxf(acc.z, acc.w));
    smn[t] = lmn; smx[t] = lmx;
    __syncthreads();
    for (int s = 128; s > 0; s >>= 1) {
        if (t < s) { smn[t] = fminf(smn[t], smn[t + s]); smx[t] = fmaxf(smx[t], smx[t + s]); }
        __syncthreads();
    }
    if (t == 0) { pmn[blockIdx.x] = smn[0]; pmx[blockIdx.x] = smx[0]; }
}

// Normalize + border mask -> final saliency (d_out), fused with hist round 1.
// Each block redundantly folds its image's 256 min/max partials first.
__global__ void k_norm_hist(const float* __restrict__ in, const float* __restrict__ pmn,
                            const float* __restrict__ pmx, float* __restrict__ out,
                            unsigned int* __restrict__ g) {
    __shared__ unsigned int h[4096];
    __shared__ float smn[256], smx[256];
    int t = threadIdx.x;
    int b = blockIdx.x >> 5;
    int base = b * HW + (blockIdx.x & 31) * 8192;
    smn[t] = pmn[b * 256 + t];
    smx[t] = pmx[b * 256 + t];
    for (int i = t; i < 4096; i += 256) h[i] = 0u;
    __syncthreads();
    for (int s = 128; s > 0; s >>= 1) {
        if (t < s) { smn[t] = fminf(smn[t], smn[t + s]); smx[t] = fmaxf(smx[t], smx[t + s]); }
        __syncthreads();
    }
    float mn = smn[0], mx = smx[0];
    float inv = 1.0f / (mx - mn + 1e-8f);
    for (int j = 0; j < 32; ++j) {
        int idx = base + j * 256 + t;
        float v = (in[idx] - mn) * inv;
        int xx = idx & 511, yy = (idx >> 9) & 511;
        bool inside = (xx >= 12) && (xx < 500) && (yy >= 12) && (yy < 500);
        v = inside ? v : 0.0f;
        out[idx] = v;
        atomicAdd(&h[__float_as_uint(v) >> 20], 1u);
    }
    __syncthreads();
    unsigned int* gb = g + b * 4096;
    for (int i = t; i < 4096; i += 256)
        if (h[i]) atomicAdd(&gb[i], h[i]);
}

// Find bin d (from top) s.t. suffix count crosses krem.
__device__ void radix_step(const unsigned int* __restrict__ h, int nbins, int krem,
                           int t, unsigned int* tsum, int* sbin, int* skrem) {
    int bpt = nbins >> 8;
    unsigned int s = 0;
    for (int j = 0; j < bpt; ++j) s += h[t * bpt + j];
    tsum[t] = s;
    __syncthreads();
    if (t == 0) {
        unsigned int cum = 0; int seg = 0;
        for (int d = 255; d >= 0; --d) {
            unsigned int c2 = cum + tsum[d];
            if ((int)c2 >= krem) { seg = d; break; }
            cum = c2;
        }
        unsigned int c = cum;
        for (int j = bpt - 1; j >= 0; --j) {
            unsigned int hv = h[seg * bpt + j];
            if ((int)(c + hv) >= krem) { *sbin = seg * bpt + j; *skrem = krem - (int)c; break; }
            c += hv;
        }
    }
    __syncthreads();
}

// Round-2 histograms, with round-1 scan fused (redundant per block; integer
// ops -> identical result in every block). Designated blocks publish stats.
__global__ void k_hist2(const float* __restrict__ sal, const unsigned int* __restrict__ g1,
                        unsigned int* __restrict__ gA, unsigned int* __restrict__ gB,
                        unsigned int* prefA1, int* kremA1, unsigned int* prefB1, int* kremB1) {
    __shared__ unsigned int hA[4096];
    __shared__ unsigned int hB[4096];
    __shared__ unsigned int tsum[256];
    __shared__ int sbin, skrem;
    int t = threadIdx.x;
    int b = blockIdx.x >> 5;
    int start = (blockIdx.x & 31) * 8192;
    for (int i = t; i < 4096; i += 256) { hA[i] = 0u; hB[i] = 0u; }
    radix_step(g1 + b * 4096, 4096, KSEL, t, tsum, &sbin, &skrem);
    unsigned int pA = (unsigned int)sbin; int krA = skrem;
    radix_step(g1 + b * 4096, 4096, MCAND, t, tsum, &sbin, &skrem);
    unsigned int pB = (unsigned int)sbin; int krB = skrem;
    if (t == 0 && (blockIdx.x & 31) == 0) {
        prefA1[b] = pA; kremA1[b] = krA; prefB1[b] = pB; kremB1[b] = krB;
    }
    const float* p = sal + (size_t)b * HW;
    for (int j = 0; j < 32; ++j) {
        unsigned int u = __float_as_uint(p[start + j * 256 + t]);
        unsigned int hi = u >> 20, mid = (u >> 8) & 4095u;
        if (hi == pA) atomicAdd(&hA[mid], 1u);
        if (hi == pB) atomicAdd(&hB[mid], 1u);
    }
    __syncthreads();
    unsigned int* ga = gA + b * 4096;
    unsigned int* gb2 = gB + b * 4096;
    for (int i = t; i < 4096; i += 256) {
        if (hA[i]) atomicAdd(&ga[i], hA[i]);
        if (hB[i]) atomicAdd(&gb2[i], hB[i]);
    }
}

// Round-3 A-histogram + candidate collection, with round-2 scan fused.
// cutoffB = bucket floor of the unfiltered 80th value: every top-80 candidate
// is >= it; sub-thr extras are filtered exactly in k_final.
__global__ void k_hist3collect(const float* __restrict__ sal,
                               const unsigned int* __restrict__ gA2, const unsigned int* __restrict__ gB2,
                               const unsigned int* prefA1, const int* kremA1,
                               const unsigned int* prefB1, const int* kremB1,
                               unsigned int* __restrict__ gA3,
                               unsigned int* prefA24, int* kremA2,
                               float* __restrict__ candv, int* __restrict__ candi,
                               int* __restrict__ ccnt) {
    __shared__ unsigned int hA[256];
    __shared__ unsigned int tsum[256];
    __shared__ int sbin, skrem;
    int t = threadIdx.x;
    int b = blockIdx.x >> 5;
    int start = (blockIdx.x & 31) * 8192;
    hA[t] = 0u;
    radix_step(gA2 + b * 4096, 4096, kremA1[b], t, tsum, &sbin, &skrem);
    unsigned int pA = (prefA1[b] << 12) | (unsigned int)sbin;
    int krA2 = skrem;
    radix_step(gB2 + b * 4096, 4096, kremB1[b], t, tsum, &sbin, &skrem);
    unsigned int cutB = ((prefB1[b] << 12) | (unsigned int)sbin) << 8;
    if (t == 0 && (blockIdx.x & 31) == 0) { prefA24[b] = pA; kremA2[b] = krA2; }
    const float* p = sal + (size_t)b * HW;
    for (int j = 0; j < 32; ++j) {
        int i = start + j * 256 + t;
        unsigned int u = __float_as_uint(p[i]);
        if ((u >> 8) == pA) atomicAdd(&hA[u & 255u], 1u);
        if (u >= cutB) {
            int pos = atomicAdd(&ccnt[b], 1);
            if (pos < CAP) { candv[b * CAP + pos] = p[i]; candi[b * CAP + pos] = i; }
        }
    }
    __syncthreads();
    if (hA[t]) atomicAdd(&gA3[b * 256 + t], hA[t]);
}

// Final: derive exact thr from hist3a, rank (value desc, index asc), bitmask
// greedy NMS with validity v >= thr (matches reference -inf filtering).
__global__ void k_final(const unsigned int* __restrict__ gA3,
                        const unsigned int* prefA24, const int* kremA2,
                        const float* __restrict__ candv, const int* __restrict__ candi,
                        const int* __restrict__ ccnt, float* __restrict__ out) {
    __shared__ float cval[CAP];
    __shared__ int   cidx[CAP];
    __shared__ int   si[MCAND];
    __shared__ float svv[MCAND];
    __shared__ float sx[MCAND];
    __shared__ float sy[MCAND];
    __shared__ unsigned long long nearLo[MCAND];
    __shared__ unsigned long long nearHi[MCAND];
    __shared__ unsigned int tsum[256];
    __shared__ int sbin, skrem;
    int b = blockIdx.x, t = threadIdx.x;
    radix_step(gA3 + b * 256, 256, kremA2[b], t, tsum, &sbin, &skrem);
    float thr = fmaxf(__uint_as_float((prefA24[b] << 8) | (unsigned int)sbin), 0.1f);
    int n = min(ccnt[b], CAP);
    for (int i = t; i < n; i += 256) { cval[i] = candv[b * CAP + i]; cidx[i] = candi[b * CAP + i]; }
    __syncthreads();
    int m = min(n, MCAND);
    for (int i = t; i < n; i += 256) {
        float vi = cval[i]; int ii = cidx[i];
        int rank = 0;
        for (int j = 0; j < n; j++) {
            float vj = cval[j];
            if (vj > vi || (vj == vi && cidx[j] < ii)) rank++;
        }
        if (rank < MCAND) { si[rank] = ii; svv[rank] = vi; }
    }
    __syncthreads();
    for (int i = t; i < m; i += 256) {
        sx[i] = (float)(si[i] & 511);
        sy[i] = (float)(si[i] >> 9);
    }
    __syncthreads();
    for (int i = t; i < m; i += 256) {
        unsigned long long lo = 0ull, hi = 0ull;
        float x = sx[i], y = sy[i];
        for (int j = 0; j < m; j++) {
            float dx = sx[j] - x, dy = sy[j] - y;
            if (dx * dx + dy * dy < 100.0f) {
                if (j < 64) lo |= (1ull << j);
                else        hi |= (1ull << (j - 64));
            }
        }
        nearLo[i] = lo; nearHi[i] = hi;
    }
    __syncthreads();
    if (t == 0) {
        unsigned long long kLo = 0ull, kHi = 0ull;
        int cnt = 0;
        for (int i = 0; i < m; i++) {
            bool near_kept = ((nearLo[i] & kLo) | (nearHi[i] & kHi)) != 0ull;
            if (svv[i] >= thr && !near_kept) {
                out[b * 10 + 2 * cnt]     = sx[i];
                out[b * 10 + 2 * cnt + 1] = sy[i];
                out[160 + b * 5 + cnt]    = 1.0f;
                if (i < 64) kLo |= (1ull << i); else kHi |= (1ull << (i - 64));
                cnt++;
                if (cnt == TOPK) break;
            }
        }
        for (int j = cnt; j < TOPK; j++) {
            out[b * 10 + 2 * j]     = -1.0f;
            out[b * 10 + 2 * j + 1] = -1.0f;
            out[160 + b * 5 + j]    = -1.0f;
        }
    }
}

extern "C" void kernel_launch(void* const* d_in, const int* in_sizes, int n_in,
                              void* d_out, int out_size, void* d_ws, size_t ws_size,
                              hipStream_t stream) {
    const float* img = (const float*)d_in[0];
    float* out = (float*)d_out;
    char* ws = (char*)d_ws;

    float2* A    = (float2*)ws;
    float*  hb   = (float*)(ws + 33554432UL);
    float*  salb = (float*)(ws + 50331648UL);

    unsigned int* hist1  = (unsigned int*)(ws + 0UL);
    unsigned int* hist2a = (unsigned int*)(ws + 262144UL);
    unsigned int* hist2b = (unsigned int*)(ws + 524288UL);
    unsigned int* hist3a = (unsigned int*)(ws + 786432UL);
    int*          ccnt   = (int*)(ws + 819200UL);
    float*        candv  = (float*)(ws + 851968UL);
    int*          candi  = (int*)(ws + 983040UL);

    float* pmn = (float*)(ws + 20971520UL);                 // 4096 f32
    float* pmx = (float*)(ws + 21037056UL);                 // 4096 f32

    char* stats = ws + 67108864UL;
    unsigned int* prefA1  = (unsigned int*)(stats + 0);
    int*          kremA1  = (int*)(stats + 64);
    unsigned int* prefB1  = (unsigned int*)(stats + 128);
    int*          kremB1  = (int*)(stats + 192);
    unsigned int* prefA24 = (unsigned int*)(stats + 256);
    int*          kremA2  = (int*)(stats + 320);

    float* salout = out + 240;   // sal region of d_out

    k_win_rowfft<<<dim3(4096), dim3(256), 0, stream>>>(img, A);     // radix-4 W fwd
    k_colfft<<<dim3(512), dim3(512), 0, stream>>>(A);               // radix-4 H pass
    k_mag_hblur<<<dim3(4096), dim3(256), 0, stream>>>(A, hb);       // radix-4 W inv + mag + hblur
    k_vblur<<<dim3(4096), dim3(256), 0, stream>>>(hb, salb, pmn, pmx,
                                                  (unsigned int*)ws); // + zero hists/ccnt
    k_norm_hist<<<dim3(512), dim3(256), 0, stream>>>(salb, pmn, pmx, salout, hist1);
    k_hist2<<<dim3(512), dim3(256), 0, stream>>>(salout, hist1, hist2a, hist2b,
                                                 prefA1, kremA1, prefB1, kremB1);
    k_hist3collect<<<dim3(512), dim3(256), 0, stream>>>(salout, hist2a, hist2b,
                                                        prefA1, kremA1, prefB1, kremB1,
                                                        hist3a, prefA24, kremA2,
                                                        candv, candi, ccnt);
    k_final<<<dim3(BATCH), dim3(256), 0, stream>>>(hist3a, prefA24, kremA2,
                                                   candv, candi, ccnt, out);
}

// Round 12
// 154.520 us; speedup vs baseline: 1.6949x; 1.2862x over previous
//
#include <hip/hip_runtime.h>
#include <math.h>

#define BATCH 16
#define HW 262144          // 512*512
#define KSEL 26214         // int(0.1 * 262144)
#define MCAND 80           // TOP_K * CAND_MULT
#define TOPK 5
#define CAP 2048
#define ZEROWORDS 204816   // (hists + ccnt) bytes / 4, zeroed inside k_vblur

// ---------------------------------------------------------------------------
// In-place FFT, N=512, mixed radix-4 (4 stages) + radix-2 (1 stage) on all
// axes. Forward DIF: natural -> digit-reversed; inverse DIT (conj twiddles,
// mirrored stage order): digit-reversed -> natural. DIT(DIF(x)) = 512*x
// elementwise, so the digit-reversed intermediate order is unobservable
// (phase normalize is elementwise; axes independent).
// Twiddles from LDS table tw[i] = e^{-2*pi*i/512} (tw[i+256] = -tw[i]).
// ---------------------------------------------------------------------------

// Gaussian blur coefficients, sigma=1, 5-tap.
#define GW0 0.05448868454964294f
#define GW1 0.24420134200323332f
#define GW2 0.40261994689424746f

#define FILL_TW512(nthr)                                       \
    for (int i_ = threadIdx.x; i_ < 256; i_ += (nthr)) {       \
        float rev_ = -(float)i_ * (1.0f / 512.0f);             \
        float s_ = __builtin_amdgcn_sinf(rev_);                \
        float c_ = __builtin_amdgcn_cosf(rev_);                \
        tws[i_] = s_;        twc[i_] = c_;                     \
        tws[i_ + 256] = -s_; twc[i_ + 256] = -c_;              \
    }

// LDS pad-every-16: breaks power-of-2 stride conflicts (<=4-way worst).
#define RP(a) ((a) + ((a) >> 4))
#define RSZ 544             // 512 + 32 pad floats per row

// Radix-4 DIF forward butterfly (1 per thread), q = butterfly idx 0..127.
#define R4_FWD(rr, ri, q, s4)                                                 \
    {                                                                          \
        const int log2n = 9 - 2 * (s4);                                        \
        const int log2m = log2n - 2;                                           \
        const int m = 1 << log2m;                                              \
        int r = (q) & (m - 1);                                                 \
        int j0 = (((q) >> log2m) << log2n) + r;                                \
        float a0x = rr[RP(j0)],       a0y = ri[RP(j0)];                        \
        float a1x = rr[RP(j0 + m)],   a1y = ri[RP(j0 + m)];                    \
        float a2x = rr[RP(j0 + 2*m)], a2y = ri[RP(j0 + 2*m)];                  \
        float a3x = rr[RP(j0 + 3*m)], a3y = ri[RP(j0 + 3*m)];                  \
        float s02x = a0x + a2x, s02y = a0y + a2y;                              \
        float d02x = a0x - a2x, d02y = a0y - a2y;                              \
        float s13x = a1x + a3x, s13y = a1y + a3y;                              \
        float d13x = a1x - a3x, d13y = a1y - a3y;                              \
        float y0x = s02x + s13x, y0y = s02y + s13y;                            \
        float y2x = s02x - s13x, y2y = s02y - s13y;                            \
        float y1x = d02x + d13y, y1y = d02y - d13x;                            \
        float y3x = d02x - d13y, y3y = d02y + d13x;                            \
        int e = r << (2 * (s4));                                               \
        float c1 = twc[e],   s1 = tws[e];                                      \
        float c2 = twc[2*e], s2 = tws[2*e];                                    \
        float c3 = twc[3*e], s3 = tws[3*e];                                    \
        rr[RP(j0)]       = y0x;             ri[RP(j0)]       = y0y;            \
        rr[RP(j0 + m)]   = y1x*c1 - y1y*s1; ri[RP(j0 + m)]   = y1x*s1 + y1y*c1;\
        rr[RP(j0 + 2*m)] = y2x*c2 - y2y*s2; ri[RP(j0 + 2*m)] = y2x*s2 + y2y*c2;\
        rr[RP(j0 + 3*m)] = y3x*c3 - y3y*s3; ri[RP(j0 + 3*m)] = y3x*s3 + y3y*c3;\
    }

// Radix-4 DIT inverse butterfly (conj twiddles), mirror of R4_FWD.
#define R4_INV(rr, ri, q, s4)                                                 \
    {                                                                          \
        const int log2n = 9 - 2 * (s4);                                        \
        const int log2m = log2n - 2;                                           \
        const int m = 1 << log2m;                                              \
        int r = (q) & (m - 1);                                                 \
        int j0 = (((q) >> log2m) << log2n) + r;                                \
        float a0x = rr[RP(j0)],       a0y = ri[RP(j0)];                        \
        float a1x = rr[RP(j0 + m)],   a1y = ri[RP(j0 + m)];                    \
        float a2x = rr[RP(j0 + 2*m)], a2y = ri[RP(j0 + 2*m)];                  \
        float a3x = rr[RP(j0 + 3*m)], a3y = ri[RP(j0 + 3*m)];                  \
        int e = r << (2 * (s4));                                               \
        float c1 = twc[e],   s1 = tws[e];                                      \
        float c2 = twc[2*e], s2 = tws[2*e];                                    \
        float c3 = twc[3*e], s3 = tws[3*e];                                    \
        float t1x = a1x*c1 + a1y*s1,  t1y = a1y*c1 - a1x*s1;                   \
        float t2x = a2x*c2 + a2y*s2,  t2y = a2y*c2 - a2x*s2;                   \
        float t3x = a3x*c3 + a3y*s3,  t3y = a3y*c3 - a3x*s3;                   \
        float s02x = a0x + t2x, s02y = a0y + t2y;                              \
        float d02x = a0x - t2x, d02y = a0y - t2y;                              \
        float s13x = t1x + t3x, s13y = t1y + t3y;                              \
        float d13x = t1x - t3x, d13y = t1y - t3y;                              \
        rr[RP(j0)]       = s02x + s13x;  ri[RP(j0)]       = s02y + s13y;       \
        rr[RP(j0 + 2*m)] = s02x - s13x;  ri[RP(j0 + 2*m)] = s02y - s13y;       \
        rr[RP(j0 + m)]   = d02x - d13y;  ri[RP(j0 + m)]   = d02y + d13x;       \
        rr[RP(j0 + 3*m)] = d02x + d13y;  ri[RP(j0 + 3*m)] = d02y - d13x;       \
    }

// K1: window + forward radix-4 FFT along W. 2 rows per 256-thread block.
__global__ void k_win_rowfft(const float* __restrict__ img, float2* __restrict__ A) {
    __shared__ float re[2 * RSZ], im[2 * RSZ];
    __shared__ float twc[512], tws[512];
    int t = threadIdx.x;
    FILL_TW512(256)
    int lr = t >> 7;                 // local row 0/1
    int u  = t & 127;                // per-row lane
    int row = blockIdx.x * 2 + lr;   // b*512 + h
    int h = row & 511;
    float wr = 0.5f * (1.0f - __builtin_amdgcn_cosf((float)h * (1.0f / 511.0f)));
    const float* p = img + (size_t)row * 512;
    float* rr = re + lr * RSZ;
    float* ri = im + lr * RSZ;
    {
        int i0 = u * 4;
        float4 v = *reinterpret_cast<const float4*>(p + i0);
        float w0 = 0.5f * (1.0f - __builtin_amdgcn_cosf((float)(i0 + 0) * (1.0f / 511.0f)));
        float w1 = 0.5f * (1.0f - __builtin_amdgcn_cosf((float)(i0 + 1) * (1.0f / 511.0f)));
        float w2 = 0.5f * (1.0f - __builtin_amdgcn_cosf((float)(i0 + 2) * (1.0f / 511.0f)));
        float w3 = 0.5f * (1.0f - __builtin_amdgcn_cosf((float)(i0 + 3) * (1.0f / 511.0f)));
        rr[RP(i0 + 0)] = v.x * wr * w0;  ri[RP(i0 + 0)] = 0.0f;
        rr[RP(i0 + 1)] = v.y * wr * w1;  ri[RP(i0 + 1)] = 0.0f;
        rr[RP(i0 + 2)] = v.z * wr * w2;  ri[RP(i0 + 2)] = 0.0f;
        rr[RP(i0 + 3)] = v.w * wr * w3;  ri[RP(i0 + 3)] = 0.0f;
    }
    __syncthreads();
    R4_FWD(rr, ri, u, 0)  __syncthreads();
    R4_FWD(rr, ri, u, 1)  __syncthreads();
    R4_FWD(rr, ri, u, 2)  __syncthreads();
    R4_FWD(rr, ri, u, 3)  __syncthreads();
    #pragma unroll
    for (int kk = 0; kk < 2; ++kk) {     // final radix-2 (2 butterflies/thread)
        int j = (kk * 128 + u) << 1;
        float ax = rr[RP(j)], ay = ri[RP(j)], bx = rr[RP(j + 1)], by = ri[RP(j + 1)];
        rr[RP(j)]     = ax + bx;  ri[RP(j)]     = ay + by;
        rr[RP(j + 1)] = ax - bx;  ri[RP(j + 1)] = ay - by;
    }
    __syncthreads();
    float2* out = A + (size_t)row * 512;
    #pragma unroll
    for (int k2 = 0; k2 < 2; ++k2) {
        int i = u * 4 + k2 * 2;
        float4 v = make_float4(rr[RP(i)], ri[RP(i)], rr[RP(i + 1)], ri[RP(i + 1)]);
        *reinterpret_cast<float4*>(&out[i]) = v;
    }
}

// Fused H-axis pass on 512x16 column tiles, radix-4.
#define CSTR 514
__global__ __launch_bounds__(512) void k_colfft(float2* __restrict__ X) {
    __shared__ float re[16 * CSTR];
    __shared__ float im[16 * CSTR];
    __shared__ float twc[512], tws[512];
    int b = blockIdx.x >> 5;
    int c0 = (blockIdx.x & 31) * 16;
    int t = threadIdx.x;
    FILL_TW512(512)
    float2* base = X + (size_t)b * HW + c0;
    #pragma unroll
    for (int ii = 0; ii < 8; ++ii) {
        int linear = ii * 512 + t;
        int cp = linear & 7;
        int e  = linear >> 3;
        const float4 v = *reinterpret_cast<const float4*>(&base[(size_t)e * 512 + cp * 2]);
        int a0 = (cp * 2) * CSTR + e;
        int a1 = a0 + CSTR;
        re[a0] = v.x; im[a0] = v.y;
        re[a1] = v.z; im[a1] = v.w;
    }
    __syncthreads();
    int c = t & 15, tt = t >> 4;
    float* cr = re + c * CSTR;
    float* ci = im + c * CSTR;

    for (int s4 = 0; s4 < 4; ++s4) {
        int log2n = 9 - 2 * s4;
        int log2m = log2n - 2;
        int m = 1 << log2m;
        #pragma unroll
        for (int kk = 0; kk < 4; ++kk) {
            int q = kk * 32 + tt;
            int r = q & (m - 1);
            int j0 = ((q >> log2m) << log2n) + r;
            float a0x = cr[j0],       a0y = ci[j0];
            float a1x = cr[j0 + m],   a1y = ci[j0 + m];
            float a2x = cr[j0 + 2*m], a2y = ci[j0 + 2*m];
            float a3x = cr[j0 + 3*m], a3y = ci[j0 + 3*m];
            float s02x = a0x + a2x, s02y = a0y + a2y;
            float d02x = a0x - a2x, d02y = a0y - a2y;
            float s13x = a1x + a3x, s13y = a1y + a3y;
            float d13x = a1x - a3x, d13y = a1y - a3y;
            float y0x = s02x + s13x, y0y = s02y + s13y;
            float y2x = s02x - s13x, y2y = s02y - s13y;
            float y1x = d02x + d13y, y1y = d02y - d13x;
            float y3x = d02x - d13y, y3y = d02y + d13x;
            int e = r << (2 * s4);
            float c1 = twc[e],   s1 = tws[e];
            float c2 = twc[2*e], s2 = tws[2*e];
            float c3 = twc[3*e], s3 = tws[3*e];
            cr[j0]       = y0x;                 ci[j0]       = y0y;
            cr[j0 + m]   = y1x*c1 - y1y*s1;     ci[j0 + m]   = y1x*s1 + y1y*c1;
            cr[j0 + 2*m] = y2x*c2 - y2y*s2;     ci[j0 + 2*m] = y2x*s2 + y2y*c2;
            cr[j0 + 3*m] = y3x*c3 - y3y*s3;     ci[j0 + 3*m] = y3x*s3 + y3y*c3;
        }
        __syncthreads();
    }
    #pragma unroll
    for (int kk = 0; kk < 8; ++kk) {
        int j = (kk * 32 + tt) << 1;
        float ax = cr[j], ay = ci[j], bx = cr[j+1], by = ci[j+1];
        cr[j]   = ax + bx; ci[j]   = ay + by;
        cr[j+1] = ax - bx; ci[j+1] = ay - by;
    }
    __syncthreads();
    #pragma unroll
    for (int ii = 0; ii < 16; ++ii) {
        int linear = ii * 512 + t;
        int cc = linear & 15, e = linear >> 4;
        int a = cc * CSTR + e;
        float x = re[a], y = im[a];
        float m2 = x * x + y * y;
        if (m2 > 0.0f) {
            float inv = rsqrtf(m2);
            re[a] = x * inv; im[a] = y * inv;
        } else {
            re[a] = 1.0f; im[a] = 0.0f;
        }
    }
    __syncthreads();
    #pragma unroll
    for (int kk = 0; kk < 8; ++kk) {
        int j = (kk * 32 + tt) << 1;
        float ax = cr[j], ay = ci[j], bx = cr[j+1], by = ci[j+1];
        cr[j]   = ax + bx; ci[j]   = ay + by;
        cr[j+1] = ax - bx; ci[j+1] = ay - by;
    }
    __syncthreads();
    for (int s4 = 3; s4 >= 0; --s4) {
        int log2n = 9 - 2 * s4;
        int log2m = log2n - 2;
        int m = 1 << log2m;
        #pragma unroll
        for (int kk = 0; kk < 4; ++kk) {
            int q = kk * 32 + tt;
            int r = q & (m - 1);
            int j0 = ((q >> log2m) << log2n) + r;
            float a0x = cr[j0],       a0y = ci[j0];
            float a1x = cr[j0 + m],   a1y = ci[j0 + m];
            float a2x = cr[j0 + 2*m], a2y = ci[j0 + 2*m];
            float a3x = cr[j0 + 3*m], a3y = ci[j0 + 3*m];
            int e = r << (2 * s4);
            float c1 = twc[e],   s1 = tws[e];
            float c2 = twc[2*e], s2 = tws[2*e];
            float c3 = twc[3*e], s3 = tws[3*e];
            float t1x = a1x*c1 + a1y*s1,  t1y = a1y*c1 - a1x*s1;
            float t2x = a2x*c2 + a2y*s2,  t2y = a2y*c2 - a2x*s2;
            float t3x = a3x*c3 + a3y*s3,  t3y = a3y*c3 - a3x*s3;
            float s02x = a0x + t2x, s02y = a0y + t2y;
            float d02x = a0x - t2x, d02y = a0y - t2y;
            float s13x = t1x + t3x, s13y = t1y + t3y;
            float d13x = t1x - t3x, d13y = t1y - t3y;
            cr[j0]       = s02x + s13x;   ci[j0]       = s02y + s13y;
            cr[j0 + 2*m] = s02x - s13x;   ci[j0 + 2*m] = s02y - s13y;
            cr[j0 + m]   = d02x - d13y;   ci[j0 + m]   = d02y + d13x;
            cr[j0 + 3*m] = d02x + d13y;   ci[j0 + 3*m] = d02y - d13x;
        }
        __syncthreads();
    }
    #pragma unroll
    for (int ii = 0; ii < 8; ++ii) {
        int linear = ii * 512 + t;
        int cp = linear & 7;
        int e  = linear >> 3;
        int a0 = (cp * 2) * CSTR + e;
        int a1 = a0 + CSTR;
        float4 v = make_float4(re[a0], im[a0], re[a1], im[a1]);
        *reinterpret_cast<float4*>(&base[(size_t)e * 512 + cp * 2]) = v;
    }
}

// Inverse radix-4 FFT along W + 1/(H*W) scaling + |.|^2 + horizontal blur.
__global__ void k_mag_hblur(const float2* __restrict__ X, float* __restrict__ out) {
    __shared__ float re[2 * RSZ], im[2 * RSZ];
    __shared__ float twc[512], tws[512];
    int t = threadIdx.x;
    FILL_TW512(256)
    int lr = t >> 7;
    int u  = t & 127;
    int row = blockIdx.x * 2 + lr;
    const float2* p = X + (size_t)row * 512;
    float* rr = re + lr * RSZ;
    float* ri = im + lr * RSZ;
    #pragma unroll
    for (int k2 = 0; k2 < 2; ++k2) {
        int i = u * 4 + k2 * 2;
        float4 v = *reinterpret_cast<const float4*>(&p[i]);
        rr[RP(i)]     = v.x; ri[RP(i)]     = v.y;
        rr[RP(i + 1)] = v.z; ri[RP(i + 1)] = v.w;
    }
    __syncthreads();
    #pragma unroll
    for (int kk = 0; kk < 2; ++kk) {     // radix-2 first (mirror)
        int j = (kk * 128 + u) << 1;
        float ax = rr[RP(j)], ay = ri[RP(j)], bx = rr[RP(j + 1)], by = ri[RP(j + 1)];
        rr[RP(j)]     = ax + bx;  ri[RP(j)]     = ay + by;
        rr[RP(j + 1)] = ax - bx;  ri[RP(j + 1)] = ay - by;
    }
    __syncthreads();
    R4_INV(rr, ri, u, 3)  __syncthreads();
    R4_INV(rr, ri, u, 2)  __syncthreads();
    R4_INV(rr, ri, u, 1)  __syncthreads();
    R4_INV(rr, ri, u, 0)  __syncthreads();
    const float s = 3.814697265625e-06f;   // 1/262144, exact
    #pragma unroll
    for (int k4 = 0; k4 < 4; ++k4) {       // |.|^2 into ri
        int i = u * 4 + k4;
        float x = rr[RP(i)] * s, y = ri[RP(i)] * s;
        ri[RP(i)] = x * x + y * y;
    }
    __syncthreads();
    float* o = out + (size_t)row * 512;
    float4 res;
    #pragma unroll
    for (int k4 = 0; k4 < 4; ++k4) {
        int i = u * 4 + k4;
        float acc = GW2 * ri[RP(i)];
        if (i >= 1)   acc += GW1 * ri[RP(i - 1)];
        if (i >= 2)   acc += GW0 * ri[RP(i - 2)];
        if (i <= 510) acc += GW1 * ri[RP(i + 1)];
        if (i <= 509) acc += GW0 * ri[RP(i + 2)];
        ((float*)&res)[k4] = acc;
    }
    *reinterpret_cast<float4*>(o + u * 4) = res;
}

// Vertical blur (float4, 4 elems/thread) + per-BLOCK min/max partials.
// Also zeroes the hist/ccnt scratch region (replaces a runtime memset).
__global__ void k_vblur(const float* __restrict__ in, float* __restrict__ out,
                        float* __restrict__ pmn, float* __restrict__ pmx,
                        unsigned int* __restrict__ zr) {
    __shared__ float smn[256];
    __shared__ float smx[256];
    int t = threadIdx.x;
    int gi = blockIdx.x * 256 + t;
    if (gi < ZEROWORDS) zr[gi] = 0u;      // hists + ccnt live at ws[0..819264)
    int i = gi * 4;
    int y = (i >> 9) & 511;               // same row for all 4 elems (4 | 512)
    const float4 c = *reinterpret_cast<const float4*>(in + i);
    float4 acc = make_float4(GW2 * c.x, GW2 * c.y, GW2 * c.z, GW2 * c.w);
    if (y >= 1) {
        const float4 v = *reinterpret_cast<const float4*>(in + i - 512);
        acc.x += GW1 * v.x; acc.y += GW1 * v.y; acc.z += GW1 * v.z; acc.w += GW1 * v.w;
    }
    if (y >= 2) {
        const float4 v = *reinterpret_cast<const float4*>(in + i - 1024);
        acc.x += GW0 * v.x; acc.y += GW0 * v.y; acc.z += GW0 * v.z; acc.w += GW0 * v.w;
    }
    if (y <= 510) {
        const float4 v = *reinterpret_cast<const float4*>(in + i + 512);
        acc.x += GW1 * v.x; acc.y += GW1 * v.y; acc.z += GW1 * v.z; acc.w += GW1 * v.w;
    }
    if (y <= 509) {
        const float4 v = *reinterpret_cast<const float4*>(in + i + 1024);
        acc.x += GW0 * v.x; acc.y += GW0 * v.y; acc.z += GW0 * v.z; acc.w += GW0 * v.w;
    }
    *reinterpret_cast<float4*>(out + i) = acc;
    float lmn = fminf(fminf(acc.x, acc.y), fminf(acc.z, acc.w));
    float lmx = fmaxf(fmaxf(acc.x, acc.y), fmaxf(acc.z, acc.w));
    smn[t] = lmn; smx[t] = lmx;
    __syncthreads();
    for (int s = 128; s > 0; s >>= 1) {
        if (t < s) { smn[t] = fminf(smn[t], smn[t + s]); smx[t] = fmaxf(smx[t], smx[t + s]); }
        __syncthreads();
    }
    if (t == 0) { pmn[blockIdx.x] = smn[0]; pmx[blockIdx.x] = smx[0]; }
}

// Normalize + border mask -> final saliency (d_out), fused with hist round 1.
// Each block redundantly folds its image's 256 min/max partials first.
__global__ void k_norm_hist(const float* __restrict__ in, const float* __restrict__ pmn,
                            const float* __restrict__ pmx, float* __restrict__ out,
                            unsigned int* __restrict__ g) {
    __shared__ unsigned int h[4096];
    __shared__ float smn[256], smx[256];
    int t = threadIdx.x;
    int b = blockIdx.x >> 5;
    int base = b * HW + (blockIdx.x & 31) * 8192;
    smn[t] = pmn[b * 256 + t];
    smx[t] = pmx[b * 256 + t];
    for (int i = t; i < 4096; i += 256) h[i] = 0u;
    __syncthreads();
    for (int s = 128; s > 0; s >>= 1) {
        if (t < s) { smn[t] = fminf(smn[t], smn[t + s]); smx[t] = fmaxf(smx[t], smx[t + s]); }
        __syncthreads();
    }
    float mn = smn[0], mx = smx[0];
    float inv = 1.0f / (mx - mn + 1e-8f);
    for (int j = 0; j < 32; ++j) {
        int idx = base + j * 256 + t;
        float v = (in[idx] - mn) * inv;
        int xx = idx & 511, yy = (idx >> 9) & 511;
        bool inside = (xx >= 12) && (xx < 500) && (yy >= 12) && (yy < 500);
        v = inside ? v : 0.0f;
        out[idx] = v;
        atomicAdd(&h[__float_as_uint(v) >> 20], 1u);
    }
    __syncthreads();
    unsigned int* gb = g + b * 4096;
    for (int i = t; i < 4096; i += 256)
        if (h[i]) atomicAdd(&gb[i], h[i]);
}

// ---------------------------------------------------------------------------
// PARALLEL radix_step: find largest bin B with suffix-count(B) >= krem and
// the remainder krem' = krem - suffix(B+1). Hillis-Steele suffix scan across
// 256 threads + unique-boundary publication (no serial thread-0 walk, no
// atomics). Semantically identical to the previous serial version.
// ---------------------------------------------------------------------------
__device__ void radix_step(const unsigned int* __restrict__ h, int nbins, int krem,
                           int t, unsigned int* tsuf, int* sbin, int* skrem) {
    int bpt = nbins >> 8;
    unsigned int s = 0;
    for (int j = 0; j < bpt; ++j) s += h[t * bpt + j];
    tsuf[t] = s;
    __syncthreads();
    #pragma unroll
    for (int off = 1; off < 256; off <<= 1) {
        unsigned int v = (t + off < 256) ? tsuf[t + off] : 0u;
        __syncthreads();
        tsuf[t] += v;
        __syncthreads();
    }
    // unique t with tsuf[t] >= krem > tsuf[t+1]  (tsuf non-increasing)
    if ((int)tsuf[t] >= krem && (t == 255 || (int)tsuf[t + 1] < krem))
        *sbin = t;
    __syncthreads();
    int seg = *sbin;
    int krem2 = krem - (seg < 255 ? (int)tsuf[seg + 1] : 0);
    __syncthreads();            // all threads have read seg before overwrite
    if (t < bpt) {
        unsigned int L = 0;
        for (int j = t; j < bpt; ++j) L += h[seg * bpt + j];
        unsigned int hv = h[seg * bpt + t];
        // unique j with L(j) >= krem2 > L(j+1) = L - hv
        if ((int)L >= krem2 && (int)(L - hv) < krem2) {
            *sbin  = seg * bpt + t;
            *skrem = krem2 - (int)(L - hv);
        }
    }
    __syncthreads();
}

// Round-2 histograms, with round-1 scan fused (redundant per block; integer
// ops -> identical result in every block). Designated blocks publish stats.
__global__ void k_hist2(const float* __restrict__ sal, const unsigned int* __restrict__ g1,
                        unsigned int* __restrict__ gA, unsigned int* __restrict__ gB,
                        unsigned int* prefA1, int* kremA1, unsigned int* prefB1, int* kremB1) {
    __shared__ unsigned int hA[4096];
    __shared__ unsigned int hB[4096];
    __shared__ unsigned int tsuf[256];
    __shared__ int sbin, skrem;
    int t = threadIdx.x;
    int b = blockIdx.x >> 5;
    int start = (blockIdx.x & 31) * 8192;
    for (int i = t; i < 4096; i += 256) { hA[i] = 0u; hB[i] = 0u; }
    radix_step(g1 + b * 4096, 4096, KSEL, t, tsuf, &sbin, &skrem);
    unsigned int pA = (unsigned int)sbin; int krA = skrem;
    radix_step(g1 + b * 4096, 4096, MCAND, t, tsuf, &sbin, &skrem);
    unsigned int pB = (unsigned int)sbin; int krB = skrem;
    if (t == 0 && (blockIdx.x & 31) == 0) {
        prefA1[b] = pA; kremA1[b] = krA; prefB1[b] = pB; kremB1[b] = krB;
    }
    const float* p = sal + (size_t)b * HW;
    for (int j = 0; j < 32; ++j) {
        unsigned int u = __float_as_uint(p[start + j * 256 + t]);
        unsigned int hi = u >> 20, mid = (u >> 8) & 4095u;
        if (hi == pA) atomicAdd(&hA[mid], 1u);
        if (hi == pB) atomicAdd(&hB[mid], 1u);
    }
    __syncthreads();
    unsigned int* ga = gA + b * 4096;
    unsigned int* gb2 = gB + b * 4096;
    for (int i = t; i < 4096; i += 256) {
        if (hA[i]) atomicAdd(&ga[i], hA[i]);
        if (hB[i]) atomicAdd(&gb2[i], hB[i]);
    }
}

// Round-3 A-histogram + candidate collection, with round-2 scan fused.
// cutoffB = bucket floor of the unfiltered 80th value: every top-80 candidate
// is >= it; sub-thr extras are filtered exactly in k_final.
__global__ void k_hist3collect(const float* __restrict__ sal,
                               const unsigned int* __restrict__ gA2, const unsigned int* __restrict__ gB2,
                               const unsigned int* prefA1, const int* kremA1,
                               const unsigned int* prefB1, const int* kremB1,
                               unsigned int* __restrict__ gA3,
                               unsigned int* prefA24, int* kremA2,
                               float* __restrict__ candv, int* __restrict__ candi,
                               int* __restrict__ ccnt) {
    __shared__ unsigned int hA[256];
    __shared__ unsigned int tsuf[256];
    __shared__ int sbin, skrem;
    int t = threadIdx.x;
    int b = blockIdx.x >> 5;
    int start = (blockIdx.x & 31) * 8192;
    hA[t] = 0u;
    radix_step(gA2 + b * 4096, 4096, kremA1[b], t, tsuf, &sbin, &skrem);
    unsigned int pA = (prefA1[b] << 12) | (unsigned int)sbin;
    int krA2 = skrem;
    radix_step(gB2 + b * 4096, 4096, kremB1[b], t, tsuf, &sbin, &skrem);
    unsigned int cutB = ((prefB1[b] << 12) | (unsigned int)sbin) << 8;
    if (t == 0 && (blockIdx.x & 31) == 0) { prefA24[b] = pA; kremA2[b] = krA2; }
    const float* p = sal + (size_t)b * HW;
    for (int j = 0; j < 32; ++j) {
        int i = start + j * 256 + t;
        unsigned int u = __float_as_uint(p[i]);
        if ((u >> 8) == pA) atomicAdd(&hA[u & 255u], 1u);
        if (u >= cutB) {
            int pos = atomicAdd(&ccnt[b], 1);
            if (pos < CAP) { candv[b * CAP + pos] = p[i]; candi[b * CAP + pos] = i; }
        }
    }
    __syncthreads();
    if (hA[t]) atomicAdd(&gA3[b * 256 + t], hA[t]);
}

// Final: derive exact thr from hist3a, rank (value desc, index asc), bitmask
// greedy NMS with validity v >= thr (matches reference -inf filtering).
__global__ void k_final(const unsigned int* __restrict__ gA3,
                        const unsigned int* prefA24, const int* kremA2,
                        const float* __restrict__ candv, const int* __restrict__ candi,
                        const int* __restrict__ ccnt, float* __restrict__ out) {
    __shared__ float cval[CAP];
    __shared__ int   cidx[CAP];
    __shared__ int   si[MCAND];
    __shared__ float svv[MCAND];
    __shared__ float sx[MCAND];
    __shared__ float sy[MCAND];
    __shared__ unsigned long long nearLo[MCAND];
    __shared__ unsigned long long nearHi[MCAND];
    __shared__ unsigned int tsuf[256];
    __shared__ int sbin, skrem;
    int b = blockIdx.x, t = threadIdx.x;
    radix_step(gA3 + b * 256, 256, kremA2[b], t, tsuf, &sbin, &skrem);
    float thr = fmaxf(__uint_as_float((prefA24[b] << 8) | (unsigned int)sbin), 0.1f);
    int n = min(ccnt[b], CAP);
    for (int i = t; i < n; i += 256) { cval[i] = candv[b * CAP + i]; cidx[i] = candi[b * CAP + i]; }
    __syncthreads();
    int m = min(n, MCAND);
    for (int i = t; i < n; i += 256) {
        float vi = cval[i]; int ii = cidx[i];
        int rank = 0;
        for (int j = 0; j < n; j++) {
            float vj = cval[j];
            if (vj > vi || (vj == vi && cidx[j] < ii)) rank++;
        }
        if (rank < MCAND) { si[rank] = ii; svv[rank] = vi; }
    }
    __syncthreads();
    for (int i = t; i < m; i += 256) {
        sx[i] = (float)(si[i] & 511);
        sy[i] = (float)(si[i] >> 9);
    }
    __syncthreads();
    for (int i = t; i < m; i += 256) {
        unsigned long long lo = 0ull, hi = 0ull;
        float x = sx[i], y = sy[i];
        for (int j = 0; j < m; j++) {
            float dx = sx[j] - x, dy = sy[j] - y;
            if (dx * dx + dy * dy < 100.0f) {
                if (j < 64) lo |= (1ull << j);
                else        hi |= (1ull << (j - 64));
            }
        }
        nearLo[i] = lo; nearHi[i] = hi;
    }
    __syncthreads();
    if (t == 0) {
        unsigned long long kLo = 0ull, kHi = 0ull;
        int cnt = 0;
        for (int i = 0; i < m; i++) {
            bool near_kept = ((nearLo[i] & kLo) | (nearHi[i] & kHi)) != 0ull;
            if (svv[i] >= thr && !near_kept) {
                out[b * 10 + 2 * cnt]     = sx[i];
                out[b * 10 + 2 * cnt + 1] = sy[i];
                out[160 + b * 5 + cnt]    = 1.0f;
                if (i < 64) kLo |= (1ull << i); else kHi |= (1ull << (i - 64));
                cnt++;
                if (cnt == TOPK) break;
            }
        }
        for (int j = cnt; j < TOPK; j++) {
            out[b * 10 + 2 * j]     = -1.0f;
            out[b * 10 + 2 * j + 1] = -1.0f;
            out[160 + b * 5 + j]    = -1.0f;
        }
    }
}

extern "C" void kernel_launch(void* const* d_in, const int* in_sizes, int n_in,
                              void* d_out, int out_size, void* d_ws, size_t ws_size,
                              hipStream_t stream) {
    const float* img = (const float*)d_in[0];
    float* out = (float*)d_out;
    char* ws = (char*)d_ws;

    float2* A    = (float2*)ws;
    float*  hb   = (float*)(ws + 33554432UL);
    float*  salb = (float*)(ws + 50331648UL);

    unsigned int* hist1  = (unsigned int*)(ws + 0UL);
    unsigned int* hist2a = (unsigned int*)(ws + 262144UL);
    unsigned int* hist2b = (unsigned int*)(ws + 524288UL);
    unsigned int* hist3a = (unsigned int*)(ws + 786432UL);
    int*          ccnt   = (int*)(ws + 819200UL);
    float*        candv  = (float*)(ws + 851968UL);
    int*          candi  = (int*)(ws + 983040UL);

    float* pmn = (float*)(ws + 20971520UL);                 // 4096 f32
    float* pmx = (float*)(ws + 21037056UL);                 // 4096 f32

    char* stats = ws + 67108864UL;
    unsigned int* prefA1  = (unsigned int*)(stats + 0);
    int*          kremA1  = (int*)(stats + 64);
    unsigned int* prefB1  = (unsigned int*)(stats + 128);
    int*          kremB1  = (int*)(stats + 192);
    unsigned int* prefA24 = (unsigned int*)(stats + 256);
    int*          kremA2  = (int*)(stats + 320);

    float* salout = out + 240;   // sal region of d_out

    k_win_rowfft<<<dim3(4096), dim3(256), 0, stream>>>(img, A);     // radix-4 W fwd
    k_colfft<<<dim3(512), dim3(512), 0, stream>>>(A);               // radix-4 H pass
    k_mag_hblur<<<dim3(4096), dim3(256), 0, stream>>>(A, hb);       // radix-4 W inv + mag + hblur
    k_vblur<<<dim3(4096), dim3(256), 0, stream>>>(hb, salb, pmn, pmx,
                                                  (unsigned int*)ws); // + zero hists/ccnt
    k_norm_hist<<<dim3(512), dim3(256), 0, stream>>>(salb, pmn, pmx, salout, hist1);
    k_hist2<<<dim3(512), dim3(256), 0, stream>>>(salout, hist1, hist2a, hist2b,
                                                 prefA1, kremA1, prefB1, kremB1);
    k_hist3collect<<<dim3(512), dim3(256), 0, stream>>>(salout, hist2a, hist2b,
                                                        prefA1, kremA1, prefB1, kremB1,
                                                        hist3a, prefA24, kremA2,
                                                        candv, candi, ccnt);
    k_final<<<dim3(BATCH), dim3(256), 0, stream>>>(hist3a, prefA24, kremA2,
                                                   candv, candi, ccnt, out);
}

// Round 13
// 152.370 us; speedup vs baseline: 1.7188x; 1.0141x over previous
//
#include <hip/hip_runtime.h>
#include <math.h>

#define BATCH 16
#define HW 262144          // 512*512
#define KSEL 26214         // int(0.1 * 262144)
#define MCAND 80           // TOP_K * CAND_MULT
#define TOPK 5
#define CAP 2048
#define ZEROWORDS 204816   // (hists + ccnt) bytes / 4, zeroed inside k_vblur

// ---------------------------------------------------------------------------
// In-place FFT, N=512, mixed radix-4 (4 stages) + radix-2 (1 stage) on all
// axes. Forward DIF: natural -> digit-reversed; inverse DIT (conj twiddles,
// mirrored stage order): digit-reversed -> natural. DIT(DIF(x)) = 512*x
// elementwise, so the digit-reversed intermediate order is unobservable.
// k_colfft combines stage pairs in registers (radix-16 via 2x radix-4):
// each thread owns 16 elements, halving LDS stage traffic.
// Twiddles from LDS table tw[i] = e^{-2*pi*i/512} (tw[i+256] = -tw[i]).
// ---------------------------------------------------------------------------

// Gaussian blur coefficients, sigma=1, 5-tap.
#define GW0 0.05448868454964294f
#define GW1 0.24420134200323332f
#define GW2 0.40261994689424746f

#define FILL_TW512(nthr)                                       \
    for (int i_ = threadIdx.x; i_ < 256; i_ += (nthr)) {       \
        float rev_ = -(float)i_ * (1.0f / 512.0f);             \
        float s_ = __builtin_amdgcn_sinf(rev_);                \
        float c_ = __builtin_amdgcn_cosf(rev_);                \
        tws[i_] = s_;        twc[i_] = c_;                     \
        tws[i_ + 256] = -s_; twc[i_ + 256] = -c_;              \
    }

// LDS pad-every-16: breaks power-of-2 stride conflicts (<=4-way worst).
#define RP(a) ((a) + ((a) >> 4))
#define RSZ 544             // 512 + 32 pad floats per row

// Radix-4 DIF forward butterfly via LDS (1 per thread), q = butterfly idx.
#define R4_FWD(rr, ri, q, s4)                                                 \
    {                                                                          \
        const int log2n = 9 - 2 * (s4);                                        \
        const int log2m = log2n - 2;                                           \
        const int m = 1 << log2m;                                              \
        int r = (q) & (m - 1);                                                 \
        int j0 = (((q) >> log2m) << log2n) + r;                                \
        float a0x = rr[RP(j0)],       a0y = ri[RP(j0)];                        \
        float a1x = rr[RP(j0 + m)],   a1y = ri[RP(j0 + m)];                    \
        float a2x = rr[RP(j0 + 2*m)], a2y = ri[RP(j0 + 2*m)];                  \
        float a3x = rr[RP(j0 + 3*m)], a3y = ri[RP(j0 + 3*m)];                  \
        float s02x = a0x + a2x, s02y = a0y + a2y;                              \
        float d02x = a0x - a2x, d02y = a0y - a2y;                              \
        float s13x = a1x + a3x, s13y = a1y + a3y;                              \
        float d13x = a1x - a3x, d13y = a1y - a3y;                              \
        float y0x = s02x + s13x, y0y = s02y + s13y;                            \
        float y2x = s02x - s13x, y2y = s02y - s13y;                            \
        float y1x = d02x + d13y, y1y = d02y - d13x;                            \
        float y3x = d02x - d13y, y3y = d02y + d13x;                            \
        int e = r << (2 * (s4));                                               \
        float c1 = twc[e],   s1 = tws[e];                                      \
        float c2 = twc[2*e], s2 = tws[2*e];                                    \
        float c3 = twc[3*e], s3 = tws[3*e];                                    \
        rr[RP(j0)]       = y0x;             ri[RP(j0)]       = y0y;            \
        rr[RP(j0 + m)]   = y1x*c1 - y1y*s1; ri[RP(j0 + m)]   = y1x*s1 + y1y*c1;\
        rr[RP(j0 + 2*m)] = y2x*c2 - y2y*s2; ri[RP(j0 + 2*m)] = y2x*s2 + y2y*c2;\
        rr[RP(j0 + 3*m)] = y3x*c3 - y3y*s3; ri[RP(j0 + 3*m)] = y3x*s3 + y3y*c3;\
    }

// Radix-4 DIT inverse butterfly via LDS (conj twiddles), mirror of R4_FWD.
#define R4_INV(rr, ri, q, s4)                                                 \
    {                                                                          \
        const int log2n = 9 - 2 * (s4);                                        \
        const int log2m = log2n - 2;                                           \
        const int m = 1 << log2m;                                              \
        int r = (q) & (m - 1);                                                 \
        int j0 = (((q) >> log2m) << log2n) + r;                                \
        float a0x = rr[RP(j0)],       a0y = ri[RP(j0)];                        \
        float a1x = rr[RP(j0 + m)],   a1y = ri[RP(j0 + m)];                    \
        float a2x = rr[RP(j0 + 2*m)], a2y = ri[RP(j0 + 2*m)];                  \
        float a3x = rr[RP(j0 + 3*m)], a3y = ri[RP(j0 + 3*m)];                  \
        int e = r << (2 * (s4));                                               \
        float c1 = twc[e],   s1 = tws[e];                                      \
        float c2 = twc[2*e], s2 = tws[2*e];                                    \
        float c3 = twc[3*e], s3 = tws[3*e];                                    \
        float t1x = a1x*c1 + a1y*s1,  t1y = a1y*c1 - a1x*s1;                   \
        float t2x = a2x*c2 + a2y*s2,  t2y = a2y*c2 - a2x*s2;                   \
        float t3x = a3x*c3 + a3y*s3,  t3y = a3y*c3 - a3x*s3;                   \
        float s02x = a0x + t2x, s02y = a0y + t2y;                              \
        float d02x = a0x - t2x, d02y = a0y - t2y;                              \
        float s13x = t1x + t3x, s13y = t1y + t3y;                              \
        float d13x = t1x - t3x, d13y = t1y - t3y;                              \
        rr[RP(j0)]       = s02x + s13x;  ri[RP(j0)]       = s02y + s13y;       \
        rr[RP(j0 + 2*m)] = s02x - s13x;  ri[RP(j0 + 2*m)] = s02y - s13y;       \
        rr[RP(j0 + m)]   = d02x - d13y;  ri[RP(j0 + m)]   = d02y + d13x;       \
        rr[RP(j0 + 3*m)] = d02x + d13y;  ri[RP(j0 + 3*m)] = d02y - d13x;       \
    }

// Register radix-4 DIF butterfly (outputs in place, twiddles applied).
#define R4F_REG(x0,y0,x1,y1,x2,y2,x3,y3, e)                                   \
    { float s02x=(x0)+(x2), s02y=(y0)+(y2), d02x=(x0)-(x2), d02y=(y0)-(y2);    \
      float s13x=(x1)+(x3), s13y=(y1)+(y3), d13x=(x1)-(x3), d13y=(y1)-(y3);    \
      float z0x=s02x+s13x, z0y=s02y+s13y;                                      \
      float z2x=s02x-s13x, z2y=s02y-s13y;                                      \
      float z1x=d02x+d13y, z1y=d02y-d13x;                                      \
      float z3x=d02x-d13y, z3y=d02y+d13x;                                      \
      float c1=twc[(e)], s1=tws[(e)], c2=twc[2*(e)], s2=tws[2*(e)];            \
      float c3=twc[3*(e)], s3=tws[3*(e)];                                      \
      x0=z0x; y0=z0y;                                                          \
      x1=z1x*c1-z1y*s1; y1=z1x*s1+z1y*c1;                                      \
      x2=z2x*c2-z2y*s2; y2=z2x*s2+z2y*c2;                                      \
      x3=z3x*c3-z3y*s3; y3=z3x*s3+z3y*c3; }

// Register radix-4 DIT inverse butterfly (conj twiddles first).
#define R4I_REG(x0,y0,x1,y1,x2,y2,x3,y3, e)                                   \
    { float c1=twc[(e)], s1=tws[(e)], c2=twc[2*(e)], s2=tws[2*(e)];            \
      float c3=twc[3*(e)], s3=tws[3*(e)];                                      \
      float t1x=(x1)*c1+(y1)*s1, t1y=(y1)*c1-(x1)*s1;                          \
      float t2x=(x2)*c2+(y2)*s2, t2y=(y2)*c2-(x2)*s2;                          \
      float t3x=(x3)*c3+(y3)*s3, t3y=(y3)*c3-(x3)*s3;                          \
      float s02x=(x0)+t2x, s02y=(y0)+t2y, d02x=(x0)-t2x, d02y=(y0)-t2y;        \
      float s13x=t1x+t3x, s13y=t1y+t3y, d13x=t1x-t3x, d13y=t1y-t3y;            \
      x0=s02x+s13x; y0=s02y+s13y;                                              \
      x2=s02x-s13x; y2=s02y-s13y;                                              \
      x1=d02x-d13y; y1=d02y+d13x;                                              \
      x3=d02x+d13y; y3=d02y-d13x; }

// K1: window + forward radix-4 FFT along W. 2 rows per 256-thread block.
__global__ void k_win_rowfft(const float* __restrict__ img, float2* __restrict__ A) {
    __shared__ float re[2 * RSZ], im[2 * RSZ];
    __shared__ float twc[512], tws[512];
    int t = threadIdx.x;
    FILL_TW512(256)
    int lr = t >> 7;                 // local row 0/1
    int u  = t & 127;                // per-row lane
    int row = blockIdx.x * 2 + lr;   // b*512 + h
    int h = row & 511;
    float wr = 0.5f * (1.0f - __builtin_amdgcn_cosf((float)h * (1.0f / 511.0f)));
    const float* p = img + (size_t)row * 512;
    float* rr = re + lr * RSZ;
    float* ri = im + lr * RSZ;
    {
        int i0 = u * 4;
        float4 v = *reinterpret_cast<const float4*>(p + i0);
        float w0 = 0.5f * (1.0f - __builtin_amdgcn_cosf((float)(i0 + 0) * (1.0f / 511.0f)));
        float w1 = 0.5f * (1.0f - __builtin_amdgcn_cosf((float)(i0 + 1) * (1.0f / 511.0f)));
        float w2 = 0.5f * (1.0f - __builtin_amdgcn_cosf((float)(i0 + 2) * (1.0f / 511.0f)));
        float w3 = 0.5f * (1.0f - __builtin_amdgcn_cosf((float)(i0 + 3) * (1.0f / 511.0f)));
        rr[RP(i0 + 0)] = v.x * wr * w0;  ri[RP(i0 + 0)] = 0.0f;
        rr[RP(i0 + 1)] = v.y * wr * w1;  ri[RP(i0 + 1)] = 0.0f;
        rr[RP(i0 + 2)] = v.z * wr * w2;  ri[RP(i0 + 2)] = 0.0f;
        rr[RP(i0 + 3)] = v.w * wr * w3;  ri[RP(i0 + 3)] = 0.0f;
    }
    __syncthreads();
    R4_FWD(rr, ri, u, 0)  __syncthreads();
    R4_FWD(rr, ri, u, 1)  __syncthreads();
    R4_FWD(rr, ri, u, 2)  __syncthreads();
    R4_FWD(rr, ri, u, 3)  __syncthreads();
    #pragma unroll
    for (int kk = 0; kk < 2; ++kk) {     // final radix-2 (2 butterflies/thread)
        int j = (kk * 128 + u) << 1;
        float ax = rr[RP(j)], ay = ri[RP(j)], bx = rr[RP(j + 1)], by = ri[RP(j + 1)];
        rr[RP(j)]     = ax + bx;  ri[RP(j)]     = ay + by;
        rr[RP(j + 1)] = ax - bx;  ri[RP(j + 1)] = ay - by;
    }
    __syncthreads();
    float2* out = A + (size_t)row * 512;
    #pragma unroll
    for (int k2 = 0; k2 < 2; ++k2) {
        int i = u * 4 + k2 * 2;
        float4 v = make_float4(rr[RP(i)], ri[RP(i)], rr[RP(i + 1)], ri[RP(i + 1)]);
        *reinterpret_cast<float4*>(&out[i]) = v;
    }
}

// Fused H-axis pass on 512x16 column tiles. Stage pairs combined in registers
// (radix-16 = 2x radix-4): each thread owns one 16-element group.
#define CSTR 514
__global__ __launch_bounds__(512) void k_colfft(float2* __restrict__ X) {
    __shared__ float re[16 * CSTR];
    __shared__ float im[16 * CSTR];
    __shared__ float twc[512], tws[512];
    int b = blockIdx.x >> 5;
    int c0 = (blockIdx.x & 31) * 16;
    int t = threadIdx.x;
    FILL_TW512(512)
    float2* base = X + (size_t)b * HW + c0;
    #pragma unroll
    for (int ii = 0; ii < 8; ++ii) {
        int linear = ii * 512 + t;
        int cp = linear & 7;
        int e  = linear >> 3;
        const float4 v = *reinterpret_cast<const float4*>(&base[(size_t)e * 512 + cp * 2]);
        int a0 = (cp * 2) * CSTR + e;
        int a1 = a0 + CSTR;
        re[a0] = v.x; im[a0] = v.y;
        re[a1] = v.z; im[a1] = v.w;
    }
    __syncthreads();
    int c = t & 15, tt = t >> 4;          // 32 threads per column
    float* cr = re + c * CSTR;
    float* ci = im + c * CSTR;
    float rx[4][4], ry[4][4];             // [a][b], fully unrolled (no scratch)

    // ---- forward pair 1: stages s4=0 (m=128) + s4=1 (m=32) ----
    // group elements j(a,b) = tt + 128a + 32b
    #pragma unroll
    for (int a = 0; a < 4; ++a)
        #pragma unroll
        for (int bq = 0; bq < 4; ++bq) {
            int j = tt + a * 128 + bq * 32;
            rx[a][bq] = cr[j]; ry[a][bq] = ci[j];
        }
    #pragma unroll
    for (int bq = 0; bq < 4; ++bq) {      // stage s4=0: quad over a, e = tt+32b
        int e = tt + bq * 32;
        R4F_REG(rx[0][bq], ry[0][bq], rx[1][bq], ry[1][bq],
                rx[2][bq], ry[2][bq], rx[3][bq], ry[3][bq], e)
    }
    {
        int e = tt << 2;                  // stage s4=1: quad over b, e = tt<<2
        #pragma unroll
        for (int a = 0; a < 4; ++a)
            R4F_REG(rx[a][0], ry[a][0], rx[a][1], ry[a][1],
                    rx[a][2], ry[a][2], rx[a][3], ry[a][3], e)
    }
    #pragma unroll
    for (int a = 0; a < 4; ++a)
        #pragma unroll
        for (int bq = 0; bq < 4; ++bq) {
            int j = tt + a * 128 + bq * 32;
            cr[j] = rx[a][bq]; ci[j] = ry[a][bq];
        }
    __syncthreads();

    // ---- forward pair 2: stages s4=2 (m=8) + s4=3 (m=2) ----
    // group: blk = tt>>1, r = tt&1; j(a,b) = 32*blk + r + 8a + 2b
    {
        int blk = tt >> 1, r = tt & 1;
        int jb = blk * 32 + r;
        #pragma unroll
        for (int a = 0; a < 4; ++a)
            #pragma unroll
            for (int bq = 0; bq < 4; ++bq) {
                int j = jb + a * 8 + bq * 2;
                rx[a][bq] = cr[j]; ry[a][bq] = ci[j];
            }
        #pragma unroll
        for (int bq = 0; bq < 4; ++bq) {  // stage s4=2: quad over a, e=(r+2b)<<4
            int e = (r + 2 * bq) << 4;
            R4F_REG(rx[0][bq], ry[0][bq], rx[1][bq], ry[1][bq],
                    rx[2][bq], ry[2][bq], rx[3][bq], ry[3][bq], e)
        }
        {
            int e = r << 6;               // stage s4=3: quad over b, e = r<<6
            #pragma unroll
            for (int a = 0; a < 4; ++a)
                R4F_REG(rx[a][0], ry[a][0], rx[a][1], ry[a][1],
                        rx[a][2], ry[a][2], rx[a][3], ry[a][3], e)
        }
        #pragma unroll
        for (int a = 0; a < 4; ++a)
            #pragma unroll
            for (int bq = 0; bq < 4; ++bq) {
                int j = jb + a * 8 + bq * 2;
                cr[j] = rx[a][bq]; ci[j] = ry[a][bq];
            }
    }
    __syncthreads();
    // ---- forward final radix-2 (m=1) ----
    #pragma unroll
    for (int kk = 0; kk < 8; ++kk) {
        int j = (kk * 32 + tt) << 1;
        float ax = cr[j], ay = ci[j], bx = cr[j+1], by = ci[j+1];
        cr[j]   = ax + bx; ci[j]   = ay + by;
        cr[j+1] = ax - bx; ci[j+1] = ay - by;
    }
    __syncthreads();
    // ---- phase-only normalize (elementwise; order-agnostic) ----
    #pragma unroll
    for (int ii = 0; ii < 16; ++ii) {
        int linear = ii * 512 + t;
        int cc = linear & 15, e = linear >> 4;
        int a = cc * CSTR + e;
        float x = re[a], y = im[a];
        float m2 = x * x + y * y;
        if (m2 > 0.0f) {
            float inv = rsqrtf(m2);
            re[a] = x * inv; im[a] = y * inv;
        } else {
            re[a] = 1.0f; im[a] = 0.0f;
        }
    }
    __syncthreads();
    // ---- inverse radix-2 first (mirror) ----
    #pragma unroll
    for (int kk = 0; kk < 8; ++kk) {
        int j = (kk * 32 + tt) << 1;
        float ax = cr[j], ay = ci[j], bx = cr[j+1], by = ci[j+1];
        cr[j]   = ax + bx; ci[j]   = ay + by;
        cr[j+1] = ax - bx; ci[j+1] = ay - by;
    }
    __syncthreads();
    // ---- inverse pair 2: stages s4=3 then s4=2 (conj twiddles) ----
    {
        int blk = tt >> 1, r = tt & 1;
        int jb = blk * 32 + r;
        #pragma unroll
        for (int a = 0; a < 4; ++a)
            #pragma unroll
            for (int bq = 0; bq < 4; ++bq) {
                int j = jb + a * 8 + bq * 2;
                rx[a][bq] = cr[j]; ry[a][bq] = ci[j];
            }
        {
            int e = r << 6;               // undo s4=3: quad over b
            #pragma unroll
            for (int a = 0; a < 4; ++a)
                R4I_REG(rx[a][0], ry[a][0], rx[a][1], ry[a][1],
                        rx[a][2], ry[a][2], rx[a][3], ry[a][3], e)
        }
        #pragma unroll
        for (int bq = 0; bq < 4; ++bq) {  // undo s4=2: quad over a
            int e = (r + 2 * bq) << 4;
            R4I_REG(rx[0][bq], ry[0][bq], rx[1][bq], ry[1][bq],
                    rx[2][bq], ry[2][bq], rx[3][bq], ry[3][bq], e)
        }
        #pragma unroll
        for (int a = 0; a < 4; ++a)
            #pragma unroll
            for (int bq = 0; bq < 4; ++bq) {
                int j = jb + a * 8 + bq * 2;
                cr[j] = rx[a][bq]; ci[j] = ry[a][bq];
            }
    }
    __syncthreads();
    // ---- inverse pair 1: stages s4=1 then s4=0 (conj twiddles) ----
    #pragma unroll
    for (int a = 0; a < 4; ++a)
        #pragma unroll
        for (int bq = 0; bq < 4; ++bq) {
            int j = tt + a * 128 + bq * 32;
            rx[a][bq] = cr[j]; ry[a][bq] = ci[j];
        }
    {
        int e = tt << 2;                  // undo s4=1: quad over b
        #pragma unroll
        for (int a = 0; a < 4; ++a)
            R4I_REG(rx[a][0], ry[a][0], rx[a][1], ry[a][1],
                    rx[a][2], ry[a][2], rx[a][3], ry[a][3], e)
    }
    #pragma unroll
    for (int bq = 0; bq < 4; ++bq) {      // undo s4=0: quad over a
        int e = tt + bq * 32;
        R4I_REG(rx[0][bq], ry[0][bq], rx[1][bq], ry[1][bq],
                rx[2][bq], ry[2][bq], rx[3][bq], ry[3][bq], e)
    }
    #pragma unroll
    for (int a = 0; a < 4; ++a)
        #pragma unroll
        for (int bq = 0; bq < 4; ++bq) {
            int j = tt + a * 128 + bq * 32;
            cr[j] = rx[a][bq]; ci[j] = ry[a][bq];
        }
    __syncthreads();
    #pragma unroll
    for (int ii = 0; ii < 8; ++ii) {
        int linear = ii * 512 + t;
        int cp = linear & 7;
        int e  = linear >> 3;
        int a0 = (cp * 2) * CSTR + e;
        int a1 = a0 + CSTR;
        float4 v = make_float4(re[a0], im[a0], re[a1], im[a1]);
        *reinterpret_cast<float4*>(&base[(size_t)e * 512 + cp * 2]) = v;
    }
}

// Inverse radix-4 FFT along W + 1/(H*W) scaling + |.|^2 + horizontal blur.
__global__ void k_mag_hblur(const float2* __restrict__ X, float* __restrict__ out) {
    __shared__ float re[2 * RSZ], im[2 * RSZ];
    __shared__ float twc[512], tws[512];
    int t = threadIdx.x;
    FILL_TW512(256)
    int lr = t >> 7;
    int u  = t & 127;
    int row = blockIdx.x * 2 + lr;
    const float2* p = X + (size_t)row * 512;
    float* rr = re + lr * RSZ;
    float* ri = im + lr * RSZ;
    #pragma unroll
    for (int k2 = 0; k2 < 2; ++k2) {
        int i = u * 4 + k2 * 2;
        float4 v = *reinterpret_cast<const float4*>(&p[i]);
        rr[RP(i)]     = v.x; ri[RP(i)]     = v.y;
        rr[RP(i + 1)] = v.z; ri[RP(i + 1)] = v.w;
    }
    __syncthreads();
    #pragma unroll
    for (int kk = 0; kk < 2; ++kk) {     // radix-2 first (mirror)
        int j = (kk * 128 + u) << 1;
        float ax = rr[RP(j)], ay = ri[RP(j)], bx = rr[RP(j + 1)], by = ri[RP(j + 1)];
        rr[RP(j)]     = ax + bx;  ri[RP(j)]     = ay + by;
        rr[RP(j + 1)] = ax - bx;  ri[RP(j + 1)] = ay - by;
    }
    __syncthreads();
    R4_INV(rr, ri, u, 3)  __syncthreads();
    R4_INV(rr, ri, u, 2)  __syncthreads();
    R4_INV(rr, ri, u, 1)  __syncthreads();
    R4_INV(rr, ri, u, 0)  __syncthreads();
    const float s = 3.814697265625e-06f;   // 1/262144, exact
    #pragma unroll
    for (int k4 = 0; k4 < 4; ++k4) {       // |.|^2 into ri
        int i = u * 4 + k4;
        float x = rr[RP(i)] * s, y = ri[RP(i)] * s;
        ri[RP(i)] = x * x + y * y;
    }
    __syncthreads();
    float* o = out + (size_t)row * 512;
    float4 res;
    #pragma unroll
    for (int k4 = 0; k4 < 4; ++k4) {
        int i = u * 4 + k4;
        float acc = GW2 * ri[RP(i)];
        if (i >= 1)   acc += GW1 * ri[RP(i - 1)];
        if (i >= 2)   acc += GW0 * ri[RP(i - 2)];
        if (i <= 510) acc += GW1 * ri[RP(i + 1)];
        if (i <= 509) acc += GW0 * ri[RP(i + 2)];
        ((float*)&res)[k4] = acc;
    }
    *reinterpret_cast<float4*>(o + u * 4) = res;
}

// Vertical blur (float4, 4 elems/thread) + per-BLOCK min/max partials.
// Also zeroes the hist/ccnt scratch region (replaces a runtime memset).
__global__ void k_vblur(const float* __restrict__ in, float* __restrict__ out,
                        float* __restrict__ pmn, float* __restrict__ pmx,
                        unsigned int* __restrict__ zr) {
    __shared__ float smn[256];
    __shared__ float smx[256];
    int t = threadIdx.x;
    int gi = blockIdx.x * 256 + t;
    if (gi < ZEROWORDS) zr[gi] = 0u;      // hists + ccnt live at ws[0..819264)
    int i = gi * 4;
    int y = (i >> 9) & 511;               // same row for all 4 elems (4 | 512)
    const float4 c = *reinterpret_cast<const float4*>(in + i);
    float4 acc = make_float4(GW2 * c.x, GW2 * c.y, GW2 * c.z, GW2 * c.w);
    if (y >= 1) {
        const float4 v = *reinterpret_cast<const float4*>(in + i - 512);
        acc.x += GW1 * v.x; acc.y += GW1 * v.y; acc.z += GW1 * v.z; acc.w += GW1 * v.w;
    }
    if (y >= 2) {
        const float4 v = *reinterpret_cast<const float4*>(in + i - 1024);
        acc.x += GW0 * v.x; acc.y += GW0 * v.y; acc.z += GW0 * v.z; acc.w += GW0 * v.w;
    }
    if (y <= 510) {
        const float4 v = *reinterpret_cast<const float4*>(in + i + 512);
        acc.x += GW1 * v.x; acc.y += GW1 * v.y; acc.z += GW1 * v.z; acc.w += GW1 * v.w;
    }
    if (y <= 509) {
        const float4 v = *reinterpret_cast<const float4*>(in + i + 1024);
        acc.x += GW0 * v.x; acc.y += GW0 * v.y; acc.z += GW0 * v.z; acc.w += GW0 * v.w;
    }
    *reinterpret_cast<float4*>(out + i) = acc;
    float lmn = fminf(fminf(acc.x, acc.y), fminf(acc.z, acc.w));
    float lmx = fmaxf(fmaxf(acc.x, acc.y), fmaxf(acc.z, acc.w));
    smn[t] = lmn; smx[t] = lmx;
    __syncthreads();
    for (int s = 128; s > 0; s >>= 1) {
        if (t < s) { smn[t] = fminf(smn[t], smn[t + s]); smx[t] = fmaxf(smx[t], smx[t + s]); }
        __syncthreads();
    }
    if (t == 0) { pmn[blockIdx.x] = smn[0]; pmx[blockIdx.x] = smx[0]; }
}

// Normalize + border mask -> final saliency (d_out), fused with hist round 1.
// Each block redundantly folds its image's 256 min/max partials first.
__global__ void k_norm_hist(const float* __restrict__ in, const float* __restrict__ pmn,
                            const float* __restrict__ pmx, float* __restrict__ out,
                            unsigned int* __restrict__ g) {
    __shared__ unsigned int h[4096];
    __shared__ float smn[256], smx[256];
    int t = threadIdx.x;
    int b = blockIdx.x >> 5;
    int base = b * HW + (blockIdx.x & 31) * 8192;
    smn[t] = pmn[b * 256 + t];
    smx[t] = pmx[b * 256 + t];
    for (int i = t; i < 4096; i += 256) h[i] = 0u;
    __syncthreads();
    for (int s = 128; s > 0; s >>= 1) {
        if (t < s) { smn[t] = fminf(smn[t], smn[t + s]); smx[t] = fmaxf(smx[t], smx[t + s]); }
        __syncthreads();
    }
    float mn = smn[0], mx = smx[0];
    float inv = 1.0f / (mx - mn + 1e-8f);
    for (int j = 0; j < 32; ++j) {
        int idx = base + j * 256 + t;
        float v = (in[idx] - mn) * inv;
        int xx = idx & 511, yy = (idx >> 9) & 511;
        bool inside = (xx >= 12) && (xx < 500) && (yy >= 12) && (yy < 500);
        v = inside ? v : 0.0f;
        out[idx] = v;
        atomicAdd(&h[__float_as_uint(v) >> 20], 1u);
    }
    __syncthreads();
    unsigned int* gb = g + b * 4096;
    for (int i = t; i < 4096; i += 256)
        if (h[i]) atomicAdd(&gb[i], h[i]);
}

// ---------------------------------------------------------------------------
// PARALLEL radix_step: find largest bin B with suffix-count(B) >= krem and
// the remainder krem' = krem - suffix(B+1). Hillis-Steele suffix scan across
// 256 threads + unique-boundary publication.
// ---------------------------------------------------------------------------
__device__ void radix_step(const unsigned int* __restrict__ h, int nbins, int krem,
                           int t, unsigned int* tsuf, int* sbin, int* skrem) {
    int bpt = nbins >> 8;
    unsigned int s = 0;
    for (int j = 0; j < bpt; ++j) s += h[t * bpt + j];
    tsuf[t] = s;
    __syncthreads();
    #pragma unroll
    for (int off = 1; off < 256; off <<= 1) {
        unsigned int v = (t + off < 256) ? tsuf[t + off] : 0u;
        __syncthreads();
        tsuf[t] += v;
        __syncthreads();
    }
    if ((int)tsuf[t] >= krem && (t == 255 || (int)tsuf[t + 1] < krem))
        *sbin = t;
    __syncthreads();
    int seg = *sbin;
    int krem2 = krem - (seg < 255 ? (int)tsuf[seg + 1] : 0);
    __syncthreads();            // all threads have read seg before overwrite
    if (t < bpt) {
        unsigned int L = 0;
        for (int j = t; j < bpt; ++j) L += h[seg * bpt + j];
        unsigned int hv = h[seg * bpt + t];
        if ((int)L >= krem2 && (int)(L - hv) < krem2) {
            *sbin  = seg * bpt + t;
            *skrem = krem2 - (int)(L - hv);
        }
    }
    __syncthreads();
}

// Round-2 histograms, with round-1 scan fused (redundant per block).
__global__ void k_hist2(const float* __restrict__ sal, const unsigned int* __restrict__ g1,
                        unsigned int* __restrict__ gA, unsigned int* __restrict__ gB,
                        unsigned int* prefA1, int* kremA1, unsigned int* prefB1, int* kremB1) {
    __shared__ unsigned int hA[4096];
    __shared__ unsigned int hB[4096];
    __shared__ unsigned int tsuf[256];
    __shared__ int sbin, skrem;
    int t = threadIdx.x;
    int b = blockIdx.x >> 5;
    int start = (blockIdx.x & 31) * 8192;
    for (int i = t; i < 4096; i += 256) { hA[i] = 0u; hB[i] = 0u; }
    radix_step(g1 + b * 4096, 4096, KSEL, t, tsuf, &sbin, &skrem);
    unsigned int pA = (unsigned int)sbin; int krA = skrem;
    radix_step(g1 + b * 4096, 4096, MCAND, t, tsuf, &sbin, &skrem);
    unsigned int pB = (unsigned int)sbin; int krB = skrem;
    if (t == 0 && (blockIdx.x & 31) == 0) {
        prefA1[b] = pA; kremA1[b] = krA; prefB1[b] = pB; kremB1[b] = krB;
    }
    const float* p = sal + (size_t)b * HW;
    for (int j = 0; j < 32; ++j) {
        unsigned int u = __float_as_uint(p[start + j * 256 + t]);
        unsigned int hi = u >> 20, mid = (u >> 8) & 4095u;
        if (hi == pA) atomicAdd(&hA[mid], 1u);
        if (hi == pB) atomicAdd(&hB[mid], 1u);
    }
    __syncthreads();
    unsigned int* ga = gA + b * 4096;
    unsigned int* gb2 = gB + b * 4096;
    for (int i = t; i < 4096; i += 256) {
        if (hA[i]) atomicAdd(&ga[i], hA[i]);
        if (hB[i]) atomicAdd(&gb2[i], hB[i]);
    }
}

// Round-3 A-histogram + candidate collection, with round-2 scan fused.
__global__ void k_hist3collect(const float* __restrict__ sal,
                               const unsigned int* __restrict__ gA2, const unsigned int* __restrict__ gB2,
                               const unsigned int* prefA1, const int* kremA1,
                               const unsigned int* prefB1, const int* kremB1,
                               unsigned int* __restrict__ gA3,
                               unsigned int* prefA24, int* kremA2,
                               float* __restrict__ candv, int* __restrict__ candi,
                               int* __restrict__ ccnt) {
    __shared__ unsigned int hA[256];
    __shared__ unsigned int tsuf[256];
    __shared__ int sbin, skrem;
    int t = threadIdx.x;
    int b = blockIdx.x >> 5;
    int start = (blockIdx.x & 31) * 8192;
    hA[t] = 0u;
    radix_step(gA2 + b * 4096, 4096, kremA1[b], t, tsuf, &sbin, &skrem);
    unsigned int pA = (prefA1[b] << 12) | (unsigned int)sbin;
    int krA2 = skrem;
    radix_step(gB2 + b * 4096, 4096, kremB1[b], t, tsuf, &sbin, &skrem);
    unsigned int cutB = ((prefB1[b] << 12) | (unsigned int)sbin) << 8;
    if (t == 0 && (blockIdx.x & 31) == 0) { prefA24[b] = pA; kremA2[b] = krA2; }
    const float* p = sal + (size_t)b * HW;
    for (int j = 0; j < 32; ++j) {
        int i = start + j * 256 + t;
        unsigned int u = __float_as_uint(p[i]);
        if ((u >> 8) == pA) atomicAdd(&hA[u & 255u], 1u);
        if (u >= cutB) {
            int pos = atomicAdd(&ccnt[b], 1);
            if (pos < CAP) { candv[b * CAP + pos] = p[i]; candi[b * CAP + pos] = i; }
        }
    }
    __syncthreads();
    if (hA[t]) atomicAdd(&gA3[b * 256 + t], hA[t]);
}

// Final: derive exact thr from hist3a, rank (value desc, index asc), bitmask
// greedy NMS with validity v >= thr (matches reference -inf filtering).
__global__ void k_final(const unsigned int* __restrict__ gA3,
                        const unsigned int* prefA24, const int* kremA2,
                        const float* __restrict__ candv, const int* __restrict__ candi,
                        const int* __restrict__ ccnt, float* __restrict__ out) {
    __shared__ float cval[CAP];
    __shared__ int   cidx[CAP];
    __shared__ int   si[MCAND];
    __shared__ float svv[MCAND];
    __shared__ float sx[MCAND];
    __shared__ float sy[MCAND];
    __shared__ unsigned long long nearLo[MCAND];
    __shared__ unsigned long long nearHi[MCAND];
    __shared__ unsigned int tsuf[256];
    __shared__ int sbin, skrem;
    int b = blockIdx.x, t = threadIdx.x;
    radix_step(gA3 + b * 256, 256, kremA2[b], t, tsuf, &sbin, &skrem);
    float thr = fmaxf(__uint_as_float((prefA24[b] << 8) | (unsigned int)sbin), 0.1f);
    int n = min(ccnt[b], CAP);
    for (int i = t; i < n; i += 256) { cval[i] = candv[b * CAP + i]; cidx[i] = candi[b * CAP + i]; }
    __syncthreads();
    int m = min(n, MCAND);
    for (int i = t; i < n; i += 256) {
        float vi = cval[i]; int ii = cidx[i];
        int rank = 0;
        for (int j = 0; j < n; j++) {
            float vj = cval[j];
            if (vj > vi || (vj == vi && cidx[j] < ii)) rank++;
        }
        if (rank < MCAND) { si[rank] = ii; svv[rank] = vi; }
    }
    __syncthreads();
    for (int i = t; i < m; i += 256) {
        sx[i] = (float)(si[i] & 511);
        sy[i] = (float)(si[i] >> 9);
    }
    __syncthreads();
    for (int i = t; i < m; i += 256) {
        unsigned long long lo = 0ull, hi = 0ull;
        float x = sx[i], y = sy[i];
        for (int j = 0; j < m; j++) {
            float dx = sx[j] - x, dy = sy[j] - y;
            if (dx * dx + dy * dy < 100.0f) {
                if (j < 64) lo |= (1ull << j);
                else        hi |= (1ull << (j - 64));
            }
        }
        nearLo[i] = lo; nearHi[i] = hi;
    }
    __syncthreads();
    if (t == 0) {
        unsigned long long kLo = 0ull, kHi = 0ull;
        int cnt = 0;
        for (int i = 0; i < m; i++) {
            bool near_kept = ((nearLo[i] & kLo) | (nearHi[i] & kHi)) != 0ull;
            if (svv[i] >= thr && !near_kept) {
                out[b * 10 + 2 * cnt]     = sx[i];
                out[b * 10 + 2 * cnt + 1] = sy[i];
                out[160 + b * 5 + cnt]    = 1.0f;
                if (i < 64) kLo |= (1ull << i); else kHi |= (1ull << (i - 64));
                cnt++;
                if (cnt == TOPK) break;
            }
        }
        for (int j = cnt; j < TOPK; j++) {
            out[b * 10 + 2 * j]     = -1.0f;
            out[b * 10 + 2 * j + 1] = -1.0f;
            out[160 + b * 5 + j]    = -1.0f;
        }
    }
}

extern "C" void kernel_launch(void* const* d_in, const int* in_sizes, int n_in,
                              void* d_out, int out_size, void* d_ws, size_t ws_size,
                              hipStream_t stream) {
    const float* img = (const float*)d_in[0];
    float* out = (float*)d_out;
    char* ws = (char*)d_ws;

    float2* A    = (float2*)ws;
    float*  hb   = (float*)(ws + 33554432UL);
    float*  salb = (float*)(ws + 50331648UL);

    unsigned int* hist1  = (unsigned int*)(ws + 0UL);
    unsigned int* hist2a = (unsigned int*)(ws + 262144UL);
    unsigned int* hist2b = (unsigned int*)(ws + 524288UL);
    unsigned int* hist3a = (unsigned int*)(ws + 786432UL);
    int*          ccnt   = (int*)(ws + 819200UL);
    float*        candv  = (float*)(ws + 851968UL);
    int*          candi  = (int*)(ws + 983040UL);

    float* pmn = (float*)(ws + 20971520UL);                 // 4096 f32
    float* pmx = (float*)(ws + 21037056UL);                 // 4096 f32

    char* stats = ws + 67108864UL;
    unsigned int* prefA1  = (unsigned int*)(stats + 0);
    int*          kremA1  = (int*)(stats + 64);
    unsigned int* prefB1  = (unsigned int*)(stats + 128);
    int*          kremB1  = (int*)(stats + 192);
    unsigned int* prefA24 = (unsigned int*)(stats + 256);
    int*          kremA2  = (int*)(stats + 320);

    float* salout = out + 240;   // sal region of d_out

    k_win_rowfft<<<dim3(4096), dim3(256), 0, stream>>>(img, A);     // radix-4 W fwd
    k_colfft<<<dim3(512), dim3(512), 0, stream>>>(A);               // radix-16-paired H pass
    k_mag_hblur<<<dim3(4096), dim3(256), 0, stream>>>(A, hb);       // radix-4 W inv + mag + hblur
    k_vblur<<<dim3(4096), dim3(256), 0, stream>>>(hb, salb, pmn, pmx,
                                                  (unsigned int*)ws); // + zero hists/ccnt
    k_norm_hist<<<dim3(512), dim3(256), 0, stream>>>(salb, pmn, pmx, salout, hist1);
    k_hist2<<<dim3(512), dim3(256), 0, stream>>>(salout, hist1, hist2a, hist2b,
                                                 prefA1, kremA1, prefB1, kremB1);
    k_hist3collect<<<dim3(512), dim3(256), 0, stream>>>(salout, hist2a, hist2b,
                                                        prefA1, kremA1, prefB1, kremB1,
                                                        hist3a, prefA24, kremA2,
                                                        candv, candi, ccnt);
    k_final<<<dim3(BATCH), dim3(256), 0, stream>>>(hist3a, prefA24, kremA2,
                                                   candv, candi, ccnt, out);
}

// Round 14
// 129.462 us; speedup vs baseline: 2.0230x; 1.1769x over previous
//
#include <hip/hip_runtime.h>
#include <math.h>

#define BATCH 16
#define HW 262144          // 512*512
#define KSEL 26214         // int(0.1 * 262144)
#define MCAND 80           // TOP_K * CAND_MULT
#define TOPK 5
#define CAP 2048
#define ZEROWORDS 204816   // (hists + ccnt) bytes / 4, zeroed inside k_vblur

// ---------------------------------------------------------------------------
// In-place FFT, N=512 = 4*4*4*4*2. Forward DIF natural->digit-reversed;
// inverse DIT (conj twiddles, mirrored order) digit-reversed->natural.
// DIT(DIF(x)) = 512*x elementwise; the digit-reversed intermediate order is
// unobservable (phase normalize elementwise; axes independent).
// All kernels: stage PAIRS combined in registers (16 elems/thread), and the
// lone radix-2 stage fused into adjacent global-IO or the normalize pass.
// Twiddles from LDS table tw[i] = e^{-2*pi*i/512} (tw[i+256] = -tw[i]).
// ---------------------------------------------------------------------------

// Gaussian blur coefficients, sigma=1, 5-tap.
#define GW0 0.05448868454964294f
#define GW1 0.24420134200323332f
#define GW2 0.40261994689424746f

#define FILL_TW512(nthr)                                       \
    for (int i_ = threadIdx.x; i_ < 256; i_ += (nthr)) {       \
        float rev_ = -(float)i_ * (1.0f / 512.0f);             \
        float s_ = __builtin_amdgcn_sinf(rev_);                \
        float c_ = __builtin_amdgcn_cosf(rev_);                \
        tws[i_] = s_;        twc[i_] = c_;                     \
        tws[i_ + 256] = -s_; twc[i_ + 256] = -c_;              \
    }

// LDS pad-every-16.
#define RP(a) ((a) + ((a) >> 4))
#define RSZ 544             // 512 + 32 pad floats per row

// Register radix-4 DIF butterfly (outputs in place, twiddles applied).
#define R4F_REG(x0,y0,x1,y1,x2,y2,x3,y3, e)                                   \
    { float s02x=(x0)+(x2), s02y=(y0)+(y2), d02x=(x0)-(x2), d02y=(y0)-(y2);    \
      float s13x=(x1)+(x3), s13y=(y1)+(y3), d13x=(x1)-(x3), d13y=(y1)-(y3);    \
      float z0x=s02x+s13x, z0y=s02y+s13y;                                      \
      float z2x=s02x-s13x, z2y=s02y-s13y;                                      \
      float z1x=d02x+d13y, z1y=d02y-d13x;                                      \
      float z3x=d02x-d13y, z3y=d02y+d13x;                                      \
      float c1=twc[(e)], s1=tws[(e)], c2=twc[2*(e)], s2=tws[2*(e)];            \
      float c3=twc[3*(e)], s3=tws[3*(e)];                                      \
      x0=z0x; y0=z0y;                                                          \
      x1=z1x*c1-z1y*s1; y1=z1x*s1+z1y*c1;                                      \
      x2=z2x*c2-z2y*s2; y2=z2x*s2+z2y*c2;                                      \
      x3=z3x*c3-z3y*s3; y3=z3x*s3+z3y*c3; }

// Register radix-4 DIT inverse butterfly (conj twiddles first).
#define R4I_REG(x0,y0,x1,y1,x2,y2,x3,y3, e)                                   \
    { float c1=twc[(e)], s1=tws[(e)], c2=twc[2*(e)], s2=tws[2*(e)];            \
      float c3=twc[3*(e)], s3=tws[3*(e)];                                      \
      float t1x=(x1)*c1+(y1)*s1, t1y=(y1)*c1-(x1)*s1;                          \
      float t2x=(x2)*c2+(y2)*s2, t2y=(y2)*c2-(x2)*s2;                          \
      float t3x=(x3)*c3+(y3)*s3, t3y=(y3)*c3-(x3)*s3;                          \
      float s02x=(x0)+t2x, s02y=(y0)+t2y, d02x=(x0)-t2x, d02y=(y0)-t2y;        \
      float s13x=t1x+t3x, s13y=t1y+t3y, d13x=t1x-t3x, d13y=t1y-t3y;            \
      x0=s02x+s13x; y0=s02y+s13y;                                              \
      x2=s02x-s13x; y2=s02y-s13y;                                              \
      x1=d02x-d13y; y1=d02y+d13x;                                              \
      x3=d02x+d13y; y3=d02y-d13x; }

// Load 16 elems (group j = tt + 128a + 32b) from LDS into rx/ry.
#define LD_P1(rr, ri)                                                          \
    _Pragma("unroll") for (int a = 0; a < 4; ++a)                              \
    _Pragma("unroll") for (int bq = 0; bq < 4; ++bq) {                         \
        int j = tt + a * 128 + bq * 32;                                        \
        rx[a][bq] = rr[RP(j)]; ry[a][bq] = ri[RP(j)]; }
#define ST_P1(rr, ri)                                                          \
    _Pragma("unroll") for (int a = 0; a < 4; ++a)                              \
    _Pragma("unroll") for (int bq = 0; bq < 4; ++bq) {                         \
        int j = tt + a * 128 + bq * 32;                                        \
        rr[RP(j)] = rx[a][bq]; ri[RP(j)] = ry[a][bq]; }
// Pair-2 group j = 32*(tt>>1) + (tt&1) + 8a + 2b.
#define LD_P2(rr, ri)                                                          \
    _Pragma("unroll") for (int a = 0; a < 4; ++a)                              \
    _Pragma("unroll") for (int bq = 0; bq < 4; ++bq) {                         \
        int j = jb + a * 8 + bq * 2;                                           \
        rx[a][bq] = rr[RP(j)]; ry[a][bq] = ri[RP(j)]; }
#define ST_P2(rr, ri)                                                          \
    _Pragma("unroll") for (int a = 0; a < 4; ++a)                              \
    _Pragma("unroll") for (int bq = 0; bq < 4; ++bq) {                         \
        int j = jb + a * 8 + bq * 2;                                           \
        rr[RP(j)] = rx[a][bq]; ri[RP(j)] = ry[a][bq]; }

#define PAIR1_FWD                                                              \
    _Pragma("unroll") for (int bq = 0; bq < 4; ++bq) {                         \
        int e = tt + bq * 32;                                                  \
        R4F_REG(rx[0][bq], ry[0][bq], rx[1][bq], ry[1][bq],                    \
                rx[2][bq], ry[2][bq], rx[3][bq], ry[3][bq], e) }               \
    { int e = tt << 2;                                                         \
      _Pragma("unroll") for (int a = 0; a < 4; ++a)                            \
          R4F_REG(rx[a][0], ry[a][0], rx[a][1], ry[a][1],                      \
                  rx[a][2], ry[a][2], rx[a][3], ry[a][3], e) }
#define PAIR2_FWD                                                              \
    _Pragma("unroll") for (int bq = 0; bq < 4; ++bq) {                         \
        int e = (r2 + 2 * bq) << 4;                                            \
        R4F_REG(rx[0][bq], ry[0][bq], rx[1][bq], ry[1][bq],                    \
                rx[2][bq], ry[2][bq], rx[3][bq], ry[3][bq], e) }               \
    { int e = r2 << 6;                                                         \
      _Pragma("unroll") for (int a = 0; a < 4; ++a)                            \
          R4F_REG(rx[a][0], ry[a][0], rx[a][1], ry[a][1],                      \
                  rx[a][2], ry[a][2], rx[a][3], ry[a][3], e) }
#define PAIR2_INV                                                              \
    { int e = r2 << 6;                                                         \
      _Pragma("unroll") for (int a = 0; a < 4; ++a)                            \
          R4I_REG(rx[a][0], ry[a][0], rx[a][1], ry[a][1],                      \
                  rx[a][2], ry[a][2], rx[a][3], ry[a][3], e) }                 \
    _Pragma("unroll") for (int bq = 0; bq < 4; ++bq) {                         \
        int e = (r2 + 2 * bq) << 4;                                            \
        R4I_REG(rx[0][bq], ry[0][bq], rx[1][bq], ry[1][bq],                    \
                rx[2][bq], ry[2][bq], rx[3][bq], ry[3][bq], e) }
#define PAIR1_INV                                                              \
    { int e = tt << 2;                                                         \
      _Pragma("unroll") for (int a = 0; a < 4; ++a)                            \
          R4I_REG(rx[a][0], ry[a][0], rx[a][1], ry[a][1],                      \
                  rx[a][2], ry[a][2], rx[a][3], ry[a][3], e) }                 \
    _Pragma("unroll") for (int bq = 0; bq < 4; ++bq) {                         \
        int e = tt + bq * 32;                                                  \
        R4I_REG(rx[0][bq], ry[0][bq], rx[1][bq], ry[1][bq],                    \
                rx[2][bq], ry[2][bq], rx[3][bq], ry[3][bq], e) }

// K1: window + forward FFT along W. 8 rows per 256-thread block, 32 thr/row.
// Final radix-2 fused into the global store (pairs (2q,2q+1) = store lanes).
__global__ void k_win_rowfft(const float* __restrict__ img, float2* __restrict__ A) {
    __shared__ float re[8 * RSZ], im[8 * RSZ];
    __shared__ float twc[512], tws[512];
    int t = threadIdx.x;
    FILL_TW512(256)
    int lr = t >> 5;                 // local row 0..7
    int tt = t & 31;                 // per-row lane
    int row = blockIdx.x * 8 + lr;   // b*512 + h
    int h = row & 511;
    float wr = 0.5f * (1.0f - __builtin_amdgcn_cosf((float)h * (1.0f / 511.0f)));
    const float* p = img + (size_t)row * 512;
    float* rr = re + lr * RSZ;
    float* ri = im + lr * RSZ;
    #pragma unroll
    for (int k = 0; k < 4; ++k) {
        int i0 = k * 128 + tt * 4;
        float4 v = *reinterpret_cast<const float4*>(p + i0);
        #pragma unroll
        for (int j = 0; j < 4; ++j) {
            float wc = 0.5f * (1.0f - __builtin_amdgcn_cosf((float)(i0 + j) * (1.0f / 511.0f)));
            rr[RP(i0 + j)] = ((const float*)&v)[j] * wr * wc;
            ri[RP(i0 + j)] = 0.0f;
        }
    }
    __syncthreads();
    float rx[4][4], ry[4][4];
    LD_P1(rr, ri)
    PAIR1_FWD
    ST_P1(rr, ri)
    __syncthreads();
    int r2 = tt & 1, jb = (tt >> 1) * 32 + r2;
    LD_P2(rr, ri)
    PAIR2_FWD
    ST_P2(rr, ri)
    __syncthreads();
    // final radix-2 fused with store: pair (2q, 2q+1), q = kk*32+tt
    float2* out = A + (size_t)row * 512;
    #pragma unroll
    for (int kk = 0; kk < 8; ++kk) {
        int j = (kk * 32 + tt) << 1;
        float ax = rr[RP(j)], ay = ri[RP(j)], bx = rr[RP(j + 1)], by = ri[RP(j + 1)];
        float4 v = make_float4(ax + bx, ay + by, ax - bx, ay - by);
        *reinterpret_cast<float4*>(&out[j]) = v;
    }
}

// Fused H-axis pass on 512x16 column tiles. Pairs in registers; the
// fwd-radix-2 + phase-normalize + inv-radix-2 trio fused into ONE pass.
#define CSTR 514
__global__ __launch_bounds__(512) void k_colfft(float2* __restrict__ X) {
    __shared__ float re[16 * CSTR];
    __shared__ float im[16 * CSTR];
    __shared__ float twc[512], tws[512];
    int b = blockIdx.x >> 5;
    int c0 = (blockIdx.x & 31) * 16;
    int t = threadIdx.x;
    FILL_TW512(512)
    float2* base = X + (size_t)b * HW + c0;
    #pragma unroll
    for (int ii = 0; ii < 8; ++ii) {
        int linear = ii * 512 + t;
        int cp = linear & 7;
        int e  = linear >> 3;
        const float4 v = *reinterpret_cast<const float4*>(&base[(size_t)e * 512 + cp * 2]);
        int a0 = (cp * 2) * CSTR + e;
        int a1 = a0 + CSTR;
        re[a0] = v.x; im[a0] = v.y;
        re[a1] = v.z; im[a1] = v.w;
    }
    __syncthreads();
    int c = t & 15, tt = t >> 4;          // 32 threads per column
    float* cr = re + c * CSTR;
    float* ci = im + c * CSTR;
    float rx[4][4], ry[4][4];

    // forward pair 1 (s0: m=128, s1: m=32) — note colfft LDS is unpadded
    #pragma unroll
    for (int a = 0; a < 4; ++a)
        #pragma unroll
        for (int bq = 0; bq < 4; ++bq) {
            int j = tt + a * 128 + bq * 32;
            rx[a][bq] = cr[j]; ry[a][bq] = ci[j];
        }
    PAIR1_FWD
    #pragma unroll
    for (int a = 0; a < 4; ++a)
        #pragma unroll
        for (int bq = 0; bq < 4; ++bq) {
            int j = tt + a * 128 + bq * 32;
            cr[j] = rx[a][bq]; ci[j] = ry[a][bq];
        }
    __syncthreads();
    // forward pair 2 (s2: m=8, s3: m=2)
    int r2 = tt & 1, jb = (tt >> 1) * 32 + r2;
    #pragma unroll
    for (int a = 0; a < 4; ++a)
        #pragma unroll
        for (int bq = 0; bq < 4; ++bq) {
            int j = jb + a * 8 + bq * 2;
            rx[a][bq] = cr[j]; ry[a][bq] = ci[j];
        }
    PAIR2_FWD
    #pragma unroll
    for (int a = 0; a < 4; ++a)
        #pragma unroll
        for (int bq = 0; bq < 4; ++bq) {
            int j = jb + a * 8 + bq * 2;
            cr[j] = rx[a][bq]; ci[j] = ry[a][bq];
        }
    __syncthreads();
    // fused: fwd radix-2 -> phase normalize -> inv radix-2 (same pairs)
    #pragma unroll
    for (int kk = 0; kk < 8; ++kk) {
        int j = (kk * 32 + tt) << 1;
        float ax = cr[j], ay = ci[j], bx = cr[j+1], by = ci[j+1];
        float ux = ax + bx, uy = ay + by;     // fwd r2
        float vx = ax - bx, vy = ay - by;
        float m2u = ux * ux + uy * uy;        // normalize
        if (m2u > 0.0f) { float iv = rsqrtf(m2u); ux *= iv; uy *= iv; }
        else            { ux = 1.0f; uy = 0.0f; }
        float m2v = vx * vx + vy * vy;
        if (m2v > 0.0f) { float iv = rsqrtf(m2v); vx *= iv; vy *= iv; }
        else            { vx = 1.0f; vy = 0.0f; }
        cr[j]   = ux + vx; ci[j]   = uy + vy; // inv r2
        cr[j+1] = ux - vx; ci[j+1] = uy - vy;
    }
    __syncthreads();
    // inverse pair 2 (undo s3 then s2)
    #pragma unroll
    for (int a = 0; a < 4; ++a)
        #pragma unroll
        for (int bq = 0; bq < 4; ++bq) {
            int j = jb + a * 8 + bq * 2;
            rx[a][bq] = cr[j]; ry[a][bq] = ci[j];
        }
    PAIR2_INV
    #pragma unroll
    for (int a = 0; a < 4; ++a)
        #pragma unroll
        for (int bq = 0; bq < 4; ++bq) {
            int j = jb + a * 8 + bq * 2;
            cr[j] = rx[a][bq]; ci[j] = ry[a][bq];
        }
    __syncthreads();
    // inverse pair 1 (undo s1 then s0)
    #pragma unroll
    for (int a = 0; a < 4; ++a)
        #pragma unroll
        for (int bq = 0; bq < 4; ++bq) {
            int j = tt + a * 128 + bq * 32;
            rx[a][bq] = cr[j]; ry[a][bq] = ci[j];
        }
    PAIR1_INV
    #pragma unroll
    for (int a = 0; a < 4; ++a)
        #pragma unroll
        for (int bq = 0; bq < 4; ++bq) {
            int j = tt + a * 128 + bq * 32;
            cr[j] = rx[a][bq]; ci[j] = ry[a][bq];
        }
    __syncthreads();
    #pragma unroll
    for (int ii = 0; ii < 8; ++ii) {
        int linear = ii * 512 + t;
        int cp = linear & 7;
        int e  = linear >> 3;
        int a0 = (cp * 2) * CSTR + e;
        int a1 = a0 + CSTR;
        float4 v = make_float4(re[a0], im[a0], re[a1], im[a1]);
        *reinterpret_cast<float4*>(&base[(size_t)e * 512 + cp * 2]) = v;
    }
}

// Inverse FFT along W + 1/N^2 + |.|^2 + horizontal blur. 8 rows/block.
// First inv radix-2 fused into the global load; |.|^2 in registers after
// inverse pair1 (same element group), storing only ri.
__global__ void k_mag_hblur(const float2* __restrict__ X, float* __restrict__ out) {
    __shared__ float re[8 * RSZ], im[8 * RSZ];
    __shared__ float twc[512], tws[512];
    int t = threadIdx.x;
    FILL_TW512(256)
    int lr = t >> 5;
    int tt = t & 31;
    int row = blockIdx.x * 8 + lr;
    const float2* p = X + (size_t)row * 512;
    float* rr = re + lr * RSZ;
    float* ri = im + lr * RSZ;
    // load + inverse radix-2 (pair (2q,2q+1) = load lanes)
    #pragma unroll
    for (int kk = 0; kk < 8; ++kk) {
        int j = (kk * 32 + tt) << 1;
        float4 v = *reinterpret_cast<const float4*>(&p[j]);
        rr[RP(j)]     = v.x + v.z;  ri[RP(j)]     = v.y + v.w;
        rr[RP(j + 1)] = v.x - v.z;  ri[RP(j + 1)] = v.y - v.w;
    }
    __syncthreads();
    float rx[4][4], ry[4][4];
    int r2 = tt & 1, jb = (tt >> 1) * 32 + r2;
    LD_P2(rr, ri)
    PAIR2_INV
    ST_P2(rr, ri)
    __syncthreads();
    LD_P1(rr, ri)
    PAIR1_INV
    // |.|^2 in registers; store only into ri (rr dead)
    const float s = 3.814697265625e-06f;   // 1/262144, exact
    #pragma unroll
    for (int a = 0; a < 4; ++a)
        #pragma unroll
        for (int bq = 0; bq < 4; ++bq) {
            int j = tt + a * 128 + bq * 32;
            float x = rx[a][bq] * s, y = ry[a][bq] * s;
            ri[RP(j)] = x * x + y * y;
        }
    __syncthreads();
    float* o = out + (size_t)row * 512;
    #pragma unroll
    for (int kk = 0; kk < 4; ++kk) {
        int i0 = (kk * 32 + tt) * 4;
        float4 res;
        #pragma unroll
        for (int j = 0; j < 4; ++j) {
            int i = i0 + j;
            float acc = GW2 * ri[RP(i)];
            if (i >= 1)   acc += GW1 * ri[RP(i - 1)];
            if (i >= 2)   acc += GW0 * ri[RP(i - 2)];
            if (i <= 510) acc += GW1 * ri[RP(i + 1)];
            if (i <= 509) acc += GW0 * ri[RP(i + 2)];
            ((float*)&res)[j] = acc;
        }
        *reinterpret_cast<float4*>(o + i0) = res;
    }
}

// Vertical blur (float4, 4 elems/thread) + per-BLOCK min/max partials.
// Also zeroes the hist/ccnt scratch region (replaces a runtime memset).
__global__ void k_vblur(const float* __restrict__ in, float* __restrict__ out,
                        float* __restrict__ pmn, float* __restrict__ pmx,
                        unsigned int* __restrict__ zr) {
    __shared__ float smn[256];
    __shared__ float smx[256];
    int t = threadIdx.x;
    int gi = blockIdx.x * 256 + t;
    if (gi < ZEROWORDS) zr[gi] = 0u;      // hists + ccnt live at ws[0..819264)
    int i = gi * 4;
    int y = (i >> 9) & 511;               // same row for all 4 elems (4 | 512)
    const float4 c = *reinterpret_cast<const float4*>(in + i);
    float4 acc = make_float4(GW2 * c.x, GW2 * c.y, GW2 * c.z, GW2 * c.w);
    if (y >= 1) {
        const float4 v = *reinterpret_cast<const float4*>(in + i - 512);
        acc.x += GW1 * v.x; acc.y += GW1 * v.y; acc.z += GW1 * v.z; acc.w += GW1 * v.w;
    }
    if (y >= 2) {
        const float4 v = *reinterpret_cast<const float4*>(in + i - 1024);
        acc.x += GW0 * v.x; acc.y += GW0 * v.y; acc.z += GW0 * v.z; acc.w += GW0 * v.w;
    }
    if (y <= 510) {
        const float4 v = *reinterpret_cast<const float4*>(in + i + 512);
        acc.x += GW1 * v.x; acc.y += GW1 * v.y; acc.z += GW1 * v.z; acc.w += GW1 * v.w;
    }
    if (y <= 509) {
        const float4 v = *reinterpret_cast<const float4*>(in + i + 1024);
        acc.x += GW0 * v.x; acc.y += GW0 * v.y; acc.z += GW0 * v.z; acc.w += GW0 * v.w;
    }
    *reinterpret_cast<float4*>(out + i) = acc;
    float lmn = fminf(fminf(acc.x, acc.y), fminf(acc.z, acc.w));
    float lmx = fmaxf(fmaxf(acc.x, acc.y), fmaxf(acc.z, acc.w));
    smn[t] = lmn; smx[t] = lmx;
    __syncthreads();
    for (int s = 128; s > 0; s >>= 1) {
        if (t < s) { smn[t] = fminf(smn[t], smn[t + s]); smx[t] = fmaxf(smx[t], smx[t + s]); }
        __syncthreads();
    }
    if (t == 0) { pmn[blockIdx.x] = smn[0]; pmx[blockIdx.x] = smx[0]; }
}

// Normalize + border mask -> final saliency (d_out), fused with hist round 1.
__global__ void k_norm_hist(const float* __restrict__ in, const float* __restrict__ pmn,
                            const float* __restrict__ pmx, float* __restrict__ out,
                            unsigned int* __restrict__ g) {
    __shared__ unsigned int h[4096];
    __shared__ float smn[256], smx[256];
    int t = threadIdx.x;
    int b = blockIdx.x >> 5;
    int base = b * HW + (blockIdx.x & 31) * 8192;
    smn[t] = pmn[b * 256 + t];
    smx[t] = pmx[b * 256 + t];
    for (int i = t; i < 4096; i += 256) h[i] = 0u;
    __syncthreads();
    for (int s = 128; s > 0; s >>= 1) {
        if (t < s) { smn[t] = fminf(smn[t], smn[t + s]); smx[t] = fmaxf(smx[t], smx[t + s]); }
        __syncthreads();
    }
    float mn = smn[0], mx = smx[0];
    float inv = 1.0f / (mx - mn + 1e-8f);
    for (int j = 0; j < 32; ++j) {
        int idx = base + j * 256 + t;
        float v = (in[idx] - mn) * inv;
        int xx = idx & 511, yy = (idx >> 9) & 511;
        bool inside = (xx >= 12) && (xx < 500) && (yy >= 12) && (yy < 500);
        v = inside ? v : 0.0f;
        out[idx] = v;
        atomicAdd(&h[__float_as_uint(v) >> 20], 1u);
    }
    __syncthreads();
    unsigned int* gb = g + b * 4096;
    for (int i = t; i < 4096; i += 256)
        if (h[i]) atomicAdd(&gb[i], h[i]);
}

// PARALLEL radix_step (suffix scan + unique-boundary publication).
__device__ void radix_step(const unsigned int* __restrict__ h, int nbins, int krem,
                           int t, unsigned int* tsuf, int* sbin, int* skrem) {
    int bpt = nbins >> 8;
    unsigned int s = 0;
    for (int j = 0; j < bpt; ++j) s += h[t * bpt + j];
    tsuf[t] = s;
    __syncthreads();
    #pragma unroll
    for (int off = 1; off < 256; off <<= 1) {
        unsigned int v = (t + off < 256) ? tsuf[t + off] : 0u;
        __syncthreads();
        tsuf[t] += v;
        __syncthreads();
    }
    if ((int)tsuf[t] >= krem && (t == 255 || (int)tsuf[t + 1] < krem))
        *sbin = t;
    __syncthreads();
    int seg = *sbin;
    int krem2 = krem - (seg < 255 ? (int)tsuf[seg + 1] : 0);
    __syncthreads();
    if (t < bpt) {
        unsigned int L = 0;
        for (int j = t; j < bpt; ++j) L += h[seg * bpt + j];
        unsigned int hv = h[seg * bpt + t];
        if ((int)L >= krem2 && (int)(L - hv) < krem2) {
            *sbin  = seg * bpt + t;
            *skrem = krem2 - (int)(L - hv);
        }
    }
    __syncthreads();
}

// Round-2 histograms, with round-1 scan fused (redundant per block).
__global__ void k_hist2(const float* __restrict__ sal, const unsigned int* __restrict__ g1,
                        unsigned int* __restrict__ gA, unsigned int* __restrict__ gB,
                        unsigned int* prefA1, int* kremA1, unsigned int* prefB1, int* kremB1) {
    __shared__ unsigned int hA[4096];
    __shared__ unsigned int hB[4096];
    __shared__ unsigned int tsuf[256];
    __shared__ int sbin, skrem;
    int t = threadIdx.x;
    int b = blockIdx.x >> 5;
    int start = (blockIdx.x & 31) * 8192;
    for (int i = t; i < 4096; i += 256) { hA[i] = 0u; hB[i] = 0u; }
    radix_step(g1 + b * 4096, 4096, KSEL, t, tsuf, &sbin, &skrem);
    unsigned int pA = (unsigned int)sbin; int krA = skrem;
    radix_step(g1 + b * 4096, 4096, MCAND, t, tsuf, &sbin, &skrem);
    unsigned int pB = (unsigned int)sbin; int krB = skrem;
    if (t == 0 && (blockIdx.x & 31) == 0) {
        prefA1[b] = pA; kremA1[b] = krA; prefB1[b] = pB; kremB1[b] = krB;
    }
    const float* p = sal + (size_t)b * HW;
    for (int j = 0; j < 32; ++j) {
        unsigned int u = __float_as_uint(p[start + j * 256 + t]);
        unsigned int hi = u >> 20, mid = (u >> 8) & 4095u;
        if (hi == pA) atomicAdd(&hA[mid], 1u);
        if (hi == pB) atomicAdd(&hB[mid], 1u);
    }
    __syncthreads();
    unsigned int* ga = gA + b * 4096;
    unsigned int* gb2 = gB + b * 4096;
    for (int i = t; i < 4096; i += 256) {
        if (hA[i]) atomicAdd(&ga[i], hA[i]);
        if (hB[i]) atomicAdd(&gb2[i], hB[i]);
    }
}

// Round-3 A-histogram + candidate collection, with round-2 scan fused.
__global__ void k_hist3collect(const float* __restrict__ sal,
                               const unsigned int* __restrict__ gA2, const unsigned int* __restrict__ gB2,
                               const unsigned int* prefA1, const int* kremA1,
                               const unsigned int* prefB1, const int* kremB1,
                               unsigned int* __restrict__ gA3,
                               unsigned int* prefA24, int* kremA2,
                               float* __restrict__ candv, int* __restrict__ candi,
                               int* __restrict__ ccnt) {
    __shared__ unsigned int hA[256];
    __shared__ unsigned int tsuf[256];
    __shared__ int sbin, skrem;
    int t = threadIdx.x;
    int b = blockIdx.x >> 5;
    int start = (blockIdx.x & 31) * 8192;
    hA[t] = 0u;
    radix_step(gA2 + b * 4096, 4096, kremA1[b], t, tsuf, &sbin, &skrem);
    unsigned int pA = (prefA1[b] << 12) | (unsigned int)sbin;
    int krA2 = skrem;
    radix_step(gB2 + b * 4096, 4096, kremB1[b], t, tsuf, &sbin, &skrem);
    unsigned int cutB = ((prefB1[b] << 12) | (unsigned int)sbin) << 8;
    if (t == 0 && (blockIdx.x & 31) == 0) { prefA24[b] = pA; kremA2[b] = krA2; }
    const float* p = sal + (size_t)b * HW;
    for (int j = 0; j < 32; ++j) {
        int i = start + j * 256 + t;
        unsigned int u = __float_as_uint(p[i]);
        if ((u >> 8) == pA) atomicAdd(&hA[u & 255u], 1u);
        if (u >= cutB) {
            int pos = atomicAdd(&ccnt[b], 1);
            if (pos < CAP) { candv[b * CAP + pos] = p[i]; candi[b * CAP + pos] = i; }
        }
    }
    __syncthreads();
    if (hA[t]) atomicAdd(&gA3[b * 256 + t], hA[t]);
}

// Final: derive exact thr from hist3a, rank (value desc, index asc), bitmask
// greedy NMS with validity v >= thr.
__global__ void k_final(const unsigned int* __restrict__ gA3,
                        const unsigned int* prefA24, const int* kremA2,
                        const float* __restrict__ candv, const int* __restrict__ candi,
                        const int* __restrict__ ccnt, float* __restrict__ out) {
    __shared__ float cval[CAP];
    __shared__ int   cidx[CAP];
    __shared__ int   si[MCAND];
    __shared__ float svv[MCAND];
    __shared__ float sx[MCAND];
    __shared__ float sy[MCAND];
    __shared__ unsigned long long nearLo[MCAND];
    __shared__ unsigned long long nearHi[MCAND];
    __shared__ unsigned int tsuf[256];
    __shared__ int sbin, skrem;
    int b = blockIdx.x, t = threadIdx.x;
    radix_step(gA3 + b * 256, 256, kremA2[b], t, tsuf, &sbin, &skrem);
    float thr = fmaxf(__uint_as_float((prefA24[b] << 8) | (unsigned int)sbin), 0.1f);
    int n = min(ccnt[b], CAP);
    for (int i = t; i < n; i += 256) { cval[i] = candv[b * CAP + i]; cidx[i] = candi[b * CAP + i]; }
    __syncthreads();
    int m = min(n, MCAND);
    for (int i = t; i < n; i += 256) {
        float vi = cval[i]; int ii = cidx[i];
        int rank = 0;
        for (int j = 0; j < n; j++) {
            float vj = cval[j];
            if (vj > vi || (vj == vi && cidx[j] < ii)) rank++;
        }
        if (rank < MCAND) { si[rank] = ii; svv[rank] = vi; }
    }
    __syncthreads();
    for (int i = t; i < m; i += 256) {
        sx[i] = (float)(si[i] & 511);
        sy[i] = (float)(si[i] >> 9);
    }
    __syncthreads();
    for (int i = t; i < m; i += 256) {
        unsigned long long lo = 0ull, hi = 0ull;
        float x = sx[i], y = sy[i];
        for (int j = 0; j < m; j++) {
            float dx = sx[j] - x, dy = sy[j] - y;
            if (dx * dx + dy * dy < 100.0f) {
                if (j < 64) lo |= (1ull << j);
                else        hi |= (1ull << (j - 64));
            }
        }
        nearLo[i] = lo; nearHi[i] = hi;
    }
    __syncthreads();
    if (t == 0) {
        unsigned long long kLo = 0ull, kHi = 0ull;
        int cnt = 0;
        for (int i = 0; i < m; i++) {
            bool near_kept = ((nearLo[i] & kLo) | (nearHi[i] & kHi)) != 0ull;
            if (svv[i] >= thr && !near_kept) {
                out[b * 10 + 2 * cnt]     = sx[i];
                out[b * 10 + 2 * cnt + 1] = sy[i];
                out[160 + b * 5 + cnt]    = 1.0f;
                if (i < 64) kLo |= (1ull << i); else kHi |= (1ull << (i - 64));
                cnt++;
                if (cnt == TOPK) break;
            }
        }
        for (int j = cnt; j < TOPK; j++) {
            out[b * 10 + 2 * j]     = -1.0f;
            out[b * 10 + 2 * j + 1] = -1.0f;
            out[160 + b * 5 + j]    = -1.0f;
        }
    }
}

extern "C" void kernel_launch(void* const* d_in, const int* in_sizes, int n_in,
                              void* d_out, int out_size, void* d_ws, size_t ws_size,
                              hipStream_t stream) {
    const float* img = (const float*)d_in[0];
    float* out = (float*)d_out;
    char* ws = (char*)d_ws;

    float2* A    = (float2*)ws;
    float*  hb   = (float*)(ws + 33554432UL);
    float*  salb = (float*)(ws + 50331648UL);

    unsigned int* hist1  = (unsigned int*)(ws + 0UL);
    unsigned int* hist2a = (unsigned int*)(ws + 262144UL);
    unsigned int* hist2b = (unsigned int*)(ws + 524288UL);
    unsigned int* hist3a = (unsigned int*)(ws + 786432UL);
    int*          ccnt   = (int*)(ws + 819200UL);
    float*        candv  = (float*)(ws + 851968UL);
    int*          candi  = (int*)(ws + 983040UL);

    float* pmn = (float*)(ws + 20971520UL);                 // 4096 f32
    float* pmx = (float*)(ws + 21037056UL);                 // 4096 f32

    char* stats = ws + 67108864UL;
    unsigned int* prefA1  = (unsigned int*)(stats + 0);
    int*          kremA1  = (int*)(stats + 64);
    unsigned int* prefB1  = (unsigned int*)(stats + 128);
    int*          kremB1  = (int*)(stats + 192);
    unsigned int* prefA24 = (unsigned int*)(stats + 256);
    int*          kremA2  = (int*)(stats + 320);

    float* salout = out + 240;   // sal region of d_out

    k_win_rowfft<<<dim3(1024), dim3(256), 0, stream>>>(img, A);     // 8 rows/block
    k_colfft<<<dim3(512), dim3(512), 0, stream>>>(A);               // H pass
    k_mag_hblur<<<dim3(1024), dim3(256), 0, stream>>>(A, hb);       // 8 rows/block
    k_vblur<<<dim3(4096), dim3(256), 0, stream>>>(hb, salb, pmn, pmx,
                                                  (unsigned int*)ws); // + zero hists/ccnt
    k_norm_hist<<<dim3(512), dim3(256), 0, stream>>>(salb, pmn, pmx, salout, hist1);
    k_hist2<<<dim3(512), dim3(256), 0, stream>>>(salout, hist1, hist2a, hist2b,
                                                 prefA1, kremA1, prefB1, kremB1);
    k_hist3collect<<<dim3(512), dim3(256), 0, stream>>>(salout, hist2a, hist2b,
                                                        prefA1, kremA1, prefB1, kremB1,
                                                        hist3a, prefA24, kremA2,
                                                        candv, candi, ccnt);
    k_final<<<dim3(BATCH), dim3(256), 0, stream>>>(hist3a, prefA24, kremA2,
                                                   candv, candi, ccnt, out);
}

// Round 15
// 127.124 us; speedup vs baseline: 2.0602x; 1.0184x over previous
//
#include <hip/hip_runtime.h>
#include <math.h>

#define BATCH 16
#define HW 262144          // 512*512
#define KSEL 26214         // int(0.1 * 262144)
#define MCAND 80           // TOP_K * CAND_MULT
#define TOPK 5
#define CAP 2048
#define ZEROWORDS 204816   // (hists + ccnt) bytes / 4, zeroed inside k_vblur

// ---------------------------------------------------------------------------
// In-place FFT, N=512 = 4*4*4*4*2. Forward DIF natural->digit-reversed;
// inverse DIT (conj twiddles, mirrored order) digit-reversed->natural.
// DIT(DIF(x)) = 512*x elementwise; the digit-reversed intermediate order is
// unobservable (phase normalize elementwise; axes independent).
// All kernels: stage PAIRS combined in registers (16 elems/thread), and the
// lone radix-2 stage fused into adjacent global-IO or the normalize pass.
// Twiddles from LDS table tw[i] = e^{-2*pi*i/512} (tw[i+256] = -tw[i]).
// ---------------------------------------------------------------------------

// Gaussian blur coefficients, sigma=1, 5-tap.
#define GW0 0.05448868454964294f
#define GW1 0.24420134200323332f
#define GW2 0.40261994689424746f

#define FILL_TW512(nthr)                                       \
    for (int i_ = threadIdx.x; i_ < 256; i_ += (nthr)) {       \
        float rev_ = -(float)i_ * (1.0f / 512.0f);             \
        float s_ = __builtin_amdgcn_sinf(rev_);                \
        float c_ = __builtin_amdgcn_cosf(rev_);                \
        tws[i_] = s_;        twc[i_] = c_;                     \
        tws[i_ + 256] = -s_; twc[i_ + 256] = -c_;              \
    }

// LDS pad-every-16.
#define RP(a) ((a) + ((a) >> 4))
#define RSZ 544             // 512 + 32 pad floats per row

// Register radix-4 DIF butterfly (outputs in place, twiddles applied).
#define R4F_REG(x0,y0,x1,y1,x2,y2,x3,y3, e)                                   \
    { float s02x=(x0)+(x2), s02y=(y0)+(y2), d02x=(x0)-(x2), d02y=(y0)-(y2);    \
      float s13x=(x1)+(x3), s13y=(y1)+(y3), d13x=(x1)-(x3), d13y=(y1)-(y3);    \
      float z0x=s02x+s13x, z0y=s02y+s13y;                                      \
      float z2x=s02x-s13x, z2y=s02y-s13y;                                      \
      float z1x=d02x+d13y, z1y=d02y-d13x;                                      \
      float z3x=d02x-d13y, z3y=d02y+d13x;                                      \
      float c1=twc[(e)], s1=tws[(e)], c2=twc[2*(e)], s2=tws[2*(e)];            \
      float c3=twc[3*(e)], s3=tws[3*(e)];                                      \
      x0=z0x; y0=z0y;                                                          \
      x1=z1x*c1-z1y*s1; y1=z1x*s1+z1y*c1;                                      \
      x2=z2x*c2-z2y*s2; y2=z2x*s2+z2y*c2;                                      \
      x3=z3x*c3-z3y*s3; y3=z3x*s3+z3y*c3; }

// Register radix-4 DIT inverse butterfly (conj twiddles first).
#define R4I_REG(x0,y0,x1,y1,x2,y2,x3,y3, e)                                   \
    { float c1=twc[(e)], s1=tws[(e)], c2=twc[2*(e)], s2=tws[2*(e)];            \
      float c3=twc[3*(e)], s3=tws[3*(e)];                                      \
      float t1x=(x1)*c1+(y1)*s1, t1y=(y1)*c1-(x1)*s1;                          \
      float t2x=(x2)*c2+(y2)*s2, t2y=(y2)*c2-(x2)*s2;                          \
      float t3x=(x3)*c3+(y3)*s3, t3y=(y3)*c3-(x3)*s3;                          \
      float s02x=(x0)+t2x, s02y=(y0)+t2y, d02x=(x0)-t2x, d02y=(y0)-t2y;        \
      float s13x=t1x+t3x, s13y=t1y+t3y, d13x=t1x-t3x, d13y=t1y-t3y;            \
      x0=s02x+s13x; y0=s02y+s13y;                                              \
      x2=s02x-s13x; y2=s02y-s13y;                                              \
      x1=d02x-d13y; y1=d02y+d13x;                                              \
      x3=d02x+d13y; y3=d02y-d13x; }

// Load 16 elems (group j = tt + 128a + 32b) from LDS into rx/ry.
#define LD_P1(rr, ri)                                                          \
    _Pragma("unroll") for (int a = 0; a < 4; ++a)                              \
    _Pragma("unroll") for (int bq = 0; bq < 4; ++bq) {                         \
        int j = tt + a * 128 + bq * 32;                                        \
        rx[a][bq] = rr[RP(j)]; ry[a][bq] = ri[RP(j)]; }
#define ST_P1(rr, ri)                                                          \
    _Pragma("unroll") for (int a = 0; a < 4; ++a)                              \
    _Pragma("unroll") for (int bq = 0; bq < 4; ++bq) {                         \
        int j = tt + a * 128 + bq * 32;                                        \
        rr[RP(j)] = rx[a][bq]; ri[RP(j)] = ry[a][bq]; }
// Pair-2 group j = 32*(tt>>1) + (tt&1) + 8a + 2b.
#define LD_P2(rr, ri)                                                          \
    _Pragma("unroll") for (int a = 0; a < 4; ++a)                              \
    _Pragma("unroll") for (int bq = 0; bq < 4; ++bq) {                         \
        int j = jb + a * 8 + bq * 2;                                           \
        rx[a][bq] = rr[RP(j)]; ry[a][bq] = ri[RP(j)]; }
#define ST_P2(rr, ri)                                                          \
    _Pragma("unroll") for (int a = 0; a < 4; ++a)                              \
    _Pragma("unroll") for (int bq = 0; bq < 4; ++bq) {                         \
        int j = jb + a * 8 + bq * 2;                                           \
        rr[RP(j)] = rx[a][bq]; ri[RP(j)] = ry[a][bq]; }

#define PAIR1_FWD                                                              \
    _Pragma("unroll") for (int bq = 0; bq < 4; ++bq) {                         \
        int e = tt + bq * 32;                                                  \
        R4F_REG(rx[0][bq], ry[0][bq], rx[1][bq], ry[1][bq],                    \
                rx[2][bq], ry[2][bq], rx[3][bq], ry[3][bq], e) }               \
    { int e = tt << 2;                                                         \
      _Pragma("unroll") for (int a = 0; a < 4; ++a)                            \
          R4F_REG(rx[a][0], ry[a][0], rx[a][1], ry[a][1],                      \
                  rx[a][2], ry[a][2], rx[a][3], ry[a][3], e) }
#define PAIR2_FWD                                                              \
    _Pragma("unroll") for (int bq = 0; bq < 4; ++bq) {                         \
        int e = (r2 + 2 * bq) << 4;                                            \
        R4F_REG(rx[0][bq], ry[0][bq], rx[1][bq], ry[1][bq],                    \
                rx[2][bq], ry[2][bq], rx[3][bq], ry[3][bq], e) }               \
    { int e = r2 << 6;                                                         \
      _Pragma("unroll") for (int a = 0; a < 4; ++a)                            \
          R4F_REG(rx[a][0], ry[a][0], rx[a][1], ry[a][1],                      \
                  rx[a][2], ry[a][2], rx[a][3], ry[a][3], e) }
#define PAIR2_INV                                                              \
    { int e = r2 << 6;                                                         \
      _Pragma("unroll") for (int a = 0; a < 4; ++a)                            \
          R4I_REG(rx[a][0], ry[a][0], rx[a][1], ry[a][1],                      \
                  rx[a][2], ry[a][2], rx[a][3], ry[a][3], e) }                 \
    _Pragma("unroll") for (int bq = 0; bq < 4; ++bq) {                         \
        int e = (r2 + 2 * bq) << 4;                                            \
        R4I_REG(rx[0][bq], ry[0][bq], rx[1][bq], ry[1][bq],                    \
                rx[2][bq], ry[2][bq], rx[3][bq], ry[3][bq], e) }
#define PAIR1_INV                                                              \
    { int e = tt << 2;                                                         \
      _Pragma("unroll") for (int a = 0; a < 4; ++a)                            \
          R4I_REG(rx[a][0], ry[a][0], rx[a][1], ry[a][1],                      \
                  rx[a][2], ry[a][2], rx[a][3], ry[a][3], e) }                 \
    _Pragma("unroll") for (int bq = 0; bq < 4; ++bq) {                         \
        int e = tt + bq * 32;                                                  \
        R4I_REG(rx[0][bq], ry[0][bq], rx[1][bq], ry[1][bq],                    \
                rx[2][bq], ry[2][bq], rx[3][bq], ry[3][bq], e) }

// K1: window + forward FFT along W. 8 rows per 256-thread block, 32 thr/row.
// Final radix-2 fused into the global store (pairs (2q,2q+1) = store lanes).
__global__ void k_win_rowfft(const float* __restrict__ img, float2* __restrict__ A) {
    __shared__ float re[8 * RSZ], im[8 * RSZ];
    __shared__ float twc[512], tws[512];
    int t = threadIdx.x;
    FILL_TW512(256)
    int lr = t >> 5;                 // local row 0..7
    int tt = t & 31;                 // per-row lane
    int row = blockIdx.x * 8 + lr;   // b*512 + h
    int h = row & 511;
    float wr = 0.5f * (1.0f - __builtin_amdgcn_cosf((float)h * (1.0f / 511.0f)));
    const float* p = img + (size_t)row * 512;
    float* rr = re + lr * RSZ;
    float* ri = im + lr * RSZ;
    #pragma unroll
    for (int k = 0; k < 4; ++k) {
        int i0 = k * 128 + tt * 4;
        float4 v = *reinterpret_cast<const float4*>(p + i0);
        #pragma unroll
        for (int j = 0; j < 4; ++j) {
            float wc = 0.5f * (1.0f - __builtin_amdgcn_cosf((float)(i0 + j) * (1.0f / 511.0f)));
            rr[RP(i0 + j)] = ((const float*)&v)[j] * wr * wc;
            ri[RP(i0 + j)] = 0.0f;
        }
    }
    __syncthreads();
    float rx[4][4], ry[4][4];
    LD_P1(rr, ri)
    PAIR1_FWD
    ST_P1(rr, ri)
    __syncthreads();
    int r2 = tt & 1, jb = (tt >> 1) * 32 + r2;
    LD_P2(rr, ri)
    PAIR2_FWD
    ST_P2(rr, ri)
    __syncthreads();
    float2* out = A + (size_t)row * 512;
    #pragma unroll
    for (int kk = 0; kk < 8; ++kk) {
        int j = (kk * 32 + tt) << 1;
        float ax = rr[RP(j)], ay = ri[RP(j)], bx = rr[RP(j + 1)], by = ri[RP(j + 1)];
        float4 v = make_float4(ax + bx, ay + by, ax - bx, ay - by);
        *reinterpret_cast<float4*>(&out[j]) = v;
    }
}

// Fused H-axis pass on 512x16 column tiles. Pairs in registers; the
// fwd-radix-2 + phase-normalize + inv-radix-2 trio fused into ONE pass.
#define CSTR 514
__global__ __launch_bounds__(512) void k_colfft(float2* __restrict__ X) {
    __shared__ float re[16 * CSTR];
    __shared__ float im[16 * CSTR];
    __shared__ float twc[512], tws[512];
    int b = blockIdx.x >> 5;
    int c0 = (blockIdx.x & 31) * 16;
    int t = threadIdx.x;
    FILL_TW512(512)
    float2* base = X + (size_t)b * HW + c0;
    #pragma unroll
    for (int ii = 0; ii < 8; ++ii) {
        int linear = ii * 512 + t;
        int cp = linear & 7;
        int e  = linear >> 3;
        const float4 v = *reinterpret_cast<const float4*>(&base[(size_t)e * 512 + cp * 2]);
        int a0 = (cp * 2) * CSTR + e;
        int a1 = a0 + CSTR;
        re[a0] = v.x; im[a0] = v.y;
        re[a1] = v.z; im[a1] = v.w;
    }
    __syncthreads();
    int c = t & 15, tt = t >> 4;          // 32 threads per column
    float* cr = re + c * CSTR;
    float* ci = im + c * CSTR;
    float rx[4][4], ry[4][4];

    #pragma unroll
    for (int a = 0; a < 4; ++a)
        #pragma unroll
        for (int bq = 0; bq < 4; ++bq) {
            int j = tt + a * 128 + bq * 32;
            rx[a][bq] = cr[j]; ry[a][bq] = ci[j];
        }
    PAIR1_FWD
    #pragma unroll
    for (int a = 0; a < 4; ++a)
        #pragma unroll
        for (int bq = 0; bq < 4; ++bq) {
            int j = tt + a * 128 + bq * 32;
            cr[j] = rx[a][bq]; ci[j] = ry[a][bq];
        }
    __syncthreads();
    int r2 = tt & 1, jb = (tt >> 1) * 32 + r2;
    #pragma unroll
    for (int a = 0; a < 4; ++a)
        #pragma unroll
        for (int bq = 0; bq < 4; ++bq) {
            int j = jb + a * 8 + bq * 2;
            rx[a][bq] = cr[j]; ry[a][bq] = ci[j];
        }
    PAIR2_FWD
    #pragma unroll
    for (int a = 0; a < 4; ++a)
        #pragma unroll
        for (int bq = 0; bq < 4; ++bq) {
            int j = jb + a * 8 + bq * 2;
            cr[j] = rx[a][bq]; ci[j] = ry[a][bq];
        }
    __syncthreads();
    // fused: fwd radix-2 -> phase normalize -> inv radix-2 (same pairs)
    #pragma unroll
    for (int kk = 0; kk < 8; ++kk) {
        int j = (kk * 32 + tt) << 1;
        float ax = cr[j], ay = ci[j], bx = cr[j+1], by = ci[j+1];
        float ux = ax + bx, uy = ay + by;
        float vx = ax - bx, vy = ay - by;
        float m2u = ux * ux + uy * uy;
        if (m2u > 0.0f) { float iv = rsqrtf(m2u); ux *= iv; uy *= iv; }
        else            { ux = 1.0f; uy = 0.0f; }
        float m2v = vx * vx + vy * vy;
        if (m2v > 0.0f) { float iv = rsqrtf(m2v); vx *= iv; vy *= iv; }
        else            { vx = 1.0f; vy = 0.0f; }
        cr[j]   = ux + vx; ci[j]   = uy + vy;
        cr[j+1] = ux - vx; ci[j+1] = uy - vy;
    }
    __syncthreads();
    #pragma unroll
    for (int a = 0; a < 4; ++a)
        #pragma unroll
        for (int bq = 0; bq < 4; ++bq) {
            int j = jb + a * 8 + bq * 2;
            rx[a][bq] = cr[j]; ry[a][bq] = ci[j];
        }
    PAIR2_INV
    #pragma unroll
    for (int a = 0; a < 4; ++a)
        #pragma unroll
        for (int bq = 0; bq < 4; ++bq) {
            int j = jb + a * 8 + bq * 2;
            cr[j] = rx[a][bq]; ci[j] = ry[a][bq];
        }
    __syncthreads();
    #pragma unroll
    for (int a = 0; a < 4; ++a)
        #pragma unroll
        for (int bq = 0; bq < 4; ++bq) {
            int j = tt + a * 128 + bq * 32;
            rx[a][bq] = cr[j]; ry[a][bq] = ci[j];
        }
    PAIR1_INV
    #pragma unroll
    for (int a = 0; a < 4; ++a)
        #pragma unroll
        for (int bq = 0; bq < 4; ++bq) {
            int j = tt + a * 128 + bq * 32;
            cr[j] = rx[a][bq]; ci[j] = ry[a][bq];
        }
    __syncthreads();
    #pragma unroll
    for (int ii = 0; ii < 8; ++ii) {
        int linear = ii * 512 + t;
        int cp = linear & 7;
        int e  = linear >> 3;
        int a0 = (cp * 2) * CSTR + e;
        int a1 = a0 + CSTR;
        float4 v = make_float4(re[a0], im[a0], re[a1], im[a1]);
        *reinterpret_cast<float4*>(&base[(size_t)e * 512 + cp * 2]) = v;
    }
}

// Inverse FFT along W + 1/N^2 + |.|^2 + horizontal blur. 8 rows/block.
__global__ void k_mag_hblur(const float2* __restrict__ X, float* __restrict__ out) {
    __shared__ float re[8 * RSZ], im[8 * RSZ];
    __shared__ float twc[512], tws[512];
    int t = threadIdx.x;
    FILL_TW512(256)
    int lr = t >> 5;
    int tt = t & 31;
    int row = blockIdx.x * 8 + lr;
    const float2* p = X + (size_t)row * 512;
    float* rr = re + lr * RSZ;
    float* ri = im + lr * RSZ;
    #pragma unroll
    for (int kk = 0; kk < 8; ++kk) {
        int j = (kk * 32 + tt) << 1;
        float4 v = *reinterpret_cast<const float4*>(&p[j]);
        rr[RP(j)]     = v.x + v.z;  ri[RP(j)]     = v.y + v.w;
        rr[RP(j + 1)] = v.x - v.z;  ri[RP(j + 1)] = v.y - v.w;
    }
    __syncthreads();
    float rx[4][4], ry[4][4];
    int r2 = tt & 1, jb = (tt >> 1) * 32 + r2;
    LD_P2(rr, ri)
    PAIR2_INV
    ST_P2(rr, ri)
    __syncthreads();
    LD_P1(rr, ri)
    PAIR1_INV
    const float s = 3.814697265625e-06f;   // 1/262144, exact
    #pragma unroll
    for (int a = 0; a < 4; ++a)
        #pragma unroll
        for (int bq = 0; bq < 4; ++bq) {
            int j = tt + a * 128 + bq * 32;
            float x = rx[a][bq] * s, y = ry[a][bq] * s;
            ri[RP(j)] = x * x + y * y;
        }
    __syncthreads();
    float* o = out + (size_t)row * 512;
    #pragma unroll
    for (int kk = 0; kk < 4; ++kk) {
        int i0 = (kk * 32 + tt) * 4;
        float4 res;
        #pragma unroll
        for (int j = 0; j < 4; ++j) {
            int i = i0 + j;
            float acc = GW2 * ri[RP(i)];
            if (i >= 1)   acc += GW1 * ri[RP(i - 1)];
            if (i >= 2)   acc += GW0 * ri[RP(i - 2)];
            if (i <= 510) acc += GW1 * ri[RP(i + 1)];
            if (i <= 509) acc += GW0 * ri[RP(i + 2)];
            ((float*)&res)[j] = acc;
        }
        *reinterpret_cast<float4*>(o + i0) = res;
    }
}

// Vertical blur (float4, 4 elems/thread) + per-BLOCK min/max partials.
// Also zeroes the hist/ccnt scratch region (replaces a runtime memset).
__global__ void k_vblur(const float* __restrict__ in, float* __restrict__ out,
                        float* __restrict__ pmn, float* __restrict__ pmx,
                        unsigned int* __restrict__ zr) {
    __shared__ float smn[256];
    __shared__ float smx[256];
    int t = threadIdx.x;
    int gi = blockIdx.x * 256 + t;
    if (gi < ZEROWORDS) zr[gi] = 0u;      // hists + ccnt live at ws[0..819264)
    int i = gi * 4;
    int y = (i >> 9) & 511;               // same row for all 4 elems (4 | 512)
    const float4 c = *reinterpret_cast<const float4*>(in + i);
    float4 acc = make_float4(GW2 * c.x, GW2 * c.y, GW2 * c.z, GW2 * c.w);
    if (y >= 1) {
        const float4 v = *reinterpret_cast<const float4*>(in + i - 512);
        acc.x += GW1 * v.x; acc.y += GW1 * v.y; acc.z += GW1 * v.z; acc.w += GW1 * v.w;
    }
    if (y >= 2) {
        const float4 v = *reinterpret_cast<const float4*>(in + i - 1024);
        acc.x += GW0 * v.x; acc.y += GW0 * v.y; acc.z += GW0 * v.z; acc.w += GW0 * v.w;
    }
    if (y <= 510) {
        const float4 v = *reinterpret_cast<const float4*>(in + i + 512);
        acc.x += GW1 * v.x; acc.y += GW1 * v.y; acc.z += GW1 * v.z; acc.w += GW1 * v.w;
    }
    if (y <= 509) {
        const float4 v = *reinterpret_cast<const float4*>(in + i + 1024);
        acc.x += GW0 * v.x; acc.y += GW0 * v.y; acc.z += GW0 * v.z; acc.w += GW0 * v.w;
    }
    *reinterpret_cast<float4*>(out + i) = acc;
    float lmn = fminf(fminf(acc.x, acc.y), fminf(acc.z, acc.w));
    float lmx = fmaxf(fmaxf(acc.x, acc.y), fmaxf(acc.z, acc.w));
    smn[t] = lmn; smx[t] = lmx;
    __syncthreads();
    for (int s = 128; s > 0; s >>= 1) {
        if (t < s) { smn[t] = fminf(smn[t], smn[t + s]); smx[t] = fmaxf(smx[t], smx[t + s]); }
        __syncthreads();
    }
    if (t == 0) { pmn[blockIdx.x] = smn[0]; pmx[blockIdx.x] = smx[0]; }
}

// Normalize + border mask -> final saliency (d_out), fused with hist round 1.
// float4 IO: each thread handles 8 groups of 4 consecutive elements.
__global__ void k_norm_hist(const float* __restrict__ in, const float* __restrict__ pmn,
                            const float* __restrict__ pmx, float* __restrict__ out,
                            unsigned int* __restrict__ g) {
    __shared__ unsigned int h[4096];
    __shared__ float smn[256], smx[256];
    int t = threadIdx.x;
    int b = blockIdx.x >> 5;
    int base = b * HW + (blockIdx.x & 31) * 8192;
    smn[t] = pmn[b * 256 + t];
    smx[t] = pmx[b * 256 + t];
    for (int i = t; i < 4096; i += 256) h[i] = 0u;
    __syncthreads();
    for (int s = 128; s > 0; s >>= 1) {
        if (t < s) { smn[t] = fminf(smn[t], smn[t + s]); smx[t] = fmaxf(smx[t], smx[t + s]); }
        __syncthreads();
    }
    float mn = smn[0], mx = smx[0];
    float inv = 1.0f / (mx - mn + 1e-8f);
    for (int j = 0; j < 8; ++j) {
        int idx = base + j * 1024 + t * 4;
        float4 v4 = *reinterpret_cast<const float4*>(in + idx);
        int x0 = idx & 511, yy = (idx >> 9) & 511;
        bool rowin = (yy >= 12) && (yy < 500);
        float4 o4;
        #pragma unroll
        for (int e = 0; e < 4; ++e) {
            float v = (((const float*)&v4)[e] - mn) * inv;
            int xx = x0 + e;
            bool inside = rowin && (xx >= 12) && (xx < 500);
            v = inside ? v : 0.0f;
            ((float*)&o4)[e] = v;
            atomicAdd(&h[__float_as_uint(v) >> 20], 1u);
        }
        *reinterpret_cast<float4*>(out + idx) = o4;
    }
    __syncthreads();
    unsigned int* gb = g + b * 4096;
    for (int i = t; i < 4096; i += 256)
        if (h[i]) atomicAdd(&gb[i], h[i]);
}

// PARALLEL radix_step (suffix scan + unique-boundary publication).
__device__ void radix_step(const unsigned int* __restrict__ h, int nbins, int krem,
                           int t, unsigned int* tsuf, int* sbin, int* skrem) {
    int bpt = nbins >> 8;
    unsigned int s = 0;
    for (int j = 0; j < bpt; ++j) s += h[t * bpt + j];
    tsuf[t] = s;
    __syncthreads();
    #pragma unroll
    for (int off = 1; off < 256; off <<= 1) {
        unsigned int v = (t + off < 256) ? tsuf[t + off] : 0u;
        __syncthreads();
        tsuf[t] += v;
        __syncthreads();
    }
    if ((int)tsuf[t] >= krem && (t == 255 || (int)tsuf[t + 1] < krem))
        *sbin = t;
    __syncthreads();
    int seg = *sbin;
    int krem2 = krem - (seg < 255 ? (int)tsuf[seg + 1] : 0);
    __syncthreads();
    if (t < bpt) {
        unsigned int L = 0;
        for (int j = t; j < bpt; ++j) L += h[seg * bpt + j];
        unsigned int hv = h[seg * bpt + t];
        if ((int)L >= krem2 && (int)(L - hv) < krem2) {
            *sbin  = seg * bpt + t;
            *skrem = krem2 - (int)(L - hv);
        }
    }
    __syncthreads();
}

// Round-2 histograms, round-1 scan fused; float4 data loop.
__global__ void k_hist2(const float* __restrict__ sal, const unsigned int* __restrict__ g1,
                        unsigned int* __restrict__ gA, unsigned int* __restrict__ gB,
                        unsigned int* prefA1, int* kremA1, unsigned int* prefB1, int* kremB1) {
    __shared__ unsigned int hA[4096];
    __shared__ unsigned int hB[4096];
    __shared__ unsigned int tsuf[256];
    __shared__ int sbin, skrem;
    int t = threadIdx.x;
    int b = blockIdx.x >> 5;
    int start = (blockIdx.x & 31) * 8192;
    for (int i = t; i < 4096; i += 256) { hA[i] = 0u; hB[i] = 0u; }
    radix_step(g1 + b * 4096, 4096, KSEL, t, tsuf, &sbin, &skrem);
    unsigned int pA = (unsigned int)sbin; int krA = skrem;
    radix_step(g1 + b * 4096, 4096, MCAND, t, tsuf, &sbin, &skrem);
    unsigned int pB = (unsigned int)sbin; int krB = skrem;
    if (t == 0 && (blockIdx.x & 31) == 0) {
        prefA1[b] = pA; kremA1[b] = krA; prefB1[b] = pB; kremB1[b] = krB;
    }
    const float* p = sal + (size_t)b * HW;
    for (int j = 0; j < 8; ++j) {
        int i0 = start + j * 1024 + t * 4;
        float4 v4 = *reinterpret_cast<const float4*>(p + i0);
        #pragma unroll
        for (int e = 0; e < 4; ++e) {
            unsigned int u = __float_as_uint(((const float*)&v4)[e]);
            unsigned int hi = u >> 20, mid = (u >> 8) & 4095u;
            if (hi == pA) atomicAdd(&hA[mid], 1u);
            if (hi == pB) atomicAdd(&hB[mid], 1u);
        }
    }
    __syncthreads();
    unsigned int* ga = gA + b * 4096;
    unsigned int* gb2 = gB + b * 4096;
    for (int i = t; i < 4096; i += 256) {
        if (hA[i]) atomicAdd(&ga[i], hA[i]);
        if (hB[i]) atomicAdd(&gb2[i], hB[i]);
    }
}

// Round-3 A-histogram + candidate collection, round-2 scan fused; float4 loop.
__global__ void k_hist3collect(const float* __restrict__ sal,
                               const unsigned int* __restrict__ gA2, const unsigned int* __restrict__ gB2,
                               const unsigned int* prefA1, const int* kremA1,
                               const unsigned int* prefB1, const int* kremB1,
                               unsigned int* __restrict__ gA3,
                               unsigned int* prefA24, int* kremA2,
                               float* __restrict__ candv, int* __restrict__ candi,
                               int* __restrict__ ccnt) {
    __shared__ unsigned int hA[256];
    __shared__ unsigned int tsuf[256];
    __shared__ int sbin, skrem;
    int t = threadIdx.x;
    int b = blockIdx.x >> 5;
    int start = (blockIdx.x & 31) * 8192;
    hA[t] = 0u;
    radix_step(gA2 + b * 4096, 4096, kremA1[b], t, tsuf, &sbin, &skrem);
    unsigned int pA = (prefA1[b] << 12) | (unsigned int)sbin;
    int krA2 = skrem;
    radix_step(gB2 + b * 4096, 4096, kremB1[b], t, tsuf, &sbin, &skrem);
    unsigned int cutB = ((prefB1[b] << 12) | (unsigned int)sbin) << 8;
    if (t == 0 && (blockIdx.x & 31) == 0) { prefA24[b] = pA; kremA2[b] = krA2; }
    const float* p = sal + (size_t)b * HW;
    for (int j = 0; j < 8; ++j) {
        int i0 = start + j * 1024 + t * 4;
        float4 v4 = *reinterpret_cast<const float4*>(p + i0);
        #pragma unroll
        for (int e = 0; e < 4; ++e) {
            float vv = ((const float*)&v4)[e];
            unsigned int u = __float_as_uint(vv);
            if ((u >> 8) == pA) atomicAdd(&hA[u & 255u], 1u);
            if (u >= cutB) {
                int pos = atomicAdd(&ccnt[b], 1);
                if (pos < CAP) { candv[b * CAP + pos] = vv; candi[b * CAP + pos] = i0 + e; }
            }
        }
    }
    __syncthreads();
    if (hA[t]) atomicAdd(&gA3[b * 256 + t], hA[t]);
}

// Final: derive exact thr from hist3a, rank (value desc, index asc), bitmask
// greedy NMS with validity v >= thr.
__global__ void k_final(const unsigned int* __restrict__ gA3,
                        const unsigned int* prefA24, const int* kremA2,
                        const float* __restrict__ candv, const int* __restrict__ candi,
                        const int* __restrict__ ccnt, float* __restrict__ out) {
    __shared__ float cval[CAP];
    __shared__ int   cidx[CAP];
    __shared__ int   si[MCAND];
    __shared__ float svv[MCAND];
    __shared__ float sx[MCAND];
    __shared__ float sy[MCAND];
    __shared__ unsigned long long nearLo[MCAND];
    __shared__ unsigned long long nearHi[MCAND];
    __shared__ unsigned int tsuf[256];
    __shared__ int sbin, skrem;
    int b = blockIdx.x, t = threadIdx.x;
    radix_step(gA3 + b * 256, 256, kremA2[b], t, tsuf, &sbin, &skrem);
    float thr = fmaxf(__uint_as_float((prefA24[b] << 8) | (unsigned int)sbin), 0.1f);
    int n = min(ccnt[b], CAP);
    for (int i = t; i < n; i += 256) { cval[i] = candv[b * CAP + i]; cidx[i] = candi[b * CAP + i]; }
    __syncthreads();
    int m = min(n, MCAND);
    for (int i = t; i < n; i += 256) {
        float vi = cval[i]; int ii = cidx[i];
        int rank = 0;
        for (int j = 0; j < n; j++) {
            float vj = cval[j];
            if (vj > vi || (vj == vi && cidx[j] < ii)) rank++;
        }
        if (rank < MCAND) { si[rank] = ii; svv[rank] = vi; }
    }
    __syncthreads();
    for (int i = t; i < m; i += 256) {
        sx[i] = (float)(si[i] & 511);
        sy[i] = (float)(si[i] >> 9);
    }
    __syncthreads();
    for (int i = t; i < m; i += 256) {
        unsigned long long lo = 0ull, hi = 0ull;
        float x = sx[i], y = sy[i];
        for (int j = 0; j < m; j++) {
            float dx = sx[j] - x, dy = sy[j] - y;
            if (dx * dx + dy * dy < 100.0f) {
                if (j < 64) lo |= (1ull << j);
                else        hi |= (1ull << (j - 64));
            }
        }
        nearLo[i] = lo; nearHi[i] = hi;
    }
    __syncthreads();
    if (t == 0) {
        unsigned long long kLo = 0ull, kHi = 0ull;
        int cnt = 0;
        for (int i = 0; i < m; i++) {
            bool near_kept = ((nearLo[i] & kLo) | (nearHi[i] & kHi)) != 0ull;
            if (svv[i] >= thr && !near_kept) {
                out[b * 10 + 2 * cnt]     = sx[i];
                out[b * 10 + 2 * cnt + 1] = sy[i];
                out[160 + b * 5 + cnt]    = 1.0f;
                if (i < 64) kLo |= (1ull << i); else kHi |= (1ull << (i - 64));
                cnt++;
                if (cnt == TOPK) break;
            }
        }
        for (int j = cnt; j < TOPK; j++) {
            out[b * 10 + 2 * j]     = -1.0f;
            out[b * 10 + 2 * j + 1] = -1.0f;
            out[160 + b * 5 + j]    = -1.0f;
        }
    }
}

extern "C" void kernel_launch(void* const* d_in, const int* in_sizes, int n_in,
                              void* d_out, int out_size, void* d_ws, size_t ws_size,
                              hipStream_t stream) {
    const float* img = (const float*)d_in[0];
    float* out = (float*)d_out;
    char* ws = (char*)d_ws;

    float2* A    = (float2*)ws;
    float*  hb   = (float*)(ws + 33554432UL);
    float*  salb = (float*)(ws + 50331648UL);

    unsigned int* hist1  = (unsigned int*)(ws + 0UL);
    unsigned int* hist2a = (unsigned int*)(ws + 262144UL);
    unsigned int* hist2b = (unsigned int*)(ws + 524288UL);
    unsigned int* hist3a = (unsigned int*)(ws + 786432UL);
    int*          ccnt   = (int*)(ws + 819200UL);
    float*        candv  = (float*)(ws + 851968UL);
    int*          candi  = (int*)(ws + 983040UL);

    float* pmn = (float*)(ws + 20971520UL);                 // 4096 f32
    float* pmx = (float*)(ws + 21037056UL);                 // 4096 f32

    char* stats = ws + 67108864UL;
    unsigned int* prefA1  = (unsigned int*)(stats + 0);
    int*          kremA1  = (int*)(stats + 64);
    unsigned int* prefB1  = (unsigned int*)(stats + 128);
    int*          kremB1  = (int*)(stats + 192);
    unsigned int* prefA24 = (unsigned int*)(stats + 256);
    int*          kremA2  = (int*)(stats + 320);

    float* salout = out + 240;   // sal region of d_out

    k_win_rowfft<<<dim3(1024), dim3(256), 0, stream>>>(img, A);     // 8 rows/block
    k_colfft<<<dim3(512), dim3(512), 0, stream>>>(A);               // H pass
    k_mag_hblur<<<dim3(1024), dim3(256), 0, stream>>>(A, hb);       // 8 rows/block
    k_vblur<<<dim3(4096), dim3(256), 0, stream>>>(hb, salb, pmn, pmx,
                                                  (unsigned int*)ws); // + zero hists/ccnt
    k_norm_hist<<<dim3(512), dim3(256), 0, stream>>>(salb, pmn, pmx, salout, hist1);
    k_hist2<<<dim3(512), dim3(256), 0, stream>>>(salout, hist1, hist2a, hist2b,
                                                 prefA1, kremA1, prefB1, kremB1);
    k_hist3collect<<<dim3(512), dim3(256), 0, stream>>>(salout, hist2a, hist2b,
                                                        prefA1, kremA1, prefB1, kremB1,
                                                        hist3a, prefA24, kremA2,
                                                        candv, candi, ccnt);
    k_final<<<dim3(BATCH), dim3(256), 0, stream>>>(hist3a, prefA24, kremA2,
                                                   candv, candi, ccnt, out);
}